// Round 1
// baseline (1252.407 us; speedup 1.0000x reference)
//
#include <hip/hip_runtime.h>

// HeteroGAT on MI355X. Round 4: replace the 240µs single-block scan with a
// 3-phase hierarchical scan (partial sums -> wave scan of block sums -> emit).
// Everything else identical to the passing round-3 pipeline.

#define NP 100000
#define NA 50000
#define NE 250000

typedef __attribute__((ext_vector_type(8))) short short8;
typedef __attribute__((ext_vector_type(4))) float f32x4;

__device__ __forceinline__ float b2f(unsigned short u) {
  union { unsigned int i; float f; } v; v.i = ((unsigned int)u) << 16; return v.f;
}
__device__ __forceinline__ unsigned short f2b(float f) {
  union { float f; unsigned int i; } v; v.f = f;
  unsigned int u = v.i;
  return (unsigned short)((u + 0x7fffu + ((u >> 16) & 1u)) >> 16);
}

__global__ void probe_kernel(const unsigned short* __restrict__ x, int* __restrict__ flag)
{
  __shared__ int cnt;
  if (threadIdx.x == 0) cnt = 0;
  __syncthreads();
  int c = 0;
  for (int i = threadIdx.x; i < 4096; i += 256) {
    unsigned int e = (x[i] >> 7) & 0xFFu;
    if (e >= 0xC0u) c++;
  }
  atomicAdd(&cnt, c);
  __syncthreads();
  if (threadIdx.x == 0) *flag = (cnt > 64) ? 1 : 0;   // 1 = inputs are fp32
}

__global__ void conv_kernel(const unsigned short* __restrict__ src,
                            unsigned short* __restrict__ dst, int n,
                            const int* __restrict__ flag)
{
  int i = blockIdx.x * 256 + threadIdx.x;
  if (i >= n) return;
  if (*flag) {
    const float* f = (const float*)src;
    dst[i] = f2b(f[i]);
  } else {
    dst[i] = src[i];
  }
}

template <int RELU>
__global__ __launch_bounds__(256) void gemm256(
    const unsigned short* __restrict__ A, const unsigned short* __restrict__ BT,
    unsigned short* __restrict__ C, int M, int K, const unsigned short* __restrict__ bias)
{
  __shared__ __align__(16) unsigned short As[128 * 64];
  __shared__ __align__(16) unsigned short Bs[128 * 64];
  const int t = threadIdx.x;
  const int lane = t & 63;
  const int w = t >> 6;
  const int wr = w >> 1, wc = w & 1;
  const int quad = lane >> 4;
  const int l16 = lane & 15;
  const int m0 = blockIdx.x * 128;
  const int n0 = blockIdx.y * 128;

  f32x4 acc[4][4];
#pragma unroll
  for (int i = 0; i < 4; i++)
#pragma unroll
    for (int j = 0; j < 4; j++) { acc[i][j][0] = 0.f; acc[i][j][1] = 0.f; acc[i][j][2] = 0.f; acc[i][j][3] = 0.f; }

  const int nkc = K >> 6;
  for (int kc = 0; kc < nkc; ++kc) {
    uint4 av[4], bv[4];
#pragma unroll
    for (int i = 0; i < 4; i++) {
      int chunk = i * 256 + t;
      int r = chunk >> 3, c8 = chunk & 7;
      int gr = m0 + r; gr = gr < M ? gr : (M - 1);
      av[i] = *(const uint4*)(A + (size_t)gr * K + (kc * 64 + c8 * 8));
      bv[i] = *(const uint4*)(BT + (size_t)(n0 + r) * K + (kc * 64 + c8 * 8));
    }
    __syncthreads();
#pragma unroll
    for (int i = 0; i < 4; i++) {
      int chunk = i * 256 + t;
      *(uint4*)(As + chunk * 8) = av[i];
      *(uint4*)(Bs + chunk * 8) = bv[i];
    }
    __syncthreads();
#pragma unroll
    for (int ks = 0; ks < 2; ++ks) {
      short8 af[4], bq[4];
#pragma unroll
      for (int i = 0; i < 4; i++)
        af[i] = *(const short8*)(As + (wr * 64 + i * 16 + l16) * 64 + ks * 32 + quad * 8);
#pragma unroll
      for (int j = 0; j < 4; j++)
        bq[j] = *(const short8*)(Bs + (wc * 64 + j * 16 + l16) * 64 + ks * 32 + quad * 8);
#pragma unroll
      for (int i = 0; i < 4; i++)
#pragma unroll
        for (int j = 0; j < 4; j++)
          acc[i][j] = __builtin_amdgcn_mfma_f32_16x16x32_bf16(af[i], bq[j], acc[i][j], 0, 0, 0);
    }
  }
#pragma unroll
  for (int j = 0; j < 4; j++) {
    int col = n0 + wc * 64 + j * 16 + l16;
    float bv2 = bias ? b2f(bias[col]) : 0.f;
#pragma unroll
    for (int i = 0; i < 4; i++) {
      int rbase = m0 + wr * 64 + i * 16 + quad * 4;
#pragma unroll
      for (int r = 0; r < 4; r++) {
        int row = rbase + r;
        if (row < M) {
          float v = acc[i][j][r] + bv2;
          if (RELU) v = v > 0.f ? v : 0.f;
          C[(size_t)row * 256 + col] = f2b(v);
        }
      }
    }
  }
}

// Wp cols: 0-3 al_s(t=1), 4-7 al_s(t=2), 8-11 al_d(t=0), 12-15 al_d(t=1)
// Wa cols: 0-3 al_s(t=0), 4-7 al_d(t=2)
__global__ void fold_kernel(const unsigned short* __restrict__ lin_src,
                            const unsigned short* __restrict__ lin_dst,
                            const unsigned short* __restrict__ att_src,
                            const unsigned short* __restrict__ att_dst,
                            float* __restrict__ Wp, float* __restrict__ Wa)
{
  int idx = blockIdx.x * 256 + threadIdx.x;
  if (idx >= 12288) return;
  const unsigned short *L, *At;
  int l, k, j, t, h;
  if (idx < 8192) {
    l = idx >> 12; int rem = idx & 4095; k = rem >> 4; j = rem & 15;
    if (j < 4)       { t = 1; h = j;      L = lin_src; At = att_src; }
    else if (j < 8)  { t = 2; h = j - 4;  L = lin_src; At = att_src; }
    else if (j < 12) { t = 0; h = j - 8;  L = lin_dst; At = att_dst; }
    else             { t = 1; h = j - 12; L = lin_dst; At = att_dst; }
    int lt = l * 3 + t;
    float s = 0.f;
    for (int c = 0; c < 64; c++)
      s += b2f(L[((size_t)lt * 256 + k) * 256 + h * 64 + c]) * b2f(At[(lt * 4 + h) * 64 + c]);
    Wp[l * 4096 + k * 16 + j] = s;
  } else {
    int i2 = idx - 8192;
    l = i2 >> 11; int rem = i2 & 2047; k = rem >> 3; j = rem & 7;
    if (j < 4) { t = 0; h = j;     L = lin_src; At = att_src; }
    else       { t = 2; h = j - 4; L = lin_dst; At = att_dst; }
    int lt = l * 3 + t;
    float s = 0.f;
    for (int c = 0; c < 64; c++)
      s += b2f(L[((size_t)lt * 256 + k) * 256 + h * 64 + c]) * b2f(At[(lt * 4 + h) * 64 + c]);
    Wa[l * 2048 + k * 8 + j] = s;
  }
}

__global__ void transpose_kernel(const unsigned short* __restrict__ in,
                                 unsigned short* __restrict__ out, int K, int N, int batch)
{
  int idx = blockIdx.x * 256 + threadIdx.x;
  int total = batch * K * N;
  if (idx >= total) return;
  int b = idx / (K * N); int rem = idx % (K * N);
  int k = rem / N; int n = rem % N;
  out[(size_t)b * K * N + (size_t)n * K + k] = in[idx];
}

template <int NCOL>
__global__ __launch_bounds__(256) void al_kernel(const unsigned short* __restrict__ X, int rows,
                                                 const float* __restrict__ W, float* __restrict__ out)
{
  __shared__ __align__(16) float Ws[256 * NCOL];
  for (int i = threadIdx.x; i < 256 * NCOL; i += 256) Ws[i] = W[i];
  __syncthreads();
  int row = blockIdx.x * 256 + threadIdx.x;
  if (row >= rows) return;
  f32x4 acc[NCOL / 4];
#pragma unroll
  for (int jv = 0; jv < NCOL / 4; jv++) { acc[jv][0] = 0.f; acc[jv][1] = 0.f; acc[jv][2] = 0.f; acc[jv][3] = 0.f; }
  const unsigned short* xr = X + (size_t)row * 256;
  for (int k = 0; k < 256; k += 8) {
    uint4 pk = *(const uint4*)(xr + k);
    unsigned int uu[4] = {pk.x, pk.y, pk.z, pk.w};
#pragma unroll
    for (int e2 = 0; e2 < 4; e2++) {
      float x0 = b2f((unsigned short)(uu[e2] & 0xffffu));
      float x1 = b2f((unsigned short)(uu[e2] >> 16));
      int k0 = k + e2 * 2;
#pragma unroll
      for (int jv = 0; jv < NCOL / 4; jv++) {
        const f32x4 w0 = *(const f32x4*)&Ws[k0 * NCOL + jv * 4];
        const f32x4 w1 = *(const f32x4*)&Ws[(k0 + 1) * NCOL + jv * 4];
#pragma unroll
        for (int c = 0; c < 4; c++) acc[jv][c] += x0 * w0[c] + x1 * w1[c];
      }
    }
  }
#pragma unroll
  for (int jv = 0; jv < NCOL / 4; jv++)
    *(f32x4*)&out[(size_t)row * NCOL + jv * 4] = acc[jv];
}

__global__ void hist_kernel(const int* __restrict__ dst, int E, int* __restrict__ deg)
{
  int e = blockIdx.x * 256 + threadIdx.x;
  if (e < E) atomicAdd(&deg[dst[e]], 1);
}

// ---------------- hierarchical scan: 2048 elements per 256-thread block
__global__ __launch_bounds__(256) void scan_partial_kernel(const int* __restrict__ deg, int n,
                                                           int* __restrict__ bsum)
{
  int tid = threadIdx.x;
  int base = blockIdx.x * 2048 + tid * 8;
  int s = 0;
#pragma unroll
  for (int i = 0; i < 8; i++) { int idx = base + i; if (idx < n) s += deg[idx]; }
  __shared__ int red[256];
  red[tid] = s;
  __syncthreads();
  for (int d = 128; d > 0; d >>= 1) {
    if (tid < d) red[tid] += red[tid + d];
    __syncthreads();
  }
  if (tid == 0) bsum[blockIdx.x] = red[0];
}

// one wave; nb <= 64. In-place exclusive scan of block sums.
__global__ void scan_bsum_kernel(int* __restrict__ bsum, int nb)
{
  int lane = threadIdx.x;
  int orig = (lane < nb) ? bsum[lane] : 0;
  int v = orig;
  for (int d = 1; d < 64; d <<= 1) {
    int t = __shfl_up(v, d);
    if (lane >= d) v += t;
  }
  if (lane < nb) bsum[lane] = v - orig;   // exclusive
}

__global__ __launch_bounds__(256) void scan_emit_kernel(const int* __restrict__ deg, int n, int E,
                                                        const int* __restrict__ bsum,
                                                        int* __restrict__ off, int* __restrict__ cur)
{
  int tid = threadIdx.x;
  int base = blockIdx.x * 2048 + tid * 8;
  int vals[8]; int s = 0;
#pragma unroll
  for (int i = 0; i < 8; i++) { int idx = base + i; vals[i] = (idx < n) ? deg[idx] : 0; s += vals[i]; }
  __shared__ int sh[256];
  sh[tid] = s;
  __syncthreads();
  for (int d = 1; d < 256; d <<= 1) {
    int t = (tid >= d) ? sh[tid - d] : 0;
    __syncthreads();
    sh[tid] += t;
    __syncthreads();
  }
  int run = bsum[blockIdx.x] + sh[tid] - s;   // exclusive prefix for this thread's chunk
#pragma unroll
  for (int i = 0; i < 8; i++) {
    int idx = base + i;
    if (idx < n) { off[idx] = run; cur[idx] = run; run += vals[i]; }
  }
  if (blockIdx.x == 0 && tid == 0) off[n] = E;
}

__global__ void scatter_kernel(const int* __restrict__ src, const int* __restrict__ dst, int E,
                               int* __restrict__ cur, int* __restrict__ csr)
{
  int e = blockIdx.x * 256 + threadIdx.x;
  if (e < E) {
    int p = atomicAdd(&cur[dst[e]], 1);
    csr[p] = src[e];
  }
}

__global__ __launch_bounds__(256) void msg_paper_kernel(
    const unsigned short* __restrict__ hs0, const unsigned short* __restrict__ hs1,
    const float* __restrict__ al_p, const float* __restrict__ al_a,
    const int* __restrict__ off0, const int* __restrict__ csr0,
    const int* __restrict__ off1, const int* __restrict__ csr1,
    const unsigned short* __restrict__ bg0, const unsigned short* __restrict__ bg1,
    void* __restrict__ out, const int* __restrict__ flag)
{
  int n = blockIdx.x * 4 + (threadIdx.x >> 6);
  if (n >= NP) return;
  int lane = threadIdx.x & 63;
  int h = lane >> 4;
  int cb = lane * 4;
  float o0 = 0.f, o1 = 0.f, o2 = 0.f, o3 = 0.f;
  {
    float ald = al_p[n * 16 + 8 + h];
    int s = off0[n], e = off0[n + 1];
    float m = -1e30f, denom = 0.f, a0 = 0.f, a1 = 0.f, a2 = 0.f, a3 = 0.f;
    for (int i = s; i < e; i++) {
      int sv = csr0[i];
      float als = al_a[sv * 8 + h];
      float lg = als + ald; lg = lg > 0.f ? lg : 0.2f * lg;
      float mn = lg > m ? lg : m;
      float corr = __expf(m - mn);
      float p = __expf(lg - mn);
      m = mn;
      denom = denom * corr + p;
      const ushort4 hv = *(const ushort4*)(hs0 + (size_t)sv * 256 + cb);
      a0 = a0 * corr + p * b2f(hv.x);
      a1 = a1 * corr + p * b2f(hv.y);
      a2 = a2 * corr + p * b2f(hv.z);
      a3 = a3 * corr + p * b2f(hv.w);
    }
    float inv = denom > 0.f ? 1.f / denom : 0.f;
    o0 += a0 * inv; o1 += a1 * inv; o2 += a2 * inv; o3 += a3 * inv;
  }
  {
    float ald = al_p[n * 16 + 12 + h];
    int s = off1[n], e = off1[n + 1];
    float m = -1e30f, denom = 0.f, a0 = 0.f, a1 = 0.f, a2 = 0.f, a3 = 0.f;
    for (int i = s; i < e; i++) {
      int sv = csr1[i];
      float als = al_p[sv * 16 + h];
      float lg = als + ald; lg = lg > 0.f ? lg : 0.2f * lg;
      float mn = lg > m ? lg : m;
      float corr = __expf(m - mn);
      float p = __expf(lg - mn);
      m = mn;
      denom = denom * corr + p;
      const ushort4 hv = *(const ushort4*)(hs1 + (size_t)sv * 256 + cb);
      a0 = a0 * corr + p * b2f(hv.x);
      a1 = a1 * corr + p * b2f(hv.y);
      a2 = a2 * corr + p * b2f(hv.z);
      a3 = a3 * corr + p * b2f(hv.w);
    }
    float inv = denom > 0.f ? 1.f / denom : 0.f;
    o0 += a0 * inv; o1 += a1 * inv; o2 += a2 * inv; o3 += a3 * inv;
  }
  const ushort4 bv0 = *(const ushort4*)(bg0 + cb);
  const ushort4 bv1 = *(const ushort4*)(bg1 + cb);
  float v0 = o0 + b2f(bv0.x) + b2f(bv1.x); v0 = v0 > 0.f ? v0 : __expf(v0) - 1.f;
  float v1 = o1 + b2f(bv0.y) + b2f(bv1.y); v1 = v1 > 0.f ? v1 : __expf(v1) - 1.f;
  float v2 = o2 + b2f(bv0.z) + b2f(bv1.z); v2 = v2 > 0.f ? v2 : __expf(v2) - 1.f;
  float v3 = o3 + b2f(bv0.w) + b2f(bv1.w); v3 = v3 > 0.f ? v3 : __expf(v3) - 1.f;
  if (flag && *flag) {
    float* of = (float*)out;
    f32x4 ov = {v0, v1, v2, v3};
    *(f32x4*)(of + (size_t)n * 256 + cb) = ov;
  } else {
    unsigned short* ob = (unsigned short*)out;
    ushort4 ov; ov.x = f2b(v0); ov.y = f2b(v1); ov.z = f2b(v2); ov.w = f2b(v3);
    *(ushort4*)(ob + (size_t)n * 256 + cb) = ov;
  }
}

template <int FINAL>
__global__ __launch_bounds__(256) void msg_author_kernel(
    const unsigned short* __restrict__ hs2,
    const float* __restrict__ al_p, const float* __restrict__ al_a,
    const int* __restrict__ off2, const int* __restrict__ csr2,
    const unsigned short* __restrict__ bg2, void* __restrict__ out,
    const int* __restrict__ flag)
{
  int n = blockIdx.x * 4 + (threadIdx.x >> 6);
  if (n >= NA) return;
  int lane = threadIdx.x & 63;
  int h = lane >> 4;
  int cb = lane * 4;
  float ald = al_a[n * 8 + 4 + h];
  int s = off2[n], e = off2[n + 1];
  float m = -1e30f, denom = 0.f, a0 = 0.f, a1 = 0.f, a2 = 0.f, a3 = 0.f;
  for (int i = s; i < e; i++) {
    int sv = csr2[i];
    float als = al_p[sv * 16 + 4 + h];
    float lg = als + ald; lg = lg > 0.f ? lg : 0.2f * lg;
    float mn = lg > m ? lg : m;
    float corr = __expf(m - mn);
    float p = __expf(lg - mn);
    m = mn;
    denom = denom * corr + p;
    const ushort4 hv = *(const ushort4*)(hs2 + (size_t)sv * 256 + cb);
    a0 = a0 * corr + p * b2f(hv.x);
    a1 = a1 * corr + p * b2f(hv.y);
    a2 = a2 * corr + p * b2f(hv.z);
    a3 = a3 * corr + p * b2f(hv.w);
  }
  float inv = denom > 0.f ? 1.f / denom : 0.f;
  const ushort4 bv = *(const ushort4*)(bg2 + cb);
  float v0 = a0 * inv + b2f(bv.x); v0 = v0 > 0.f ? v0 : __expf(v0) - 1.f;
  float v1 = a1 * inv + b2f(bv.y); v1 = v1 > 0.f ? v1 : __expf(v1) - 1.f;
  float v2 = a2 * inv + b2f(bv.z); v2 = v2 > 0.f ? v2 : __expf(v2) - 1.f;
  float v3 = a3 * inv + b2f(bv.w); v3 = v3 > 0.f ? v3 : __expf(v3) - 1.f;
  size_t elem = (size_t)n * 256 + cb + (FINAL ? (size_t)NP * 256 : 0);
  if (FINAL && flag && *flag) {
    float* of = (float*)out;
    f32x4 ov = {v0, v1, v2, v3};
    *(f32x4*)(of + elem) = ov;
  } else {
    unsigned short* ob = (unsigned short*)out;
    ushort4 ov; ov.x = f2b(v0); ov.y = f2b(v1); ov.z = f2b(v2); ov.w = f2b(v3);
    *(ushort4*)(ob + elem) = ov;
  }
}

extern "C" void kernel_launch(void* const* d_in, const int* in_sizes, int n_in,
                              void* d_out, int out_size, void* d_ws, size_t ws_size,
                              hipStream_t stream)
{
  const unsigned short* x_paper  = (const unsigned short*)d_in[0];
  const unsigned short* x_author = (const unsigned short*)d_in[1];
  const unsigned short* W_in_p   = (const unsigned short*)d_in[2];
  const unsigned short* b_in_p   = (const unsigned short*)d_in[3];
  const unsigned short* W_in_a   = (const unsigned short*)d_in[4];
  const unsigned short* b_in_a   = (const unsigned short*)d_in[5];
  const unsigned short* lin_src  = (const unsigned short*)d_in[6];
  const unsigned short* lin_dst  = (const unsigned short*)d_in[7];
  const unsigned short* att_src  = (const unsigned short*)d_in[8];
  const unsigned short* att_dst  = (const unsigned short*)d_in[9];
  const unsigned short* bias_gat = (const unsigned short*)d_in[10];
  const int* writes_src = (const int*)d_in[11];
  const int* writes_dst = (const int*)d_in[12];
  const int* cites_src  = (const int*)d_in[13];
  const int* cites_dst  = (const int*)d_in[14];
  const int* wb_src     = (const int*)d_in[15];
  const int* wb_dst     = (const int*)d_in[16];

  char* base = (char*)d_ws;
  size_t cur = 0;
  auto take = [&](size_t bytes) -> char* {
    char* p = base + cur;
    cur += (bytes + 255) & ~(size_t)255;
    return p;
  };

  int* flag = (int*)take(256);
  unsigned short* cxp   = (unsigned short*)take((size_t)NP * 128 * 2);
  unsigned short* cxa   = (unsigned short*)take((size_t)NA * 128 * 2);
  unsigned short* cWinP = (unsigned short*)take(128 * 256 * 2);
  unsigned short* cWinA = (unsigned short*)take(128 * 256 * 2);
  unsigned short* cbinP = (unsigned short*)take(256 * 2);
  unsigned short* cbinA = (unsigned short*)take(256 * 2);
  unsigned short* clins = (unsigned short*)take((size_t)6 * 65536 * 2);
  unsigned short* clind = (unsigned short*)take((size_t)6 * 65536 * 2);
  unsigned short* catts = (unsigned short*)take(1536 * 2);
  unsigned short* cattd = (unsigned short*)take(1536 * 2);
  unsigned short* cbias = (unsigned short*)take(1536 * 2);

  unsigned short* xp  = (unsigned short*)take((size_t)NP * 256 * 2);
  unsigned short* xa  = (unsigned short*)take((size_t)NA * 256 * 2);
  unsigned short* hs0 = (unsigned short*)take((size_t)NA * 256 * 2);
  unsigned short* hs1 = (unsigned short*)take((size_t)NP * 256 * 2);
  unsigned short* hs2 = (unsigned short*)take((size_t)NP * 256 * 2);
  float* al_p = (float*)take((size_t)NP * 16 * 4);
  float* al_a = (float*)take((size_t)NA * 8 * 4);
  float* Wp   = (float*)take(2 * 256 * 16 * 4);
  float* Wa   = (float*)take(2 * 256 * 8 * 4);
  unsigned short* WinpT = (unsigned short*)take(256 * 128 * 2);
  unsigned short* WinaT = (unsigned short*)take(256 * 128 * 2);
  unsigned short* linsT = (unsigned short*)take((size_t)6 * 65536 * 2);
  int* off0 = (int*)take((size_t)(NP + 1) * 4);
  int* cur0 = (int*)take((size_t)NP * 4);
  int* csr0 = (int*)take((size_t)NE * 4);
  int* off1 = (int*)take((size_t)(NP + 1) * 4);
  int* cur1 = (int*)take((size_t)NP * 4);
  int* csr1 = (int*)take((size_t)NE * 4);
  int* off2 = (int*)take((size_t)(NA + 1) * 4);
  int* cur2 = (int*)take((size_t)NA * 4);
  int* csr2 = (int*)take((size_t)NE * 4);
  int* deg0 = (int*)take((size_t)NP * 4);
  int* deg1 = (int*)take((size_t)NP * 4);
  int* deg2 = (int*)take((size_t)NA * 4);
  int* bsum0 = (int*)take(64 * 4);
  int* bsum1 = (int*)take(64 * 4);
  int* bsum2 = (int*)take(64 * 4);

  probe_kernel<<<1, 256, 0, stream>>>(x_paper, flag);

  auto conv = [&](const unsigned short* s, unsigned short* d, int n) {
    conv_kernel<<<(n + 255) / 256, 256, 0, stream>>>(s, d, n, flag);
  };
  conv(x_paper, cxp, NP * 128);
  conv(x_author, cxa, NA * 128);
  conv(W_in_p, cWinP, 128 * 256);
  conv(W_in_a, cWinA, 128 * 256);
  conv(b_in_p, cbinP, 256);
  conv(b_in_a, cbinA, 256);
  conv(lin_src, clins, 6 * 65536);
  conv(lin_dst, clind, 6 * 65536);
  conv(att_src, catts, 1536);
  conv(att_dst, cattd, 1536);
  conv(bias_gat, cbias, 1536);

  hipMemsetAsync(deg0, 0, (size_t)NP * 4, stream);
  hipMemsetAsync(deg1, 0, (size_t)NP * 4, stream);
  hipMemsetAsync(deg2, 0, (size_t)NA * 4, stream);

  fold_kernel<<<48, 256, 0, stream>>>(clins, clind, catts, cattd, Wp, Wa);
  transpose_kernel<<<(6 * 65536) / 256, 256, 0, stream>>>(clins, linsT, 256, 256, 6);
  transpose_kernel<<<(128 * 256) / 256, 256, 0, stream>>>(cWinP, WinpT, 128, 256, 1);
  transpose_kernel<<<(128 * 256) / 256, 256, 0, stream>>>(cWinA, WinaT, 128, 256, 1);

  hist_kernel<<<(NE + 255) / 256, 256, 0, stream>>>(writes_dst, NE, deg0);
  hist_kernel<<<(NE + 255) / 256, 256, 0, stream>>>(cites_dst, NE, deg1);
  hist_kernel<<<(NE + 255) / 256, 256, 0, stream>>>(wb_dst, NE, deg2);

  const int nbP = (NP + 2047) / 2048;   // 49
  const int nbA = (NA + 2047) / 2048;   // 25
  scan_partial_kernel<<<nbP, 256, 0, stream>>>(deg0, NP, bsum0);
  scan_partial_kernel<<<nbP, 256, 0, stream>>>(deg1, NP, bsum1);
  scan_partial_kernel<<<nbA, 256, 0, stream>>>(deg2, NA, bsum2);
  scan_bsum_kernel<<<1, 64, 0, stream>>>(bsum0, nbP);
  scan_bsum_kernel<<<1, 64, 0, stream>>>(bsum1, nbP);
  scan_bsum_kernel<<<1, 64, 0, stream>>>(bsum2, nbA);
  scan_emit_kernel<<<nbP, 256, 0, stream>>>(deg0, NP, NE, bsum0, off0, cur0);
  scan_emit_kernel<<<nbP, 256, 0, stream>>>(deg1, NP, NE, bsum1, off1, cur1);
  scan_emit_kernel<<<nbA, 256, 0, stream>>>(deg2, NA, NE, bsum2, off2, cur2);

  scatter_kernel<<<(NE + 255) / 256, 256, 0, stream>>>(writes_src, writes_dst, NE, cur0, csr0);
  scatter_kernel<<<(NE + 255) / 256, 256, 0, stream>>>(cites_src, cites_dst, NE, cur1, csr1);
  scatter_kernel<<<(NE + 255) / 256, 256, 0, stream>>>(wb_src, wb_dst, NE, cur2, csr2);

  gemm256<1><<<dim3((NP + 127) / 128, 2), 256, 0, stream>>>(cxp, WinpT, xp, NP, 128, cbinP);
  gemm256<1><<<dim3((NA + 127) / 128, 2), 256, 0, stream>>>(cxa, WinaT, xa, NA, 128, cbinA);

  for (int l = 0; l < 2; ++l) {
    gemm256<0><<<dim3((NA + 127) / 128, 2), 256, 0, stream>>>(xa, linsT + (size_t)(l * 3 + 0) * 65536, hs0, NA, 256, nullptr);
    gemm256<0><<<dim3((NP + 127) / 128, 2), 256, 0, stream>>>(xp, linsT + (size_t)(l * 3 + 1) * 65536, hs1, NP, 256, nullptr);
    gemm256<0><<<dim3((NP + 127) / 128, 2), 256, 0, stream>>>(xp, linsT + (size_t)(l * 3 + 2) * 65536, hs2, NP, 256, nullptr);
    al_kernel<16><<<(NP + 255) / 256, 256, 0, stream>>>(xp, NP, Wp + l * 4096, al_p);
    al_kernel<8><<<(NA + 255) / 256, 256, 0, stream>>>(xa, NA, Wa + l * 2048, al_a);
    if (l == 0) {
      msg_paper_kernel<<<NP / 4, 256, 0, stream>>>(hs0, hs1, al_p, al_a, off0, csr0, off1, csr1,
          cbias + 0 * 256, cbias + 1 * 256, xp, nullptr);
      msg_author_kernel<0><<<NA / 4, 256, 0, stream>>>(hs2, al_p, al_a, off2, csr2,
          cbias + 2 * 256, xa, nullptr);
    } else {
      msg_paper_kernel<<<NP / 4, 256, 0, stream>>>(hs0, hs1, al_p, al_a, off0, csr0, off1, csr1,
          cbias + 3 * 256, cbias + 4 * 256, d_out, flag);
      msg_author_kernel<1><<<NA / 4, 256, 0, stream>>>(hs2, al_p, al_a, off2, csr2,
          cbias + 5 * 256, d_out, flag);
    }
  }
}

// Round 2
// 1149.929 us; speedup vs baseline: 1.0891x; 1.0891x over previous
//
#include <hip/hip_runtime.h>

// HeteroGAT on MI355X. Round 5:
//  - msg kernels: 4-wide edge batching (4 outstanding row-gathers per wave,
//    one softmax rescale per batch) to lift random-gather BW per Little's law.
//  - fused conv (11->1), hist (3->1), scatter (3->1), scan phases (3->1 each),
//    single deg memset. Everything else identical to the 1252us pipeline.

#define NP 100000
#define NA 50000
#define NE 250000

typedef __attribute__((ext_vector_type(8))) short short8;
typedef __attribute__((ext_vector_type(4))) float f32x4;

__device__ __forceinline__ float b2f(unsigned short u) {
  union { unsigned int i; float f; } v; v.i = ((unsigned int)u) << 16; return v.f;
}
__device__ __forceinline__ unsigned short f2b(float f) {
  union { float f; unsigned int i; } v; v.f = f;
  unsigned int u = v.i;
  return (unsigned short)((u + 0x7fffu + ((u >> 16) & 1u)) >> 16);
}

__global__ void probe_kernel(const unsigned short* __restrict__ x, int* __restrict__ flag)
{
  __shared__ int cnt;
  if (threadIdx.x == 0) cnt = 0;
  __syncthreads();
  int c = 0;
  for (int i = threadIdx.x; i < 4096; i += 256) {
    unsigned int e = (x[i] >> 7) & 0xFFu;
    if (e >= 0xC0u) c++;
  }
  atomicAdd(&cnt, c);
  __syncthreads();
  if (threadIdx.x == 0) *flag = (cnt > 64) ? 1 : 0;   // 1 = inputs are fp32
}

// ---- fused bf16-conversion of all 11 input tensors in one launch ----
#define CV_E0 12800000LL
#define CV_E1 19200000LL
#define CV_E2 19232768LL
#define CV_E3 19265536LL
#define CV_E4 19265792LL
#define CV_E5 19266048LL
#define CV_E6 19659264LL
#define CV_E7 20052480LL
#define CV_E8 20054016LL
#define CV_E9 20055552LL
#define CV_E10 20057088LL

__global__ void conv_all_kernel(
    const unsigned short* __restrict__ s0, unsigned short* __restrict__ d0,
    const unsigned short* __restrict__ s1, unsigned short* __restrict__ d1,
    const unsigned short* __restrict__ s2, unsigned short* __restrict__ d2,
    const unsigned short* __restrict__ s3, unsigned short* __restrict__ d3,
    const unsigned short* __restrict__ s4, unsigned short* __restrict__ d4,
    const unsigned short* __restrict__ s5, unsigned short* __restrict__ d5,
    const unsigned short* __restrict__ s6, unsigned short* __restrict__ d6,
    const unsigned short* __restrict__ s7, unsigned short* __restrict__ d7,
    const unsigned short* __restrict__ s8, unsigned short* __restrict__ d8,
    const unsigned short* __restrict__ s9, unsigned short* __restrict__ d9,
    const unsigned short* __restrict__ s10, unsigned short* __restrict__ d10,
    const int* __restrict__ flag)
{
  long long idx = (long long)blockIdx.x * 256 + threadIdx.x;
  if (idx >= CV_E10) return;
  int f = *flag;
  const unsigned short* s; unsigned short* d; long long off;
  if (idx < CV_E0)      { s = s0;  d = d0;  off = idx; }
  else if (idx < CV_E1) { s = s1;  d = d1;  off = idx - CV_E0; }
  else if (idx < CV_E2) { s = s2;  d = d2;  off = idx - CV_E1; }
  else if (idx < CV_E3) { s = s3;  d = d3;  off = idx - CV_E2; }
  else if (idx < CV_E4) { s = s4;  d = d4;  off = idx - CV_E3; }
  else if (idx < CV_E5) { s = s5;  d = d5;  off = idx - CV_E4; }
  else if (idx < CV_E6) { s = s6;  d = d6;  off = idx - CV_E5; }
  else if (idx < CV_E7) { s = s7;  d = d7;  off = idx - CV_E6; }
  else if (idx < CV_E8) { s = s8;  d = d8;  off = idx - CV_E7; }
  else if (idx < CV_E9) { s = s9;  d = d9;  off = idx - CV_E8; }
  else                  { s = s10; d = d10; off = idx - CV_E9; }
  if (f) d[off] = f2b(((const float*)s)[off]);
  else   d[off] = s[off];
}

template <int RELU>
__global__ __launch_bounds__(256) void gemm256(
    const unsigned short* __restrict__ A, const unsigned short* __restrict__ BT,
    unsigned short* __restrict__ C, int M, int K, const unsigned short* __restrict__ bias)
{
  __shared__ __align__(16) unsigned short As[128 * 64];
  __shared__ __align__(16) unsigned short Bs[128 * 64];
  const int t = threadIdx.x;
  const int lane = t & 63;
  const int w = t >> 6;
  const int wr = w >> 1, wc = w & 1;
  const int quad = lane >> 4;
  const int l16 = lane & 15;
  const int m0 = blockIdx.x * 128;
  const int n0 = blockIdx.y * 128;

  f32x4 acc[4][4];
#pragma unroll
  for (int i = 0; i < 4; i++)
#pragma unroll
    for (int j = 0; j < 4; j++) { acc[i][j][0] = 0.f; acc[i][j][1] = 0.f; acc[i][j][2] = 0.f; acc[i][j][3] = 0.f; }

  const int nkc = K >> 6;
  for (int kc = 0; kc < nkc; ++kc) {
    uint4 av[4], bv[4];
#pragma unroll
    for (int i = 0; i < 4; i++) {
      int chunk = i * 256 + t;
      int r = chunk >> 3, c8 = chunk & 7;
      int gr = m0 + r; gr = gr < M ? gr : (M - 1);
      av[i] = *(const uint4*)(A + (size_t)gr * K + (kc * 64 + c8 * 8));
      bv[i] = *(const uint4*)(BT + (size_t)(n0 + r) * K + (kc * 64 + c8 * 8));
    }
    __syncthreads();
#pragma unroll
    for (int i = 0; i < 4; i++) {
      int chunk = i * 256 + t;
      *(uint4*)(As + chunk * 8) = av[i];
      *(uint4*)(Bs + chunk * 8) = bv[i];
    }
    __syncthreads();
#pragma unroll
    for (int ks = 0; ks < 2; ++ks) {
      short8 af[4], bq[4];
#pragma unroll
      for (int i = 0; i < 4; i++)
        af[i] = *(const short8*)(As + (wr * 64 + i * 16 + l16) * 64 + ks * 32 + quad * 8);
#pragma unroll
      for (int j = 0; j < 4; j++)
        bq[j] = *(const short8*)(Bs + (wc * 64 + j * 16 + l16) * 64 + ks * 32 + quad * 8);
#pragma unroll
      for (int i = 0; i < 4; i++)
#pragma unroll
        for (int j = 0; j < 4; j++)
          acc[i][j] = __builtin_amdgcn_mfma_f32_16x16x32_bf16(af[i], bq[j], acc[i][j], 0, 0, 0);
    }
  }
#pragma unroll
  for (int j = 0; j < 4; j++) {
    int col = n0 + wc * 64 + j * 16 + l16;
    float bv2 = bias ? b2f(bias[col]) : 0.f;
#pragma unroll
    for (int i = 0; i < 4; i++) {
      int rbase = m0 + wr * 64 + i * 16 + quad * 4;
#pragma unroll
      for (int r = 0; r < 4; r++) {
        int row = rbase + r;
        if (row < M) {
          float v = acc[i][j][r] + bv2;
          if (RELU) v = v > 0.f ? v : 0.f;
          C[(size_t)row * 256 + col] = f2b(v);
        }
      }
    }
  }
}

// Wp cols: 0-3 al_s(t=1), 4-7 al_s(t=2), 8-11 al_d(t=0), 12-15 al_d(t=1)
// Wa cols: 0-3 al_s(t=0), 4-7 al_d(t=2)
__global__ void fold_kernel(const unsigned short* __restrict__ lin_src,
                            const unsigned short* __restrict__ lin_dst,
                            const unsigned short* __restrict__ att_src,
                            const unsigned short* __restrict__ att_dst,
                            float* __restrict__ Wp, float* __restrict__ Wa)
{
  int idx = blockIdx.x * 256 + threadIdx.x;
  if (idx >= 12288) return;
  const unsigned short *L, *At;
  int l, k, j, t, h;
  if (idx < 8192) {
    l = idx >> 12; int rem = idx & 4095; k = rem >> 4; j = rem & 15;
    if (j < 4)       { t = 1; h = j;      L = lin_src; At = att_src; }
    else if (j < 8)  { t = 2; h = j - 4;  L = lin_src; At = att_src; }
    else if (j < 12) { t = 0; h = j - 8;  L = lin_dst; At = att_dst; }
    else             { t = 1; h = j - 12; L = lin_dst; At = att_dst; }
    int lt = l * 3 + t;
    float s = 0.f;
    for (int c = 0; c < 64; c++)
      s += b2f(L[((size_t)lt * 256 + k) * 256 + h * 64 + c]) * b2f(At[(lt * 4 + h) * 64 + c]);
    Wp[l * 4096 + k * 16 + j] = s;
  } else {
    int i2 = idx - 8192;
    l = i2 >> 11; int rem = i2 & 2047; k = rem >> 3; j = rem & 7;
    if (j < 4) { t = 0; h = j;     L = lin_src; At = att_src; }
    else       { t = 2; h = j - 4; L = lin_dst; At = att_dst; }
    int lt = l * 3 + t;
    float s = 0.f;
    for (int c = 0; c < 64; c++)
      s += b2f(L[((size_t)lt * 256 + k) * 256 + h * 64 + c]) * b2f(At[(lt * 4 + h) * 64 + c]);
    Wa[l * 2048 + k * 8 + j] = s;
  }
}

__global__ void transpose_kernel(const unsigned short* __restrict__ in,
                                 unsigned short* __restrict__ out, int K, int N, int batch)
{
  int idx = blockIdx.x * 256 + threadIdx.x;
  int total = batch * K * N;
  if (idx >= total) return;
  int b = idx / (K * N); int rem = idx % (K * N);
  int k = rem / N; int n = rem % N;
  out[(size_t)b * K * N + (size_t)n * K + k] = in[idx];
}

template <int NCOL>
__global__ __launch_bounds__(256) void al_kernel(const unsigned short* __restrict__ X, int rows,
                                                 const float* __restrict__ W, float* __restrict__ out)
{
  __shared__ __align__(16) float Ws[256 * NCOL];
  for (int i = threadIdx.x; i < 256 * NCOL; i += 256) Ws[i] = W[i];
  __syncthreads();
  int row = blockIdx.x * 256 + threadIdx.x;
  if (row >= rows) return;
  f32x4 acc[NCOL / 4];
#pragma unroll
  for (int jv = 0; jv < NCOL / 4; jv++) { acc[jv][0] = 0.f; acc[jv][1] = 0.f; acc[jv][2] = 0.f; acc[jv][3] = 0.f; }
  const unsigned short* xr = X + (size_t)row * 256;
  for (int k = 0; k < 256; k += 8) {
    uint4 pk = *(const uint4*)(xr + k);
    unsigned int uu[4] = {pk.x, pk.y, pk.z, pk.w};
#pragma unroll
    for (int e2 = 0; e2 < 4; e2++) {
      float x0 = b2f((unsigned short)(uu[e2] & 0xffffu));
      float x1 = b2f((unsigned short)(uu[e2] >> 16));
      int k0 = k + e2 * 2;
#pragma unroll
      for (int jv = 0; jv < NCOL / 4; jv++) {
        const f32x4 w0 = *(const f32x4*)&Ws[k0 * NCOL + jv * 4];
        const f32x4 w1 = *(const f32x4*)&Ws[(k0 + 1) * NCOL + jv * 4];
#pragma unroll
        for (int c = 0; c < 4; c++) acc[jv][c] += x0 * w0[c] + x1 * w1[c];
      }
    }
  }
#pragma unroll
  for (int jv = 0; jv < NCOL / 4; jv++)
    *(f32x4*)&out[(size_t)row * NCOL + jv * 4] = acc[jv];
}

__global__ void hist3_kernel(const int* __restrict__ wdst, const int* __restrict__ cdst,
                             const int* __restrict__ adst,
                             int* __restrict__ deg0, int* __restrict__ deg1, int* __restrict__ deg2)
{
  int idx = blockIdx.x * 256 + threadIdx.x;
  if (idx < NE)          atomicAdd(&deg0[wdst[idx]], 1);
  else if (idx < 2 * NE) atomicAdd(&deg1[cdst[idx - NE]], 1);
  else if (idx < 3 * NE) atomicAdd(&deg2[adst[idx - 2 * NE]], 1);
}

// ---------------- hierarchical scan, 3 edge-types per launch via blockIdx.y
__global__ __launch_bounds__(256) void scan_partial3(const int* __restrict__ deg0,
                                                     const int* __restrict__ deg1,
                                                     const int* __restrict__ deg2,
                                                     int* __restrict__ b0, int* __restrict__ b1,
                                                     int* __restrict__ b2)
{
  const int* deg; int n; int* bs;
  if (blockIdx.y == 0)      { deg = deg0; n = NP; bs = b0; }
  else if (blockIdx.y == 1) { deg = deg1; n = NP; bs = b1; }
  else                      { deg = deg2; n = NA; bs = b2; }
  if ((int)blockIdx.x * 2048 >= n) return;
  int tid = threadIdx.x;
  int base = blockIdx.x * 2048 + tid * 8;
  int s = 0;
#pragma unroll
  for (int i = 0; i < 8; i++) { int idx = base + i; if (idx < n) s += deg[idx]; }
  __shared__ int red[256];
  red[tid] = s;
  __syncthreads();
  for (int d = 128; d > 0; d >>= 1) {
    if (tid < d) red[tid] += red[tid + d];
    __syncthreads();
  }
  if (tid == 0) bs[blockIdx.x] = red[0];
}

// three blocks, one wave each; nb <= 64. In-place exclusive scan of block sums.
__global__ void scan_bsum3(int* __restrict__ b0, int* __restrict__ b1, int* __restrict__ b2,
                           int nb0, int nb1, int nb2)
{
  int* bsum; int nb;
  if (blockIdx.x == 0)      { bsum = b0; nb = nb0; }
  else if (blockIdx.x == 1) { bsum = b1; nb = nb1; }
  else                      { bsum = b2; nb = nb2; }
  int lane = threadIdx.x;
  int orig = (lane < nb) ? bsum[lane] : 0;
  int v = orig;
  for (int d = 1; d < 64; d <<= 1) {
    int t = __shfl_up(v, d);
    if (lane >= d) v += t;
  }
  if (lane < nb) bsum[lane] = v - orig;   // exclusive
}

__global__ __launch_bounds__(256) void scan_emit3(const int* __restrict__ deg0,
                                                  const int* __restrict__ deg1,
                                                  const int* __restrict__ deg2,
                                                  const int* __restrict__ b0,
                                                  const int* __restrict__ b1,
                                                  const int* __restrict__ b2,
                                                  int* __restrict__ off0a, int* __restrict__ cur0a,
                                                  int* __restrict__ off1a, int* __restrict__ cur1a,
                                                  int* __restrict__ off2a, int* __restrict__ cur2a)
{
  const int* deg; int n; const int* bsum; int* off; int* cur;
  if (blockIdx.y == 0)      { deg = deg0; n = NP; bsum = b0; off = off0a; cur = cur0a; }
  else if (blockIdx.y == 1) { deg = deg1; n = NP; bsum = b1; off = off1a; cur = cur1a; }
  else                      { deg = deg2; n = NA; bsum = b2; off = off2a; cur = cur2a; }
  if ((int)blockIdx.x * 2048 >= n) return;
  int tid = threadIdx.x;
  int base = blockIdx.x * 2048 + tid * 8;
  int vals[8]; int s = 0;
#pragma unroll
  for (int i = 0; i < 8; i++) { int idx = base + i; vals[i] = (idx < n) ? deg[idx] : 0; s += vals[i]; }
  __shared__ int sh[256];
  sh[tid] = s;
  __syncthreads();
  for (int d = 1; d < 256; d <<= 1) {
    int t = (tid >= d) ? sh[tid - d] : 0;
    __syncthreads();
    sh[tid] += t;
    __syncthreads();
  }
  int run = bsum[blockIdx.x] + sh[tid] - s;   // exclusive prefix for this thread's chunk
#pragma unroll
  for (int i = 0; i < 8; i++) {
    int idx = base + i;
    if (idx < n) { off[idx] = run; cur[idx] = run; run += vals[i]; }
  }
  if (blockIdx.x == 0 && tid == 0) off[n] = NE;
}

__global__ void scatter3_kernel(const int* __restrict__ ws, const int* __restrict__ wd,
                                const int* __restrict__ cs, const int* __restrict__ cd,
                                const int* __restrict__ as, const int* __restrict__ ad,
                                int* __restrict__ cur0, int* __restrict__ cur1, int* __restrict__ cur2,
                                int* __restrict__ csr0, int* __restrict__ csr1, int* __restrict__ csr2)
{
  int idx = blockIdx.x * 256 + threadIdx.x;
  if (idx < NE) {
    int p = atomicAdd(&cur0[wd[idx]], 1); csr0[p] = ws[idx];
  } else if (idx < 2 * NE) {
    int e = idx - NE;
    int p = atomicAdd(&cur1[cd[e]], 1); csr1[p] = cs[e];
  } else if (idx < 3 * NE) {
    int e = idx - 2 * NE;
    int p = atomicAdd(&cur2[ad[e]], 1); csr2[p] = as[e];
  }
}

// 4-wide-batched online-softmax GAT accumulation over one CSR list.
// Pads a partial batch by duplicating the last edge (valid address); padded
// lanes get lg=-1e30 -> p=0 -> zero contribution. One rescale per batch.
template <int STRIDE>
__device__ __forceinline__ void gat_accum(const unsigned short* __restrict__ hs,
                                          const float* __restrict__ alsb,
                                          const int* __restrict__ csr,
                                          int s, int e, float ald, int cb,
                                          float& o0, float& o1, float& o2, float& o3)
{
  if (s >= e) return;
  float m = -1e30f, denom = 0.f, a0 = 0.f, a1 = 0.f, a2 = 0.f, a3 = 0.f;
  for (int i = s; i < e; i += 4) {
    int svv[4];
#pragma unroll
    for (int j = 0; j < 4; j++) {
      int idx = (i + j < e) ? (i + j) : (e - 1);
      svv[j] = csr[idx];
    }
    float lg[4]; ushort4 hv[4];
#pragma unroll
    for (int j = 0; j < 4; j++) {
      float als = alsb[(size_t)svv[j] * STRIDE];
      hv[j] = *(const ushort4*)(hs + (size_t)svv[j] * 256 + cb);
      float l = als + ald;
      l = l > 0.f ? l : 0.2f * l;
      lg[j] = (i + j < e) ? l : -1e30f;
    }
    float mb = fmaxf(fmaxf(lg[0], lg[1]), fmaxf(lg[2], lg[3]));
    float mn = fmaxf(m, mb);
    float corr = __expf(m - mn);
    m = mn;
    denom *= corr; a0 *= corr; a1 *= corr; a2 *= corr; a3 *= corr;
#pragma unroll
    for (int j = 0; j < 4; j++) {
      float p = __expf(lg[j] - mn);
      denom += p;
      a0 += p * b2f(hv[j].x);
      a1 += p * b2f(hv[j].y);
      a2 += p * b2f(hv[j].z);
      a3 += p * b2f(hv[j].w);
    }
  }
  float inv = denom > 0.f ? 1.f / denom : 0.f;
  o0 += a0 * inv; o1 += a1 * inv; o2 += a2 * inv; o3 += a3 * inv;
}

__global__ __launch_bounds__(256) void msg_paper_kernel(
    const unsigned short* __restrict__ hs0, const unsigned short* __restrict__ hs1,
    const float* __restrict__ al_p, const float* __restrict__ al_a,
    const int* __restrict__ off0, const int* __restrict__ csr0,
    const int* __restrict__ off1, const int* __restrict__ csr1,
    const unsigned short* __restrict__ bg0, const unsigned short* __restrict__ bg1,
    void* __restrict__ out, const int* __restrict__ flag)
{
  int n = blockIdx.x * 4 + (threadIdx.x >> 6);
  if (n >= NP) return;
  int lane = threadIdx.x & 63;
  int h = lane >> 4;
  int cb = lane * 4;
  float o0 = 0.f, o1 = 0.f, o2 = 0.f, o3 = 0.f;
  gat_accum<8>(hs0, al_a + h, csr0, off0[n], off0[n + 1], al_p[n * 16 + 8 + h], cb,
               o0, o1, o2, o3);
  gat_accum<16>(hs1, al_p + h, csr1, off1[n], off1[n + 1], al_p[n * 16 + 12 + h], cb,
                o0, o1, o2, o3);
  const ushort4 bv0 = *(const ushort4*)(bg0 + cb);
  const ushort4 bv1 = *(const ushort4*)(bg1 + cb);
  float v0 = o0 + b2f(bv0.x) + b2f(bv1.x); v0 = v0 > 0.f ? v0 : __expf(v0) - 1.f;
  float v1 = o1 + b2f(bv0.y) + b2f(bv1.y); v1 = v1 > 0.f ? v1 : __expf(v1) - 1.f;
  float v2 = o2 + b2f(bv0.z) + b2f(bv1.z); v2 = v2 > 0.f ? v2 : __expf(v2) - 1.f;
  float v3 = o3 + b2f(bv0.w) + b2f(bv1.w); v3 = v3 > 0.f ? v3 : __expf(v3) - 1.f;
  if (flag && *flag) {
    float* of = (float*)out;
    f32x4 ov = {v0, v1, v2, v3};
    *(f32x4*)(of + (size_t)n * 256 + cb) = ov;
  } else {
    unsigned short* ob = (unsigned short*)out;
    ushort4 ov; ov.x = f2b(v0); ov.y = f2b(v1); ov.z = f2b(v2); ov.w = f2b(v3);
    *(ushort4*)(ob + (size_t)n * 256 + cb) = ov;
  }
}

template <int FINAL>
__global__ __launch_bounds__(256) void msg_author_kernel(
    const unsigned short* __restrict__ hs2,
    const float* __restrict__ al_p, const float* __restrict__ al_a,
    const int* __restrict__ off2, const int* __restrict__ csr2,
    const unsigned short* __restrict__ bg2, void* __restrict__ out,
    const int* __restrict__ flag)
{
  int n = blockIdx.x * 4 + (threadIdx.x >> 6);
  if (n >= NA) return;
  int lane = threadIdx.x & 63;
  int h = lane >> 4;
  int cb = lane * 4;
  float o0 = 0.f, o1 = 0.f, o2 = 0.f, o3 = 0.f;
  gat_accum<16>(hs2, al_p + 4 + h, csr2, off2[n], off2[n + 1], al_a[n * 8 + 4 + h], cb,
                o0, o1, o2, o3);
  const ushort4 bv = *(const ushort4*)(bg2 + cb);
  float v0 = o0 + b2f(bv.x); v0 = v0 > 0.f ? v0 : __expf(v0) - 1.f;
  float v1 = o1 + b2f(bv.y); v1 = v1 > 0.f ? v1 : __expf(v1) - 1.f;
  float v2 = o2 + b2f(bv.z); v2 = v2 > 0.f ? v2 : __expf(v2) - 1.f;
  float v3 = o3 + b2f(bv.w); v3 = v3 > 0.f ? v3 : __expf(v3) - 1.f;
  size_t elem = (size_t)n * 256 + cb + (FINAL ? (size_t)NP * 256 : 0);
  if (FINAL && flag && *flag) {
    float* of = (float*)out;
    f32x4 ov = {v0, v1, v2, v3};
    *(f32x4*)(of + elem) = ov;
  } else {
    unsigned short* ob = (unsigned short*)out;
    ushort4 ov; ov.x = f2b(v0); ov.y = f2b(v1); ov.z = f2b(v2); ov.w = f2b(v3);
    *(ushort4*)(ob + elem) = ov;
  }
}

extern "C" void kernel_launch(void* const* d_in, const int* in_sizes, int n_in,
                              void* d_out, int out_size, void* d_ws, size_t ws_size,
                              hipStream_t stream)
{
  const unsigned short* x_paper  = (const unsigned short*)d_in[0];
  const unsigned short* x_author = (const unsigned short*)d_in[1];
  const unsigned short* W_in_p   = (const unsigned short*)d_in[2];
  const unsigned short* b_in_p   = (const unsigned short*)d_in[3];
  const unsigned short* W_in_a   = (const unsigned short*)d_in[4];
  const unsigned short* b_in_a   = (const unsigned short*)d_in[5];
  const unsigned short* lin_src  = (const unsigned short*)d_in[6];
  const unsigned short* lin_dst  = (const unsigned short*)d_in[7];
  const unsigned short* att_src  = (const unsigned short*)d_in[8];
  const unsigned short* att_dst  = (const unsigned short*)d_in[9];
  const unsigned short* bias_gat = (const unsigned short*)d_in[10];
  const int* writes_src = (const int*)d_in[11];
  const int* writes_dst = (const int*)d_in[12];
  const int* cites_src  = (const int*)d_in[13];
  const int* cites_dst  = (const int*)d_in[14];
  const int* wb_src     = (const int*)d_in[15];
  const int* wb_dst     = (const int*)d_in[16];

  char* base = (char*)d_ws;
  size_t cur = 0;
  auto take = [&](size_t bytes) -> char* {
    char* p = base + cur;
    cur += (bytes + 255) & ~(size_t)255;
    return p;
  };

  int* flag = (int*)take(256);
  unsigned short* cxp   = (unsigned short*)take((size_t)NP * 128 * 2);
  unsigned short* cxa   = (unsigned short*)take((size_t)NA * 128 * 2);
  unsigned short* cWinP = (unsigned short*)take(128 * 256 * 2);
  unsigned short* cWinA = (unsigned short*)take(128 * 256 * 2);
  unsigned short* cbinP = (unsigned short*)take(256 * 2);
  unsigned short* cbinA = (unsigned short*)take(256 * 2);
  unsigned short* clins = (unsigned short*)take((size_t)6 * 65536 * 2);
  unsigned short* clind = (unsigned short*)take((size_t)6 * 65536 * 2);
  unsigned short* catts = (unsigned short*)take(1536 * 2);
  unsigned short* cattd = (unsigned short*)take(1536 * 2);
  unsigned short* cbias = (unsigned short*)take(1536 * 2);

  unsigned short* xp  = (unsigned short*)take((size_t)NP * 256 * 2);
  unsigned short* xa  = (unsigned short*)take((size_t)NA * 256 * 2);
  unsigned short* hs0 = (unsigned short*)take((size_t)NA * 256 * 2);
  unsigned short* hs1 = (unsigned short*)take((size_t)NP * 256 * 2);
  unsigned short* hs2 = (unsigned short*)take((size_t)NP * 256 * 2);
  float* al_p = (float*)take((size_t)NP * 16 * 4);
  float* al_a = (float*)take((size_t)NA * 8 * 4);
  float* Wp   = (float*)take(2 * 256 * 16 * 4);
  float* Wa   = (float*)take(2 * 256 * 8 * 4);
  unsigned short* WinpT = (unsigned short*)take(256 * 128 * 2);
  unsigned short* WinaT = (unsigned short*)take(256 * 128 * 2);
  unsigned short* linsT = (unsigned short*)take((size_t)6 * 65536 * 2);
  int* off0 = (int*)take((size_t)(NP + 1) * 4);
  int* cur0 = (int*)take((size_t)NP * 4);
  int* csr0 = (int*)take((size_t)NE * 4);
  int* off1 = (int*)take((size_t)(NP + 1) * 4);
  int* cur1 = (int*)take((size_t)NP * 4);
  int* csr1 = (int*)take((size_t)NE * 4);
  int* off2 = (int*)take((size_t)(NA + 1) * 4);
  int* cur2 = (int*)take((size_t)NA * 4);
  int* csr2 = (int*)take((size_t)NE * 4);
  int* degAll = (int*)take((size_t)(2 * NP + NA) * 4);
  int* deg0 = degAll;
  int* deg1 = degAll + NP;
  int* deg2 = degAll + 2 * NP;
  int* bsum0 = (int*)take(64 * 4);
  int* bsum1 = (int*)take(64 * 4);
  int* bsum2 = (int*)take(64 * 4);

  probe_kernel<<<1, 256, 0, stream>>>(x_paper, flag);

  const long long CVN = (CV_E10 + 255) / 256;
  conv_all_kernel<<<(unsigned)CVN, 256, 0, stream>>>(
      x_paper, cxp, x_author, cxa, W_in_p, cWinP, W_in_a, cWinA,
      b_in_p, cbinP, b_in_a, cbinA, lin_src, clins, lin_dst, clind,
      att_src, catts, att_dst, cattd, bias_gat, cbias, flag);

  hipMemsetAsync(degAll, 0, (size_t)(2 * NP + NA) * 4, stream);

  fold_kernel<<<48, 256, 0, stream>>>(clins, clind, catts, cattd, Wp, Wa);
  transpose_kernel<<<(6 * 65536) / 256, 256, 0, stream>>>(clins, linsT, 256, 256, 6);
  transpose_kernel<<<(128 * 256) / 256, 256, 0, stream>>>(cWinP, WinpT, 128, 256, 1);
  transpose_kernel<<<(128 * 256) / 256, 256, 0, stream>>>(cWinA, WinaT, 128, 256, 1);

  hist3_kernel<<<(3 * NE + 255) / 256, 256, 0, stream>>>(writes_dst, cites_dst, wb_dst,
                                                         deg0, deg1, deg2);

  const int nbP = (NP + 2047) / 2048;   // 49
  const int nbA = (NA + 2047) / 2048;   // 25
  scan_partial3<<<dim3(nbP, 3), 256, 0, stream>>>(deg0, deg1, deg2, bsum0, bsum1, bsum2);
  scan_bsum3<<<3, 64, 0, stream>>>(bsum0, bsum1, bsum2, nbP, nbP, nbA);
  scan_emit3<<<dim3(nbP, 3), 256, 0, stream>>>(deg0, deg1, deg2, bsum0, bsum1, bsum2,
                                               off0, cur0, off1, cur1, off2, cur2);

  scatter3_kernel<<<(3 * NE + 255) / 256, 256, 0, stream>>>(
      writes_src, writes_dst, cites_src, cites_dst, wb_src, wb_dst,
      cur0, cur1, cur2, csr0, csr1, csr2);

  gemm256<1><<<dim3((NP + 127) / 128, 2), 256, 0, stream>>>(cxp, WinpT, xp, NP, 128, cbinP);
  gemm256<1><<<dim3((NA + 127) / 128, 2), 256, 0, stream>>>(cxa, WinaT, xa, NA, 128, cbinA);

  for (int l = 0; l < 2; ++l) {
    gemm256<0><<<dim3((NA + 127) / 128, 2), 256, 0, stream>>>(xa, linsT + (size_t)(l * 3 + 0) * 65536, hs0, NA, 256, nullptr);
    gemm256<0><<<dim3((NP + 127) / 128, 2), 256, 0, stream>>>(xp, linsT + (size_t)(l * 3 + 1) * 65536, hs1, NP, 256, nullptr);
    gemm256<0><<<dim3((NP + 127) / 128, 2), 256, 0, stream>>>(xp, linsT + (size_t)(l * 3 + 2) * 65536, hs2, NP, 256, nullptr);
    al_kernel<16><<<(NP + 255) / 256, 256, 0, stream>>>(xp, NP, Wp + l * 4096, al_p);
    al_kernel<8><<<(NA + 255) / 256, 256, 0, stream>>>(xa, NA, Wa + l * 2048, al_a);
    if (l == 0) {
      msg_paper_kernel<<<NP / 4, 256, 0, stream>>>(hs0, hs1, al_p, al_a, off0, csr0, off1, csr1,
          cbias + 0 * 256, cbias + 1 * 256, xp, nullptr);
      msg_author_kernel<0><<<NA / 4, 256, 0, stream>>>(hs2, al_p, al_a, off2, csr2,
          cbias + 2 * 256, xa, nullptr);
    } else {
      msg_paper_kernel<<<NP / 4, 256, 0, stream>>>(hs0, hs1, al_p, al_a, off0, csr0, off1, csr1,
          cbias + 3 * 256, cbias + 4 * 256, d_out, flag);
      msg_author_kernel<1><<<NA / 4, 256, 0, stream>>>(hs2, al_p, al_a, off2, csr2,
          cbias + 5 * 256, d_out, flag);
    }
  }
}

// Round 3
// 945.457 us; speedup vs baseline: 1.3247x; 1.2163x over previous
//
#include <hip/hip_runtime.h>

// HeteroGAT on MI355X. Round 6:
//  - gemm256 (BM=BN=128, 2-barrier-per-K, 16-way LDS conflicts, A read 2x)
//    replaced by gemm_skinny: BM=64 x BN=256 (grid.y=1, A read once),
//    whole-K LDS A-stage via global_load_lds w/ XOR swizzle (pre-swizzled
//    global source, swizzled ds_read -> conflict-free), single barrier,
//    B served from L2 directly. 4 waves, 64x64 wave tile.
//  - everything else identical to the 1150us round-5 pipeline.

#define NP 100000
#define NA 50000
#define NE 250000

typedef __attribute__((ext_vector_type(8))) short short8;
typedef __attribute__((ext_vector_type(4))) float f32x4;

__device__ __forceinline__ float b2f(unsigned short u) {
  union { unsigned int i; float f; } v; v.i = ((unsigned int)u) << 16; return v.f;
}
__device__ __forceinline__ unsigned short f2b(float f) {
  union { float f; unsigned int i; } v; v.f = f;
  unsigned int u = v.i;
  return (unsigned short)((u + 0x7fffu + ((u >> 16) & 1u)) >> 16);
}

__global__ void probe_kernel(const unsigned short* __restrict__ x, int* __restrict__ flag)
{
  __shared__ int cnt;
  if (threadIdx.x == 0) cnt = 0;
  __syncthreads();
  int c = 0;
  for (int i = threadIdx.x; i < 4096; i += 256) {
    unsigned int e = (x[i] >> 7) & 0xFFu;
    if (e >= 0xC0u) c++;
  }
  atomicAdd(&cnt, c);
  __syncthreads();
  if (threadIdx.x == 0) *flag = (cnt > 64) ? 1 : 0;   // 1 = inputs are fp32
}

// ---- fused bf16-conversion of all 11 input tensors in one launch ----
#define CV_E0 12800000LL
#define CV_E1 19200000LL
#define CV_E2 19232768LL
#define CV_E3 19265536LL
#define CV_E4 19265792LL
#define CV_E5 19266048LL
#define CV_E6 19659264LL
#define CV_E7 20052480LL
#define CV_E8 20054016LL
#define CV_E9 20055552LL
#define CV_E10 20057088LL

__global__ void conv_all_kernel(
    const unsigned short* __restrict__ s0, unsigned short* __restrict__ d0,
    const unsigned short* __restrict__ s1, unsigned short* __restrict__ d1,
    const unsigned short* __restrict__ s2, unsigned short* __restrict__ d2,
    const unsigned short* __restrict__ s3, unsigned short* __restrict__ d3,
    const unsigned short* __restrict__ s4, unsigned short* __restrict__ d4,
    const unsigned short* __restrict__ s5, unsigned short* __restrict__ d5,
    const unsigned short* __restrict__ s6, unsigned short* __restrict__ d6,
    const unsigned short* __restrict__ s7, unsigned short* __restrict__ d7,
    const unsigned short* __restrict__ s8, unsigned short* __restrict__ d8,
    const unsigned short* __restrict__ s9, unsigned short* __restrict__ d9,
    const unsigned short* __restrict__ s10, unsigned short* __restrict__ d10,
    const int* __restrict__ flag)
{
  long long idx = (long long)blockIdx.x * 256 + threadIdx.x;
  if (idx >= CV_E10) return;
  int f = *flag;
  const unsigned short* s; unsigned short* d; long long off;
  if (idx < CV_E0)      { s = s0;  d = d0;  off = idx; }
  else if (idx < CV_E1) { s = s1;  d = d1;  off = idx - CV_E0; }
  else if (idx < CV_E2) { s = s2;  d = d2;  off = idx - CV_E1; }
  else if (idx < CV_E3) { s = s3;  d = d3;  off = idx - CV_E2; }
  else if (idx < CV_E4) { s = s4;  d = d4;  off = idx - CV_E3; }
  else if (idx < CV_E5) { s = s5;  d = d5;  off = idx - CV_E4; }
  else if (idx < CV_E6) { s = s6;  d = d6;  off = idx - CV_E5; }
  else if (idx < CV_E7) { s = s7;  d = d7;  off = idx - CV_E6; }
  else if (idx < CV_E8) { s = s8;  d = d8;  off = idx - CV_E7; }
  else if (idx < CV_E9) { s = s9;  d = d9;  off = idx - CV_E8; }
  else                  { s = s10; d = d10; off = idx - CV_E9; }
  if (f) d[off] = f2b(((const float*)s)[off]);
  else   d[off] = s[off];
}

// Skinny GEMM: C[M x 256] = A[M x K] * BT[256 x K]^T, bf16 in/out, f32 acc.
// BM=64, BN=256 (grid.y = 1 -> A fetched exactly once). Whole-K A tile in
// LDS, staged once via global_load_lds(16B) with XOR-swizzled source so the
// swizzled ds_read_b128 fragment reads are bank-conflict-free (2-way max).
// B read directly from global (128 KB, L2-resident). 4 waves, 64x64/wave.
template <int K, int RELU>
__global__ __launch_bounds__(256) void gemm_skinny(
    const unsigned short* __restrict__ A, const unsigned short* __restrict__ BT,
    unsigned short* __restrict__ C, int M, const unsigned short* __restrict__ bias)
{
  constexpr int SLOT = K / 8;               // 16B slots per row (32 or 16)
  __shared__ __align__(16) unsigned short As[64 * K];
  const int t = threadIdx.x;
  const int lane = t & 63;
  const int w = t >> 6;                     // wave id 0..3 -> 64-col group
  const int quad = lane >> 4;
  const int l16 = lane & 15;
  const int m0 = blockIdx.x * 64;

  // Stage A[64 x K] -> LDS. LDS slot s holds global (row, c16 ^ (row&7))
  // where row = s / SLOT, c16 = s % SLOT. Dest is linear (lane*16B), the
  // permutation lives entirely in the per-lane global source address.
  {
    constexpr int CALLS = (64 * SLOT) / 256;
#pragma unroll
    for (int c = 0; c < CALLS; c++) {
      int slot = c * 256 + t;
      int row = slot / SLOT;
      int c16 = slot % SLOT;
      int gr = m0 + row; gr = gr < M ? gr : (M - 1);
      int gc16 = c16 ^ (row & 7);
      const unsigned short* gp = A + (size_t)gr * K + gc16 * 8;
      unsigned short* lp = As + (size_t)(c * 256 + (t & ~63)) * 8;
      __builtin_amdgcn_global_load_lds(
          (const __attribute__((address_space(1))) unsigned int*)gp,
          (__attribute__((address_space(3))) unsigned int*)lp, 16, 0, 0);
    }
  }
  __syncthreads();

  f32x4 acc[4][4];
#pragma unroll
  for (int i = 0; i < 4; i++)
#pragma unroll
    for (int j = 0; j < 4; j++) { acc[i][j][0] = 0.f; acc[i][j][1] = 0.f; acc[i][j][2] = 0.f; acc[i][j][3] = 0.f; }

  const int colbase = w * 64;
#pragma unroll 1
  for (int kc = 0; kc < K / 32; ++kc) {
    short8 af[4], bq[4];
#pragma unroll
    for (int i = 0; i < 4; i++) {
      int row = i * 16 + l16;
      int c16 = (kc * 4 + quad) ^ (row & 7);
      af[i] = *(const short8*)(As + (size_t)row * K + c16 * 8);
    }
#pragma unroll
    for (int j = 0; j < 4; j++)
      bq[j] = *(const short8*)(BT + (size_t)(colbase + j * 16 + l16) * K + kc * 32 + quad * 8);
#pragma unroll
    for (int i = 0; i < 4; i++)
#pragma unroll
      for (int j = 0; j < 4; j++)
        acc[i][j] = __builtin_amdgcn_mfma_f32_16x16x32_bf16(af[i], bq[j], acc[i][j], 0, 0, 0);
  }

#pragma unroll
  for (int j = 0; j < 4; j++) {
    int col = colbase + j * 16 + l16;
    float bv2 = bias ? b2f(bias[col]) : 0.f;
#pragma unroll
    for (int i = 0; i < 4; i++) {
      int rbase = m0 + i * 16 + quad * 4;
#pragma unroll
      for (int r = 0; r < 4; r++) {
        int row = rbase + r;
        if (row < M) {
          float v = acc[i][j][r] + bv2;
          if (RELU) v = v > 0.f ? v : 0.f;
          C[(size_t)row * 256 + col] = f2b(v);
        }
      }
    }
  }
}

// Wp cols: 0-3 al_s(t=1), 4-7 al_s(t=2), 8-11 al_d(t=0), 12-15 al_d(t=1)
// Wa cols: 0-3 al_s(t=0), 4-7 al_d(t=2)
__global__ void fold_kernel(const unsigned short* __restrict__ lin_src,
                            const unsigned short* __restrict__ lin_dst,
                            const unsigned short* __restrict__ att_src,
                            const unsigned short* __restrict__ att_dst,
                            float* __restrict__ Wp, float* __restrict__ Wa)
{
  int idx = blockIdx.x * 256 + threadIdx.x;
  if (idx >= 12288) return;
  const unsigned short *L, *At;
  int l, k, j, t, h;
  if (idx < 8192) {
    l = idx >> 12; int rem = idx & 4095; k = rem >> 4; j = rem & 15;
    if (j < 4)       { t = 1; h = j;      L = lin_src; At = att_src; }
    else if (j < 8)  { t = 2; h = j - 4;  L = lin_src; At = att_src; }
    else if (j < 12) { t = 0; h = j - 8;  L = lin_dst; At = att_dst; }
    else             { t = 1; h = j - 12; L = lin_dst; At = att_dst; }
    int lt = l * 3 + t;
    float s = 0.f;
    for (int c = 0; c < 64; c++)
      s += b2f(L[((size_t)lt * 256 + k) * 256 + h * 64 + c]) * b2f(At[(lt * 4 + h) * 64 + c]);
    Wp[l * 4096 + k * 16 + j] = s;
  } else {
    int i2 = idx - 8192;
    l = i2 >> 11; int rem = i2 & 2047; k = rem >> 3; j = rem & 7;
    if (j < 4) { t = 0; h = j;     L = lin_src; At = att_src; }
    else       { t = 2; h = j - 4; L = lin_dst; At = att_dst; }
    int lt = l * 3 + t;
    float s = 0.f;
    for (int c = 0; c < 64; c++)
      s += b2f(L[((size_t)lt * 256 + k) * 256 + h * 64 + c]) * b2f(At[(lt * 4 + h) * 64 + c]);
    Wa[l * 2048 + k * 8 + j] = s;
  }
}

__global__ void transpose_kernel(const unsigned short* __restrict__ in,
                                 unsigned short* __restrict__ out, int K, int N, int batch)
{
  int idx = blockIdx.x * 256 + threadIdx.x;
  int total = batch * K * N;
  if (idx >= total) return;
  int b = idx / (K * N); int rem = idx % (K * N);
  int k = rem / N; int n = rem % N;
  out[(size_t)b * K * N + (size_t)n * K + k] = in[idx];
}

template <int NCOL>
__global__ __launch_bounds__(256) void al_kernel(const unsigned short* __restrict__ X, int rows,
                                                 const float* __restrict__ W, float* __restrict__ out)
{
  __shared__ __align__(16) float Ws[256 * NCOL];
  for (int i = threadIdx.x; i < 256 * NCOL; i += 256) Ws[i] = W[i];
  __syncthreads();
  int row = blockIdx.x * 256 + threadIdx.x;
  if (row >= rows) return;
  f32x4 acc[NCOL / 4];
#pragma unroll
  for (int jv = 0; jv < NCOL / 4; jv++) { acc[jv][0] = 0.f; acc[jv][1] = 0.f; acc[jv][2] = 0.f; acc[jv][3] = 0.f; }
  const unsigned short* xr = X + (size_t)row * 256;
  for (int k = 0; k < 256; k += 8) {
    uint4 pk = *(const uint4*)(xr + k);
    unsigned int uu[4] = {pk.x, pk.y, pk.z, pk.w};
#pragma unroll
    for (int e2 = 0; e2 < 4; e2++) {
      float x0 = b2f((unsigned short)(uu[e2] & 0xffffu));
      float x1 = b2f((unsigned short)(uu[e2] >> 16));
      int k0 = k + e2 * 2;
#pragma unroll
      for (int jv = 0; jv < NCOL / 4; jv++) {
        const f32x4 w0 = *(const f32x4*)&Ws[k0 * NCOL + jv * 4];
        const f32x4 w1 = *(const f32x4*)&Ws[(k0 + 1) * NCOL + jv * 4];
#pragma unroll
        for (int c = 0; c < 4; c++) acc[jv][c] += x0 * w0[c] + x1 * w1[c];
      }
    }
  }
#pragma unroll
  for (int jv = 0; jv < NCOL / 4; jv++)
    *(f32x4*)&out[(size_t)row * NCOL + jv * 4] = acc[jv];
}

__global__ void hist3_kernel(const int* __restrict__ wdst, const int* __restrict__ cdst,
                             const int* __restrict__ adst,
                             int* __restrict__ deg0, int* __restrict__ deg1, int* __restrict__ deg2)
{
  int idx = blockIdx.x * 256 + threadIdx.x;
  if (idx < NE)          atomicAdd(&deg0[wdst[idx]], 1);
  else if (idx < 2 * NE) atomicAdd(&deg1[cdst[idx - NE]], 1);
  else if (idx < 3 * NE) atomicAdd(&deg2[adst[idx - 2 * NE]], 1);
}

// ---------------- hierarchical scan, 3 edge-types per launch via blockIdx.y
__global__ __launch_bounds__(256) void scan_partial3(const int* __restrict__ deg0,
                                                     const int* __restrict__ deg1,
                                                     const int* __restrict__ deg2,
                                                     int* __restrict__ b0, int* __restrict__ b1,
                                                     int* __restrict__ b2)
{
  const int* deg; int n; int* bs;
  if (blockIdx.y == 0)      { deg = deg0; n = NP; bs = b0; }
  else if (blockIdx.y == 1) { deg = deg1; n = NP; bs = b1; }
  else                      { deg = deg2; n = NA; bs = b2; }
  if ((int)blockIdx.x * 2048 >= n) return;
  int tid = threadIdx.x;
  int base = blockIdx.x * 2048 + tid * 8;
  int s = 0;
#pragma unroll
  for (int i = 0; i < 8; i++) { int idx = base + i; if (idx < n) s += deg[idx]; }
  __shared__ int red[256];
  red[tid] = s;
  __syncthreads();
  for (int d = 128; d > 0; d >>= 1) {
    if (tid < d) red[tid] += red[tid + d];
    __syncthreads();
  }
  if (tid == 0) bs[blockIdx.x] = red[0];
}

// three blocks, one wave each; nb <= 64. In-place exclusive scan of block sums.
__global__ void scan_bsum3(int* __restrict__ b0, int* __restrict__ b1, int* __restrict__ b2,
                           int nb0, int nb1, int nb2)
{
  int* bsum; int nb;
  if (blockIdx.x == 0)      { bsum = b0; nb = nb0; }
  else if (blockIdx.x == 1) { bsum = b1; nb = nb1; }
  else                      { bsum = b2; nb = nb2; }
  int lane = threadIdx.x;
  int orig = (lane < nb) ? bsum[lane] : 0;
  int v = orig;
  for (int d = 1; d < 64; d <<= 1) {
    int t = __shfl_up(v, d);
    if (lane >= d) v += t;
  }
  if (lane < nb) bsum[lane] = v - orig;   // exclusive
}

__global__ __launch_bounds__(256) void scan_emit3(const int* __restrict__ deg0,
                                                  const int* __restrict__ deg1,
                                                  const int* __restrict__ deg2,
                                                  const int* __restrict__ b0,
                                                  const int* __restrict__ b1,
                                                  const int* __restrict__ b2,
                                                  int* __restrict__ off0a, int* __restrict__ cur0a,
                                                  int* __restrict__ off1a, int* __restrict__ cur1a,
                                                  int* __restrict__ off2a, int* __restrict__ cur2a)
{
  const int* deg; int n; const int* bsum; int* off; int* cur;
  if (blockIdx.y == 0)      { deg = deg0; n = NP; bsum = b0; off = off0a; cur = cur0a; }
  else if (blockIdx.y == 1) { deg = deg1; n = NP; bsum = b1; off = off1a; cur = cur1a; }
  else                      { deg = deg2; n = NA; bsum = b2; off = off2a; cur = cur2a; }
  if ((int)blockIdx.x * 2048 >= n) return;
  int tid = threadIdx.x;
  int base = blockIdx.x * 2048 + tid * 8;
  int vals[8]; int s = 0;
#pragma unroll
  for (int i = 0; i < 8; i++) { int idx = base + i; vals[i] = (idx < n) ? deg[idx] : 0; s += vals[i]; }
  __shared__ int sh[256];
  sh[tid] = s;
  __syncthreads();
  for (int d = 1; d < 256; d <<= 1) {
    int t = (tid >= d) ? sh[tid - d] : 0;
    __syncthreads();
    sh[tid] += t;
    __syncthreads();
  }
  int run = bsum[blockIdx.x] + sh[tid] - s;   // exclusive prefix for this thread's chunk
#pragma unroll
  for (int i = 0; i < 8; i++) {
    int idx = base + i;
    if (idx < n) { off[idx] = run; cur[idx] = run; run += vals[i]; }
  }
  if (blockIdx.x == 0 && tid == 0) off[n] = NE;
}

__global__ void scatter3_kernel(const int* __restrict__ ws, const int* __restrict__ wd,
                                const int* __restrict__ cs, const int* __restrict__ cd,
                                const int* __restrict__ as, const int* __restrict__ ad,
                                int* __restrict__ cur0, int* __restrict__ cur1, int* __restrict__ cur2,
                                int* __restrict__ csr0, int* __restrict__ csr1, int* __restrict__ csr2)
{
  int idx = blockIdx.x * 256 + threadIdx.x;
  if (idx < NE) {
    int p = atomicAdd(&cur0[wd[idx]], 1); csr0[p] = ws[idx];
  } else if (idx < 2 * NE) {
    int e = idx - NE;
    int p = atomicAdd(&cur1[cd[e]], 1); csr1[p] = cs[e];
  } else if (idx < 3 * NE) {
    int e = idx - 2 * NE;
    int p = atomicAdd(&cur2[ad[e]], 1); csr2[p] = as[e];
  }
}

// 4-wide-batched online-softmax GAT accumulation over one CSR list.
// Pads a partial batch by duplicating the last edge (valid address); padded
// lanes get lg=-1e30 -> p=0 -> zero contribution. One rescale per batch.
template <int STRIDE>
__device__ __forceinline__ void gat_accum(const unsigned short* __restrict__ hs,
                                          const float* __restrict__ alsb,
                                          const int* __restrict__ csr,
                                          int s, int e, float ald, int cb,
                                          float& o0, float& o1, float& o2, float& o3)
{
  if (s >= e) return;
  float m = -1e30f, denom = 0.f, a0 = 0.f, a1 = 0.f, a2 = 0.f, a3 = 0.f;
  for (int i = s; i < e; i += 4) {
    int svv[4];
#pragma unroll
    for (int j = 0; j < 4; j++) {
      int idx = (i + j < e) ? (i + j) : (e - 1);
      svv[j] = csr[idx];
    }
    float lg[4]; ushort4 hv[4];
#pragma unroll
    for (int j = 0; j < 4; j++) {
      float als = alsb[(size_t)svv[j] * STRIDE];
      hv[j] = *(const ushort4*)(hs + (size_t)svv[j] * 256 + cb);
      float l = als + ald;
      l = l > 0.f ? l : 0.2f * l;
      lg[j] = (i + j < e) ? l : -1e30f;
    }
    float mb = fmaxf(fmaxf(lg[0], lg[1]), fmaxf(lg[2], lg[3]));
    float mn = fmaxf(m, mb);
    float corr = __expf(m - mn);
    m = mn;
    denom *= corr; a0 *= corr; a1 *= corr; a2 *= corr; a3 *= corr;
#pragma unroll
    for (int j = 0; j < 4; j++) {
      float p = __expf(lg[j] - mn);
      denom += p;
      a0 += p * b2f(hv[j].x);
      a1 += p * b2f(hv[j].y);
      a2 += p * b2f(hv[j].z);
      a3 += p * b2f(hv[j].w);
    }
  }
  float inv = denom > 0.f ? 1.f / denom : 0.f;
  o0 += a0 * inv; o1 += a1 * inv; o2 += a2 * inv; o3 += a3 * inv;
}

__global__ __launch_bounds__(256) void msg_paper_kernel(
    const unsigned short* __restrict__ hs0, const unsigned short* __restrict__ hs1,
    const float* __restrict__ al_p, const float* __restrict__ al_a,
    const int* __restrict__ off0, const int* __restrict__ csr0,
    const int* __restrict__ off1, const int* __restrict__ csr1,
    const unsigned short* __restrict__ bg0, const unsigned short* __restrict__ bg1,
    void* __restrict__ out, const int* __restrict__ flag)
{
  int n = blockIdx.x * 4 + (threadIdx.x >> 6);
  if (n >= NP) return;
  int lane = threadIdx.x & 63;
  int h = lane >> 4;
  int cb = lane * 4;
  float o0 = 0.f, o1 = 0.f, o2 = 0.f, o3 = 0.f;
  gat_accum<8>(hs0, al_a + h, csr0, off0[n], off0[n + 1], al_p[n * 16 + 8 + h], cb,
               o0, o1, o2, o3);
  gat_accum<16>(hs1, al_p + h, csr1, off1[n], off1[n + 1], al_p[n * 16 + 12 + h], cb,
                o0, o1, o2, o3);
  const ushort4 bv0 = *(const ushort4*)(bg0 + cb);
  const ushort4 bv1 = *(const ushort4*)(bg1 + cb);
  float v0 = o0 + b2f(bv0.x) + b2f(bv1.x); v0 = v0 > 0.f ? v0 : __expf(v0) - 1.f;
  float v1 = o1 + b2f(bv0.y) + b2f(bv1.y); v1 = v1 > 0.f ? v1 : __expf(v1) - 1.f;
  float v2 = o2 + b2f(bv0.z) + b2f(bv1.z); v2 = v2 > 0.f ? v2 : __expf(v2) - 1.f;
  float v3 = o3 + b2f(bv0.w) + b2f(bv1.w); v3 = v3 > 0.f ? v3 : __expf(v3) - 1.f;
  if (flag && *flag) {
    float* of = (float*)out;
    f32x4 ov = {v0, v1, v2, v3};
    *(f32x4*)(of + (size_t)n * 256 + cb) = ov;
  } else {
    unsigned short* ob = (unsigned short*)out;
    ushort4 ov; ov.x = f2b(v0); ov.y = f2b(v1); ov.z = f2b(v2); ov.w = f2b(v3);
    *(ushort4*)(ob + (size_t)n * 256 + cb) = ov;
  }
}

template <int FINAL>
__global__ __launch_bounds__(256) void msg_author_kernel(
    const unsigned short* __restrict__ hs2,
    const float* __restrict__ al_p, const float* __restrict__ al_a,
    const int* __restrict__ off2, const int* __restrict__ csr2,
    const unsigned short* __restrict__ bg2, void* __restrict__ out,
    const int* __restrict__ flag)
{
  int n = blockIdx.x * 4 + (threadIdx.x >> 6);
  if (n >= NA) return;
  int lane = threadIdx.x & 63;
  int h = lane >> 4;
  int cb = lane * 4;
  float o0 = 0.f, o1 = 0.f, o2 = 0.f, o3 = 0.f;
  gat_accum<16>(hs2, al_p + 4 + h, csr2, off2[n], off2[n + 1], al_a[n * 8 + 4 + h], cb,
                o0, o1, o2, o3);
  const ushort4 bv = *(const ushort4*)(bg2 + cb);
  float v0 = o0 + b2f(bv.x); v0 = v0 > 0.f ? v0 : __expf(v0) - 1.f;
  float v1 = o1 + b2f(bv.y); v1 = v1 > 0.f ? v1 : __expf(v1) - 1.f;
  float v2 = o2 + b2f(bv.z); v2 = v2 > 0.f ? v2 : __expf(v2) - 1.f;
  float v3 = o3 + b2f(bv.w); v3 = v3 > 0.f ? v3 : __expf(v3) - 1.f;
  size_t elem = (size_t)n * 256 + cb + (FINAL ? (size_t)NP * 256 : 0);
  if (FINAL && flag && *flag) {
    float* of = (float*)out;
    f32x4 ov = {v0, v1, v2, v3};
    *(f32x4*)(of + elem) = ov;
  } else {
    unsigned short* ob = (unsigned short*)out;
    ushort4 ov; ov.x = f2b(v0); ov.y = f2b(v1); ov.z = f2b(v2); ov.w = f2b(v3);
    *(ushort4*)(ob + elem) = ov;
  }
}

extern "C" void kernel_launch(void* const* d_in, const int* in_sizes, int n_in,
                              void* d_out, int out_size, void* d_ws, size_t ws_size,
                              hipStream_t stream)
{
  const unsigned short* x_paper  = (const unsigned short*)d_in[0];
  const unsigned short* x_author = (const unsigned short*)d_in[1];
  const unsigned short* W_in_p   = (const unsigned short*)d_in[2];
  const unsigned short* b_in_p   = (const unsigned short*)d_in[3];
  const unsigned short* W_in_a   = (const unsigned short*)d_in[4];
  const unsigned short* b_in_a   = (const unsigned short*)d_in[5];
  const unsigned short* lin_src  = (const unsigned short*)d_in[6];
  const unsigned short* lin_dst  = (const unsigned short*)d_in[7];
  const unsigned short* att_src  = (const unsigned short*)d_in[8];
  const unsigned short* att_dst  = (const unsigned short*)d_in[9];
  const unsigned short* bias_gat = (const unsigned short*)d_in[10];
  const int* writes_src = (const int*)d_in[11];
  const int* writes_dst = (const int*)d_in[12];
  const int* cites_src  = (const int*)d_in[13];
  const int* cites_dst  = (const int*)d_in[14];
  const int* wb_src     = (const int*)d_in[15];
  const int* wb_dst     = (const int*)d_in[16];

  char* base = (char*)d_ws;
  size_t cur = 0;
  auto take = [&](size_t bytes) -> char* {
    char* p = base + cur;
    cur += (bytes + 255) & ~(size_t)255;
    return p;
  };

  int* flag = (int*)take(256);
  unsigned short* cxp   = (unsigned short*)take((size_t)NP * 128 * 2);
  unsigned short* cxa   = (unsigned short*)take((size_t)NA * 128 * 2);
  unsigned short* cWinP = (unsigned short*)take(128 * 256 * 2);
  unsigned short* cWinA = (unsigned short*)take(128 * 256 * 2);
  unsigned short* cbinP = (unsigned short*)take(256 * 2);
  unsigned short* cbinA = (unsigned short*)take(256 * 2);
  unsigned short* clins = (unsigned short*)take((size_t)6 * 65536 * 2);
  unsigned short* clind = (unsigned short*)take((size_t)6 * 65536 * 2);
  unsigned short* catts = (unsigned short*)take(1536 * 2);
  unsigned short* cattd = (unsigned short*)take(1536 * 2);
  unsigned short* cbias = (unsigned short*)take(1536 * 2);

  unsigned short* xp  = (unsigned short*)take((size_t)NP * 256 * 2);
  unsigned short* xa  = (unsigned short*)take((size_t)NA * 256 * 2);
  unsigned short* hs0 = (unsigned short*)take((size_t)NA * 256 * 2);
  unsigned short* hs1 = (unsigned short*)take((size_t)NP * 256 * 2);
  unsigned short* hs2 = (unsigned short*)take((size_t)NP * 256 * 2);
  float* al_p = (float*)take((size_t)NP * 16 * 4);
  float* al_a = (float*)take((size_t)NA * 8 * 4);
  float* Wp   = (float*)take(2 * 256 * 16 * 4);
  float* Wa   = (float*)take(2 * 256 * 8 * 4);
  unsigned short* WinpT = (unsigned short*)take(256 * 128 * 2);
  unsigned short* WinaT = (unsigned short*)take(256 * 128 * 2);
  unsigned short* linsT = (unsigned short*)take((size_t)6 * 65536 * 2);
  int* off0 = (int*)take((size_t)(NP + 1) * 4);
  int* cur0 = (int*)take((size_t)NP * 4);
  int* csr0 = (int*)take((size_t)NE * 4);
  int* off1 = (int*)take((size_t)(NP + 1) * 4);
  int* cur1 = (int*)take((size_t)NP * 4);
  int* csr1 = (int*)take((size_t)NE * 4);
  int* off2 = (int*)take((size_t)(NA + 1) * 4);
  int* cur2 = (int*)take((size_t)NA * 4);
  int* csr2 = (int*)take((size_t)NE * 4);
  int* degAll = (int*)take((size_t)(2 * NP + NA) * 4);
  int* deg0 = degAll;
  int* deg1 = degAll + NP;
  int* deg2 = degAll + 2 * NP;
  int* bsum0 = (int*)take(64 * 4);
  int* bsum1 = (int*)take(64 * 4);
  int* bsum2 = (int*)take(64 * 4);

  probe_kernel<<<1, 256, 0, stream>>>(x_paper, flag);

  const long long CVN = (CV_E10 + 255) / 256;
  conv_all_kernel<<<(unsigned)CVN, 256, 0, stream>>>(
      x_paper, cxp, x_author, cxa, W_in_p, cWinP, W_in_a, cWinA,
      b_in_p, cbinP, b_in_a, cbinA, lin_src, clins, lin_dst, clind,
      att_src, catts, att_dst, cattd, bias_gat, cbias, flag);

  hipMemsetAsync(degAll, 0, (size_t)(2 * NP + NA) * 4, stream);

  fold_kernel<<<48, 256, 0, stream>>>(clins, clind, catts, cattd, Wp, Wa);
  transpose_kernel<<<(6 * 65536) / 256, 256, 0, stream>>>(clins, linsT, 256, 256, 6);
  transpose_kernel<<<(128 * 256) / 256, 256, 0, stream>>>(cWinP, WinpT, 128, 256, 1);
  transpose_kernel<<<(128 * 256) / 256, 256, 0, stream>>>(cWinA, WinaT, 128, 256, 1);

  hist3_kernel<<<(3 * NE + 255) / 256, 256, 0, stream>>>(writes_dst, cites_dst, wb_dst,
                                                         deg0, deg1, deg2);

  const int nbP = (NP + 2047) / 2048;   // 49
  const int nbA = (NA + 2047) / 2048;   // 25
  scan_partial3<<<dim3(nbP, 3), 256, 0, stream>>>(deg0, deg1, deg2, bsum0, bsum1, bsum2);
  scan_bsum3<<<3, 64, 0, stream>>>(bsum0, bsum1, bsum2, nbP, nbP, nbA);
  scan_emit3<<<dim3(nbP, 3), 256, 0, stream>>>(deg0, deg1, deg2, bsum0, bsum1, bsum2,
                                               off0, cur0, off1, cur1, off2, cur2);

  scatter3_kernel<<<(3 * NE + 255) / 256, 256, 0, stream>>>(
      writes_src, writes_dst, cites_src, cites_dst, wb_src, wb_dst,
      cur0, cur1, cur2, csr0, csr1, csr2);

  gemm_skinny<128, 1><<<(NP + 63) / 64, 256, 0, stream>>>(cxp, WinpT, xp, NP, cbinP);
  gemm_skinny<128, 1><<<(NA + 63) / 64, 256, 0, stream>>>(cxa, WinaT, xa, NA, cbinA);

  for (int l = 0; l < 2; ++l) {
    gemm_skinny<256, 0><<<(NA + 63) / 64, 256, 0, stream>>>(xa, linsT + (size_t)(l * 3 + 0) * 65536, hs0, NA, nullptr);
    gemm_skinny<256, 0><<<(NP + 63) / 64, 256, 0, stream>>>(xp, linsT + (size_t)(l * 3 + 1) * 65536, hs1, NP, nullptr);
    gemm_skinny<256, 0><<<(NP + 63) / 64, 256, 0, stream>>>(xp, linsT + (size_t)(l * 3 + 2) * 65536, hs2, NP, nullptr);
    al_kernel<16><<<(NP + 255) / 256, 256, 0, stream>>>(xp, NP, Wp + l * 4096, al_p);
    al_kernel<8><<<(NA + 255) / 256, 256, 0, stream>>>(xa, NA, Wa + l * 2048, al_a);
    if (l == 0) {
      msg_paper_kernel<<<NP / 4, 256, 0, stream>>>(hs0, hs1, al_p, al_a, off0, csr0, off1, csr1,
          cbias + 0 * 256, cbias + 1 * 256, xp, nullptr);
      msg_author_kernel<0><<<NA / 4, 256, 0, stream>>>(hs2, al_p, al_a, off2, csr2,
          cbias + 2 * 256, xa, nullptr);
    } else {
      msg_paper_kernel<<<NP / 4, 256, 0, stream>>>(hs0, hs1, al_p, al_a, off0, csr0, off1, csr1,
          cbias + 3 * 256, cbias + 4 * 256, d_out, flag);
      msg_author_kernel<1><<<NA / 4, 256, 0, stream>>>(hs2, al_p, al_a, off2, csr2,
          cbias + 5 * 256, d_out, flag);
    }
  }
}

// Round 4
// 892.275 us; speedup vs baseline: 1.4036x; 1.0596x over previous
//
#include <hip/hip_runtime.h>

// HeteroGAT on MI355X. Round 7:
//  - gat_accum widened 4->8 edges/batch (more outstanding gathers, Little's law)
//  - launch-graph collapse: {hs0,hs1,hs2,al_p,al_a} -> 1 layer_kernel (block-range
//    dispatch), 2 input gemms -> 1, msg_paper+msg_author -> 1, 3 transposes -> 1.
//    27 launches -> 15.
//  - gemm_body / al_body identical math to round-6 gemm_skinny / al_kernel.

#define NP 100000
#define NA 50000
#define NE 250000

typedef __attribute__((ext_vector_type(8))) short short8;
typedef __attribute__((ext_vector_type(4))) float f32x4;

__device__ __forceinline__ float b2f(unsigned short u) {
  union { unsigned int i; float f; } v; v.i = ((unsigned int)u) << 16; return v.f;
}
__device__ __forceinline__ unsigned short f2b(float f) {
  union { float f; unsigned int i; } v; v.f = f;
  unsigned int u = v.i;
  return (unsigned short)((u + 0x7fffu + ((u >> 16) & 1u)) >> 16);
}

__global__ void probe_kernel(const unsigned short* __restrict__ x, int* __restrict__ flag)
{
  __shared__ int cnt;
  if (threadIdx.x == 0) cnt = 0;
  __syncthreads();
  int c = 0;
  for (int i = threadIdx.x; i < 4096; i += 256) {
    unsigned int e = (x[i] >> 7) & 0xFFu;
    if (e >= 0xC0u) c++;
  }
  atomicAdd(&cnt, c);
  __syncthreads();
  if (threadIdx.x == 0) *flag = (cnt > 64) ? 1 : 0;   // 1 = inputs are fp32
}

// ---- fused bf16-conversion of all 11 input tensors in one launch ----
#define CV_E0 12800000LL
#define CV_E1 19200000LL
#define CV_E2 19232768LL
#define CV_E3 19265536LL
#define CV_E4 19265792LL
#define CV_E5 19266048LL
#define CV_E6 19659264LL
#define CV_E7 20052480LL
#define CV_E8 20054016LL
#define CV_E9 20055552LL
#define CV_E10 20057088LL

__global__ void conv_all_kernel(
    const unsigned short* __restrict__ s0, unsigned short* __restrict__ d0,
    const unsigned short* __restrict__ s1, unsigned short* __restrict__ d1,
    const unsigned short* __restrict__ s2, unsigned short* __restrict__ d2,
    const unsigned short* __restrict__ s3, unsigned short* __restrict__ d3,
    const unsigned short* __restrict__ s4, unsigned short* __restrict__ d4,
    const unsigned short* __restrict__ s5, unsigned short* __restrict__ d5,
    const unsigned short* __restrict__ s6, unsigned short* __restrict__ d6,
    const unsigned short* __restrict__ s7, unsigned short* __restrict__ d7,
    const unsigned short* __restrict__ s8, unsigned short* __restrict__ d8,
    const unsigned short* __restrict__ s9, unsigned short* __restrict__ d9,
    const unsigned short* __restrict__ s10, unsigned short* __restrict__ d10,
    const int* __restrict__ flag)
{
  long long idx = (long long)blockIdx.x * 256 + threadIdx.x;
  if (idx >= CV_E10) return;
  int f = *flag;
  const unsigned short* s; unsigned short* d; long long off;
  if (idx < CV_E0)      { s = s0;  d = d0;  off = idx; }
  else if (idx < CV_E1) { s = s1;  d = d1;  off = idx - CV_E0; }
  else if (idx < CV_E2) { s = s2;  d = d2;  off = idx - CV_E1; }
  else if (idx < CV_E3) { s = s3;  d = d3;  off = idx - CV_E2; }
  else if (idx < CV_E4) { s = s4;  d = d4;  off = idx - CV_E3; }
  else if (idx < CV_E5) { s = s5;  d = d5;  off = idx - CV_E4; }
  else if (idx < CV_E6) { s = s6;  d = d6;  off = idx - CV_E5; }
  else if (idx < CV_E7) { s = s7;  d = d7;  off = idx - CV_E6; }
  else if (idx < CV_E8) { s = s8;  d = d8;  off = idx - CV_E7; }
  else if (idx < CV_E9) { s = s9;  d = d9;  off = idx - CV_E8; }
  else                  { s = s10; d = d10; off = idx - CV_E9; }
  if (f) d[off] = f2b(((const float*)s)[off]);
  else   d[off] = s[off];
}

// Skinny GEMM body: C[M x 256] = A[M x K] * BT[256 x K]^T, bf16 in/out, f32 acc.
// BM=64, BN=256. Whole-K A tile in LDS via global_load_lds(16B), XOR-swizzled
// source + swizzled ds_read (conflict-free). B from global (L2). 4 waves.
template <int K, int RELU>
__device__ __forceinline__ void gemm_body(
    const unsigned short* __restrict__ A, const unsigned short* __restrict__ BT,
    unsigned short* __restrict__ C, int M, const unsigned short* __restrict__ bias,
    int bx, unsigned short* As)
{
  constexpr int SLOT = K / 8;               // 16B slots per row (32 or 16)
  const int t = threadIdx.x;
  const int lane = t & 63;
  const int w = t >> 6;                     // wave id 0..3 -> 64-col group
  const int quad = lane >> 4;
  const int l16 = lane & 15;
  const int m0 = bx * 64;

  {
    constexpr int CALLS = (64 * SLOT) / 256;
#pragma unroll
    for (int c = 0; c < CALLS; c++) {
      int slot = c * 256 + t;
      int row = slot / SLOT;
      int c16 = slot % SLOT;
      int gr = m0 + row; gr = gr < M ? gr : (M - 1);
      int gc16 = c16 ^ (row & 7);
      const unsigned short* gp = A + (size_t)gr * K + gc16 * 8;
      unsigned short* lp = As + (size_t)(c * 256 + (t & ~63)) * 8;
      __builtin_amdgcn_global_load_lds(
          (const __attribute__((address_space(1))) unsigned int*)gp,
          (__attribute__((address_space(3))) unsigned int*)lp, 16, 0, 0);
    }
  }
  __syncthreads();

  f32x4 acc[4][4];
#pragma unroll
  for (int i = 0; i < 4; i++)
#pragma unroll
    for (int j = 0; j < 4; j++) { acc[i][j][0] = 0.f; acc[i][j][1] = 0.f; acc[i][j][2] = 0.f; acc[i][j][3] = 0.f; }

  const int colbase = w * 64;
#pragma unroll 1
  for (int kc = 0; kc < K / 32; ++kc) {
    short8 af[4], bq[4];
#pragma unroll
    for (int i = 0; i < 4; i++) {
      int row = i * 16 + l16;
      int c16 = (kc * 4 + quad) ^ (row & 7);
      af[i] = *(const short8*)(As + (size_t)row * K + c16 * 8);
    }
#pragma unroll
    for (int j = 0; j < 4; j++)
      bq[j] = *(const short8*)(BT + (size_t)(colbase + j * 16 + l16) * K + kc * 32 + quad * 8);
#pragma unroll
    for (int i = 0; i < 4; i++)
#pragma unroll
      for (int j = 0; j < 4; j++)
        acc[i][j] = __builtin_amdgcn_mfma_f32_16x16x32_bf16(af[i], bq[j], acc[i][j], 0, 0, 0);
  }

#pragma unroll
  for (int j = 0; j < 4; j++) {
    int col = colbase + j * 16 + l16;
    float bv2 = bias ? b2f(bias[col]) : 0.f;
#pragma unroll
    for (int i = 0; i < 4; i++) {
      int rbase = m0 + i * 16 + quad * 4;
#pragma unroll
      for (int r = 0; r < 4; r++) {
        int row = rbase + r;
        if (row < M) {
          float v = acc[i][j][r] + bv2;
          if (RELU) v = v > 0.f ? v : 0.f;
          C[(size_t)row * 256 + col] = f2b(v);
        }
      }
    }
  }
}

// al body: out[row, 0..NCOL) = X[row,:256] (bf16) dot W[:,j] (f32)
template <int NCOL>
__device__ __forceinline__ void al_body(const unsigned short* __restrict__ X, int rows,
                                        const float* __restrict__ W, float* __restrict__ out,
                                        int bx, float* Ws)
{
  for (int i = threadIdx.x; i < 256 * NCOL; i += 256) Ws[i] = W[i];
  __syncthreads();
  int row = bx * 256 + threadIdx.x;
  if (row >= rows) return;
  f32x4 acc[NCOL / 4];
#pragma unroll
  for (int jv = 0; jv < NCOL / 4; jv++) { acc[jv][0] = 0.f; acc[jv][1] = 0.f; acc[jv][2] = 0.f; acc[jv][3] = 0.f; }
  const unsigned short* xr = X + (size_t)row * 256;
  for (int k = 0; k < 256; k += 8) {
    uint4 pk = *(const uint4*)(xr + k);
    unsigned int uu[4] = {pk.x, pk.y, pk.z, pk.w};
#pragma unroll
    for (int e2 = 0; e2 < 4; e2++) {
      float x0 = b2f((unsigned short)(uu[e2] & 0xffffu));
      float x1 = b2f((unsigned short)(uu[e2] >> 16));
      int k0 = k + e2 * 2;
#pragma unroll
      for (int jv = 0; jv < NCOL / 4; jv++) {
        const f32x4 w0 = *(const f32x4*)&Ws[k0 * NCOL + jv * 4];
        const f32x4 w1 = *(const f32x4*)&Ws[(k0 + 1) * NCOL + jv * 4];
#pragma unroll
        for (int c = 0; c < 4; c++) acc[jv][c] += x0 * w0[c] + x1 * w1[c];
      }
    }
  }
#pragma unroll
  for (int jv = 0; jv < NCOL / 4; jv++)
    *(f32x4*)&out[(size_t)row * NCOL + jv * 4] = acc[jv];
}

// merged input gemms: [0,1563) paper K=128, [1563,2345) author K=128
__global__ __launch_bounds__(256) void gemm_in_kernel(
    const unsigned short* __restrict__ cxp, const unsigned short* __restrict__ WinpT,
    unsigned short* __restrict__ xp, const unsigned short* __restrict__ cbinP,
    const unsigned short* __restrict__ cxa, const unsigned short* __restrict__ WinaT,
    unsigned short* __restrict__ xa, const unsigned short* __restrict__ cbinA)
{
  __shared__ __align__(16) unsigned short As[64 * 128];
  int bx = blockIdx.x;
  if (bx < 1563) gemm_body<128, 1>(cxp, WinpT, xp, NP, cbinP, bx, As);
  else           gemm_body<128, 1>(cxa, WinaT, xa, NA, cbinA, bx - 1563, As);
}

// merged per-layer compute: hs0 [0,782), hs1 [782,2345), hs2 [2345,3908),
// al_p [3908,4299), al_a [4299,4495)
__global__ __launch_bounds__(256) void layer_kernel(
    const unsigned short* __restrict__ xp, const unsigned short* __restrict__ xa,
    const unsigned short* __restrict__ linsT_l,
    unsigned short* __restrict__ hs0, unsigned short* __restrict__ hs1,
    unsigned short* __restrict__ hs2,
    const float* __restrict__ Wp_l, const float* __restrict__ Wa_l,
    float* __restrict__ al_p, float* __restrict__ al_a)
{
  __shared__ __align__(16) unsigned short smem[64 * 256];   // 32 KB union
  int bx = blockIdx.x;
  if (bx < 782)       gemm_body<256, 0>(xa, linsT_l + 0 * 65536, hs0, NA, nullptr, bx, smem);
  else if (bx < 2345) gemm_body<256, 0>(xp, linsT_l + 1 * 65536, hs1, NP, nullptr, bx - 782, smem);
  else if (bx < 3908) gemm_body<256, 0>(xp, linsT_l + 2 * 65536, hs2, NP, nullptr, bx - 2345, smem);
  else if (bx < 4299) al_body<16>(xp, NP, Wp_l, al_p, bx - 3908, (float*)smem);
  else                al_body<8>(xa, NA, Wa_l, al_a, bx - 4299, (float*)smem);
}

// Wp cols: 0-3 al_s(t=1), 4-7 al_s(t=2), 8-11 al_d(t=0), 12-15 al_d(t=1)
// Wa cols: 0-3 al_s(t=0), 4-7 al_d(t=2)
__global__ void fold_kernel(const unsigned short* __restrict__ lin_src,
                            const unsigned short* __restrict__ lin_dst,
                            const unsigned short* __restrict__ att_src,
                            const unsigned short* __restrict__ att_dst,
                            float* __restrict__ Wp, float* __restrict__ Wa)
{
  int idx = blockIdx.x * 256 + threadIdx.x;
  if (idx >= 12288) return;
  const unsigned short *L, *At;
  int l, k, j, t, h;
  if (idx < 8192) {
    l = idx >> 12; int rem = idx & 4095; k = rem >> 4; j = rem & 15;
    if (j < 4)       { t = 1; h = j;      L = lin_src; At = att_src; }
    else if (j < 8)  { t = 2; h = j - 4;  L = lin_src; At = att_src; }
    else if (j < 12) { t = 0; h = j - 8;  L = lin_dst; At = att_dst; }
    else             { t = 1; h = j - 12; L = lin_dst; At = att_dst; }
    int lt = l * 3 + t;
    float s = 0.f;
    for (int c = 0; c < 64; c++)
      s += b2f(L[((size_t)lt * 256 + k) * 256 + h * 64 + c]) * b2f(At[(lt * 4 + h) * 64 + c]);
    Wp[l * 4096 + k * 16 + j] = s;
  } else {
    int i2 = idx - 8192;
    l = i2 >> 11; int rem = i2 & 2047; k = rem >> 3; j = rem & 7;
    if (j < 4) { t = 0; h = j;     L = lin_src; At = att_src; }
    else       { t = 2; h = j - 4; L = lin_dst; At = att_dst; }
    int lt = l * 3 + t;
    float s = 0.f;
    for (int c = 0; c < 64; c++)
      s += b2f(L[((size_t)lt * 256 + k) * 256 + h * 64 + c]) * b2f(At[(lt * 4 + h) * 64 + c]);
    Wa[l * 2048 + k * 8 + j] = s;
  }
}

// merged transposes: lins(6x256x256) [0,393216), WinP [393216,425984), WinA [..458752)
__global__ void transpose_all_kernel(const unsigned short* __restrict__ clins,
                                     unsigned short* __restrict__ linsT,
                                     const unsigned short* __restrict__ cWinP,
                                     unsigned short* __restrict__ WinpT,
                                     const unsigned short* __restrict__ cWinA,
                                     unsigned short* __restrict__ WinaT)
{
  int idx = blockIdx.x * 256 + threadIdx.x;
  if (idx < 393216) {
    int b = idx >> 16; int rem = idx & 65535; int k = rem >> 8; int n = rem & 255;
    linsT[(size_t)b * 65536 + n * 256 + k] = clins[idx];
  } else if (idx < 425984) {
    int i2 = idx - 393216; int k = i2 >> 8; int n = i2 & 255;
    WinpT[n * 128 + k] = cWinP[i2];
  } else if (idx < 458752) {
    int i2 = idx - 425984; int k = i2 >> 8; int n = i2 & 255;
    WinaT[n * 128 + k] = cWinA[i2];
  }
}

__global__ void hist3_kernel(const int* __restrict__ wdst, const int* __restrict__ cdst,
                             const int* __restrict__ adst,
                             int* __restrict__ deg0, int* __restrict__ deg1, int* __restrict__ deg2)
{
  int idx = blockIdx.x * 256 + threadIdx.x;
  if (idx < NE)          atomicAdd(&deg0[wdst[idx]], 1);
  else if (idx < 2 * NE) atomicAdd(&deg1[cdst[idx - NE]], 1);
  else if (idx < 3 * NE) atomicAdd(&deg2[adst[idx - 2 * NE]], 1);
}

// ---------------- hierarchical scan, 3 edge-types per launch via blockIdx.y
__global__ __launch_bounds__(256) void scan_partial3(const int* __restrict__ deg0,
                                                     const int* __restrict__ deg1,
                                                     const int* __restrict__ deg2,
                                                     int* __restrict__ b0, int* __restrict__ b1,
                                                     int* __restrict__ b2)
{
  const int* deg; int n; int* bs;
  if (blockIdx.y == 0)      { deg = deg0; n = NP; bs = b0; }
  else if (blockIdx.y == 1) { deg = deg1; n = NP; bs = b1; }
  else                      { deg = deg2; n = NA; bs = b2; }
  if ((int)blockIdx.x * 2048 >= n) return;
  int tid = threadIdx.x;
  int base = blockIdx.x * 2048 + tid * 8;
  int s = 0;
#pragma unroll
  for (int i = 0; i < 8; i++) { int idx = base + i; if (idx < n) s += deg[idx]; }
  __shared__ int red[256];
  red[tid] = s;
  __syncthreads();
  for (int d = 128; d > 0; d >>= 1) {
    if (tid < d) red[tid] += red[tid + d];
    __syncthreads();
  }
  if (tid == 0) bs[blockIdx.x] = red[0];
}

// three blocks, one wave each; nb <= 64. In-place exclusive scan of block sums.
__global__ void scan_bsum3(int* __restrict__ b0, int* __restrict__ b1, int* __restrict__ b2,
                           int nb0, int nb1, int nb2)
{
  int* bsum; int nb;
  if (blockIdx.x == 0)      { bsum = b0; nb = nb0; }
  else if (blockIdx.x == 1) { bsum = b1; nb = nb1; }
  else                      { bsum = b2; nb = nb2; }
  int lane = threadIdx.x;
  int orig = (lane < nb) ? bsum[lane] : 0;
  int v = orig;
  for (int d = 1; d < 64; d <<= 1) {
    int t = __shfl_up(v, d);
    if (lane >= d) v += t;
  }
  if (lane < nb) bsum[lane] = v - orig;   // exclusive
}

__global__ __launch_bounds__(256) void scan_emit3(const int* __restrict__ deg0,
                                                  const int* __restrict__ deg1,
                                                  const int* __restrict__ deg2,
                                                  const int* __restrict__ b0,
                                                  const int* __restrict__ b1,
                                                  const int* __restrict__ b2,
                                                  int* __restrict__ off0a, int* __restrict__ cur0a,
                                                  int* __restrict__ off1a, int* __restrict__ cur1a,
                                                  int* __restrict__ off2a, int* __restrict__ cur2a)
{
  const int* deg; int n; const int* bsum; int* off; int* cur;
  if (blockIdx.y == 0)      { deg = deg0; n = NP; bsum = b0; off = off0a; cur = cur0a; }
  else if (blockIdx.y == 1) { deg = deg1; n = NP; bsum = b1; off = off1a; cur = cur1a; }
  else                      { deg = deg2; n = NA; bsum = b2; off = off2a; cur = cur2a; }
  if ((int)blockIdx.x * 2048 >= n) return;
  int tid = threadIdx.x;
  int base = blockIdx.x * 2048 + tid * 8;
  int vals[8]; int s = 0;
#pragma unroll
  for (int i = 0; i < 8; i++) { int idx = base + i; vals[i] = (idx < n) ? deg[idx] : 0; s += vals[i]; }
  __shared__ int sh[256];
  sh[tid] = s;
  __syncthreads();
  for (int d = 1; d < 256; d <<= 1) {
    int t = (tid >= d) ? sh[tid - d] : 0;
    __syncthreads();
    sh[tid] += t;
    __syncthreads();
  }
  int run = bsum[blockIdx.x] + sh[tid] - s;   // exclusive prefix for this thread's chunk
#pragma unroll
  for (int i = 0; i < 8; i++) {
    int idx = base + i;
    if (idx < n) { off[idx] = run; cur[idx] = run; run += vals[i]; }
  }
  if (blockIdx.x == 0 && tid == 0) off[n] = NE;
}

__global__ void scatter3_kernel(const int* __restrict__ ws, const int* __restrict__ wd,
                                const int* __restrict__ cs, const int* __restrict__ cd,
                                const int* __restrict__ as, const int* __restrict__ ad,
                                int* __restrict__ cur0, int* __restrict__ cur1, int* __restrict__ cur2,
                                int* __restrict__ csr0, int* __restrict__ csr1, int* __restrict__ csr2)
{
  int idx = blockIdx.x * 256 + threadIdx.x;
  if (idx < NE) {
    int p = atomicAdd(&cur0[wd[idx]], 1); csr0[p] = ws[idx];
  } else if (idx < 2 * NE) {
    int e = idx - NE;
    int p = atomicAdd(&cur1[cd[e]], 1); csr1[p] = cs[e];
  } else if (idx < 3 * NE) {
    int e = idx - 2 * NE;
    int p = atomicAdd(&cur2[ad[e]], 1); csr2[p] = as[e];
  }
}

// 8-wide-batched online-softmax GAT accumulation over one CSR list.
// Pads a partial batch by duplicating the last edge (valid address); padded
// lanes get lg=-1e30 -> p=0 -> zero contribution. One rescale per batch.
template <int STRIDE>
__device__ __forceinline__ void gat_accum(const unsigned short* __restrict__ hs,
                                          const float* __restrict__ alsb,
                                          const int* __restrict__ csr,
                                          int s, int e, float ald, int cb,
                                          float& o0, float& o1, float& o2, float& o3)
{
  if (s >= e) return;
  float m = -1e30f, denom = 0.f, a0 = 0.f, a1 = 0.f, a2 = 0.f, a3 = 0.f;
  for (int i = s; i < e; i += 8) {
    int svv[8];
#pragma unroll
    for (int j = 0; j < 8; j++) {
      int idx = (i + j < e) ? (i + j) : (e - 1);
      svv[j] = csr[idx];
    }
    float als[8]; ushort4 hv[8];
#pragma unroll
    for (int j = 0; j < 8; j++) {
      als[j] = alsb[(size_t)svv[j] * STRIDE];
      hv[j] = *(const ushort4*)(hs + (size_t)svv[j] * 256 + cb);
    }
    float lg[8];
#pragma unroll
    for (int j = 0; j < 8; j++) {
      float l = als[j] + ald;
      l = l > 0.f ? l : 0.2f * l;
      lg[j] = (i + j < e) ? l : -1e30f;
    }
    float mb = fmaxf(fmaxf(fmaxf(lg[0], lg[1]), fmaxf(lg[2], lg[3])),
                     fmaxf(fmaxf(lg[4], lg[5]), fmaxf(lg[6], lg[7])));
    float mn = fmaxf(m, mb);
    float corr = __expf(m - mn);
    m = mn;
    denom *= corr; a0 *= corr; a1 *= corr; a2 *= corr; a3 *= corr;
#pragma unroll
    for (int j = 0; j < 8; j++) {
      float p = __expf(lg[j] - mn);
      denom += p;
      a0 += p * b2f(hv[j].x);
      a1 += p * b2f(hv[j].y);
      a2 += p * b2f(hv[j].z);
      a3 += p * b2f(hv[j].w);
    }
  }
  float inv = denom > 0.f ? 1.f / denom : 0.f;
  o0 += a0 * inv; o1 += a1 * inv; o2 += a2 * inv; o3 += a3 * inv;
}

// merged msg: paper [0,25000), author [25000,37500). bias_base: 0 (l=0) / 3 (l=1)
__global__ __launch_bounds__(256) void msg_all_kernel(
    const unsigned short* __restrict__ hs0, const unsigned short* __restrict__ hs1,
    const unsigned short* __restrict__ hs2,
    const float* __restrict__ al_p, const float* __restrict__ al_a,
    const int* __restrict__ off0, const int* __restrict__ csr0,
    const int* __restrict__ off1, const int* __restrict__ csr1,
    const int* __restrict__ off2, const int* __restrict__ csr2,
    const unsigned short* __restrict__ cbias, int bias_base,
    void* __restrict__ out_p, void* __restrict__ out_a, int final_,
    const int* __restrict__ flag)
{
  int bx = blockIdx.x;
  int lane = threadIdx.x & 63;
  int h = lane >> 4;
  int cb = lane * 4;
  if (bx < 25000) {
    int n = bx * 4 + (threadIdx.x >> 6);
    float o0 = 0.f, o1 = 0.f, o2 = 0.f, o3 = 0.f;
    gat_accum<8>(hs0, al_a + h, csr0, off0[n], off0[n + 1], al_p[n * 16 + 8 + h], cb,
                 o0, o1, o2, o3);
    gat_accum<16>(hs1, al_p + h, csr1, off1[n], off1[n + 1], al_p[n * 16 + 12 + h], cb,
                  o0, o1, o2, o3);
    const unsigned short* bg0 = cbias + (size_t)(bias_base + 0) * 256;
    const unsigned short* bg1 = cbias + (size_t)(bias_base + 1) * 256;
    const ushort4 bv0 = *(const ushort4*)(bg0 + cb);
    const ushort4 bv1 = *(const ushort4*)(bg1 + cb);
    float v0 = o0 + b2f(bv0.x) + b2f(bv1.x); v0 = v0 > 0.f ? v0 : __expf(v0) - 1.f;
    float v1 = o1 + b2f(bv0.y) + b2f(bv1.y); v1 = v1 > 0.f ? v1 : __expf(v1) - 1.f;
    float v2 = o2 + b2f(bv0.z) + b2f(bv1.z); v2 = v2 > 0.f ? v2 : __expf(v2) - 1.f;
    float v3 = o3 + b2f(bv0.w) + b2f(bv1.w); v3 = v3 > 0.f ? v3 : __expf(v3) - 1.f;
    if (final_ && *flag) {
      float* of = (float*)out_p;
      f32x4 ov = {v0, v1, v2, v3};
      *(f32x4*)(of + (size_t)n * 256 + cb) = ov;
    } else {
      unsigned short* ob = (unsigned short*)out_p;
      ushort4 ov; ov.x = f2b(v0); ov.y = f2b(v1); ov.z = f2b(v2); ov.w = f2b(v3);
      *(ushort4*)(ob + (size_t)n * 256 + cb) = ov;
    }
  } else {
    int n = (bx - 25000) * 4 + (threadIdx.x >> 6);
    float o0 = 0.f, o1 = 0.f, o2 = 0.f, o3 = 0.f;
    gat_accum<16>(hs2, al_p + 4 + h, csr2, off2[n], off2[n + 1], al_a[n * 8 + 4 + h], cb,
                  o0, o1, o2, o3);
    const unsigned short* bg2 = cbias + (size_t)(bias_base + 2) * 256;
    const ushort4 bv = *(const ushort4*)(bg2 + cb);
    float v0 = o0 + b2f(bv.x); v0 = v0 > 0.f ? v0 : __expf(v0) - 1.f;
    float v1 = o1 + b2f(bv.y); v1 = v1 > 0.f ? v1 : __expf(v1) - 1.f;
    float v2 = o2 + b2f(bv.z); v2 = v2 > 0.f ? v2 : __expf(v2) - 1.f;
    float v3 = o3 + b2f(bv.w); v3 = v3 > 0.f ? v3 : __expf(v3) - 1.f;
    size_t elem = (size_t)n * 256 + cb + (final_ ? (size_t)NP * 256 : 0);
    if (final_ && *flag) {
      float* of = (float*)out_a;
      f32x4 ov = {v0, v1, v2, v3};
      *(f32x4*)(of + elem) = ov;
    } else {
      unsigned short* ob = (unsigned short*)out_a;
      ushort4 ov; ov.x = f2b(v0); ov.y = f2b(v1); ov.z = f2b(v2); ov.w = f2b(v3);
      *(ushort4*)(ob + elem) = ov;
    }
  }
}

extern "C" void kernel_launch(void* const* d_in, const int* in_sizes, int n_in,
                              void* d_out, int out_size, void* d_ws, size_t ws_size,
                              hipStream_t stream)
{
  const unsigned short* x_paper  = (const unsigned short*)d_in[0];
  const unsigned short* x_author = (const unsigned short*)d_in[1];
  const unsigned short* W_in_p   = (const unsigned short*)d_in[2];
  const unsigned short* b_in_p   = (const unsigned short*)d_in[3];
  const unsigned short* W_in_a   = (const unsigned short*)d_in[4];
  const unsigned short* b_in_a   = (const unsigned short*)d_in[5];
  const unsigned short* lin_src  = (const unsigned short*)d_in[6];
  const unsigned short* lin_dst  = (const unsigned short*)d_in[7];
  const unsigned short* att_src  = (const unsigned short*)d_in[8];
  const unsigned short* att_dst  = (const unsigned short*)d_in[9];
  const unsigned short* bias_gat = (const unsigned short*)d_in[10];
  const int* writes_src = (const int*)d_in[11];
  const int* writes_dst = (const int*)d_in[12];
  const int* cites_src  = (const int*)d_in[13];
  const int* cites_dst  = (const int*)d_in[14];
  const int* wb_src     = (const int*)d_in[15];
  const int* wb_dst     = (const int*)d_in[16];

  char* base = (char*)d_ws;
  size_t cur = 0;
  auto take = [&](size_t bytes) -> char* {
    char* p = base + cur;
    cur += (bytes + 255) & ~(size_t)255;
    return p;
  };

  int* flag = (int*)take(256);
  unsigned short* cxp   = (unsigned short*)take((size_t)NP * 128 * 2);
  unsigned short* cxa   = (unsigned short*)take((size_t)NA * 128 * 2);
  unsigned short* cWinP = (unsigned short*)take(128 * 256 * 2);
  unsigned short* cWinA = (unsigned short*)take(128 * 256 * 2);
  unsigned short* cbinP = (unsigned short*)take(256 * 2);
  unsigned short* cbinA = (unsigned short*)take(256 * 2);
  unsigned short* clins = (unsigned short*)take((size_t)6 * 65536 * 2);
  unsigned short* clind = (unsigned short*)take((size_t)6 * 65536 * 2);
  unsigned short* catts = (unsigned short*)take(1536 * 2);
  unsigned short* cattd = (unsigned short*)take(1536 * 2);
  unsigned short* cbias = (unsigned short*)take(1536 * 2);

  unsigned short* xp  = (unsigned short*)take((size_t)NP * 256 * 2);
  unsigned short* xa  = (unsigned short*)take((size_t)NA * 256 * 2);
  unsigned short* hs0 = (unsigned short*)take((size_t)NA * 256 * 2);
  unsigned short* hs1 = (unsigned short*)take((size_t)NP * 256 * 2);
  unsigned short* hs2 = (unsigned short*)take((size_t)NP * 256 * 2);
  float* al_p = (float*)take((size_t)NP * 16 * 4);
  float* al_a = (float*)take((size_t)NA * 8 * 4);
  float* Wp   = (float*)take(2 * 256 * 16 * 4);
  float* Wa   = (float*)take(2 * 256 * 8 * 4);
  unsigned short* WinpT = (unsigned short*)take(256 * 128 * 2);
  unsigned short* WinaT = (unsigned short*)take(256 * 128 * 2);
  unsigned short* linsT = (unsigned short*)take((size_t)6 * 65536 * 2);
  int* off0 = (int*)take((size_t)(NP + 1) * 4);
  int* cur0 = (int*)take((size_t)NP * 4);
  int* csr0 = (int*)take((size_t)NE * 4);
  int* off1 = (int*)take((size_t)(NP + 1) * 4);
  int* cur1 = (int*)take((size_t)NP * 4);
  int* csr1 = (int*)take((size_t)NE * 4);
  int* off2 = (int*)take((size_t)(NA + 1) * 4);
  int* cur2 = (int*)take((size_t)NA * 4);
  int* csr2 = (int*)take((size_t)NE * 4);
  int* degAll = (int*)take((size_t)(2 * NP + NA) * 4);
  int* deg0 = degAll;
  int* deg1 = degAll + NP;
  int* deg2 = degAll + 2 * NP;
  int* bsum0 = (int*)take(64 * 4);
  int* bsum1 = (int*)take(64 * 4);
  int* bsum2 = (int*)take(64 * 4);

  probe_kernel<<<1, 256, 0, stream>>>(x_paper, flag);

  const long long CVN = (CV_E10 + 255) / 256;
  conv_all_kernel<<<(unsigned)CVN, 256, 0, stream>>>(
      x_paper, cxp, x_author, cxa, W_in_p, cWinP, W_in_a, cWinA,
      b_in_p, cbinP, b_in_a, cbinA, lin_src, clins, lin_dst, clind,
      att_src, catts, att_dst, cattd, bias_gat, cbias, flag);

  hipMemsetAsync(degAll, 0, (size_t)(2 * NP + NA) * 4, stream);

  fold_kernel<<<48, 256, 0, stream>>>(clins, clind, catts, cattd, Wp, Wa);
  transpose_all_kernel<<<458752 / 256, 256, 0, stream>>>(clins, linsT, cWinP, WinpT, cWinA, WinaT);

  hist3_kernel<<<(3 * NE + 255) / 256, 256, 0, stream>>>(writes_dst, cites_dst, wb_dst,
                                                         deg0, deg1, deg2);

  const int nbP = (NP + 2047) / 2048;   // 49
  const int nbA = (NA + 2047) / 2048;   // 25
  scan_partial3<<<dim3(nbP, 3), 256, 0, stream>>>(deg0, deg1, deg2, bsum0, bsum1, bsum2);
  scan_bsum3<<<3, 64, 0, stream>>>(bsum0, bsum1, bsum2, nbP, nbP, nbA);
  scan_emit3<<<dim3(nbP, 3), 256, 0, stream>>>(deg0, deg1, deg2, bsum0, bsum1, bsum2,
                                               off0, cur0, off1, cur1, off2, cur2);

  scatter3_kernel<<<(3 * NE + 255) / 256, 256, 0, stream>>>(
      writes_src, writes_dst, cites_src, cites_dst, wb_src, wb_dst,
      cur0, cur1, cur2, csr0, csr1, csr2);

  gemm_in_kernel<<<2345, 256, 0, stream>>>(cxp, WinpT, xp, cbinP, cxa, WinaT, xa, cbinA);

  for (int l = 0; l < 2; ++l) {
    layer_kernel<<<4495, 256, 0, stream>>>(
        xp, xa, linsT + (size_t)l * 3 * 65536, hs0, hs1, hs2,
        Wp + l * 4096, Wa + l * 2048, al_p, al_a);
    if (l == 0) {
      msg_all_kernel<<<37500, 256, 0, stream>>>(
          hs0, hs1, hs2, al_p, al_a, off0, csr0, off1, csr1, off2, csr2,
          cbias, 0, xp, xa, 0, flag);
    } else {
      msg_all_kernel<<<37500, 256, 0, stream>>>(
          hs0, hs1, hs2, al_p, al_a, off0, csr0, off1, csr1, off2, csr2,
          cbias, 3, d_out, d_out, 1, flag);
    }
  }
}

// Round 5
// 820.934 us; speedup vs baseline: 1.5256x; 1.0869x over previous
//
#include <hip/hip_runtime.h>

// HeteroGAT on MI355X. Round 8:
//  - msg: 4-wide batching (was 8: deg~2.5 made padding 3.2x), online-max
//    REMOVED (exp(clamp(lg,60)) directly; softmax shift-invariant, logits O(3))
//    -> no serial corr chain, ~35% fewer VALU ops/slot. uint2 bf16 unpack.
//  - gemm_body: MFMA operands swapped (computes C^T fragment) so each lane
//    holds 4 consecutive cols of one row -> packed 8B stores (was 2B scalar,
//    4x write amplification in L2 sectors).
//  - pipeline structure identical to round-7 (15 launches).

#define NP 100000
#define NA 50000
#define NE 250000

typedef __attribute__((ext_vector_type(8))) short short8;
typedef __attribute__((ext_vector_type(4))) float f32x4;

__device__ __forceinline__ float b2f(unsigned short u) {
  union { unsigned int i; float f; } v; v.i = ((unsigned int)u) << 16; return v.f;
}
__device__ __forceinline__ float u2f_lo(unsigned int u) {
  union { unsigned int i; float f; } v; v.i = u << 16; return v.f;
}
__device__ __forceinline__ float u2f_hi(unsigned int u) {
  union { unsigned int i; float f; } v; v.i = u & 0xffff0000u; return v.f;
}
__device__ __forceinline__ unsigned short f2b(float f) {
  union { float f; unsigned int i; } v; v.f = f;
  unsigned int u = v.i;
  return (unsigned short)((u + 0x7fffu + ((u >> 16) & 1u)) >> 16);
}

__global__ void probe_kernel(const unsigned short* __restrict__ x, int* __restrict__ flag)
{
  __shared__ int cnt;
  if (threadIdx.x == 0) cnt = 0;
  __syncthreads();
  int c = 0;
  for (int i = threadIdx.x; i < 4096; i += 256) {
    unsigned int e = (x[i] >> 7) & 0xFFu;
    if (e >= 0xC0u) c++;
  }
  atomicAdd(&cnt, c);
  __syncthreads();
  if (threadIdx.x == 0) *flag = (cnt > 64) ? 1 : 0;   // 1 = inputs are fp32
}

// ---- fused bf16-conversion of all 11 input tensors in one launch ----
#define CV_E0 12800000LL
#define CV_E1 19200000LL
#define CV_E2 19232768LL
#define CV_E3 19265536LL
#define CV_E4 19265792LL
#define CV_E5 19266048LL
#define CV_E6 19659264LL
#define CV_E7 20052480LL
#define CV_E8 20054016LL
#define CV_E9 20055552LL
#define CV_E10 20057088LL

__global__ void conv_all_kernel(
    const unsigned short* __restrict__ s0, unsigned short* __restrict__ d0,
    const unsigned short* __restrict__ s1, unsigned short* __restrict__ d1,
    const unsigned short* __restrict__ s2, unsigned short* __restrict__ d2,
    const unsigned short* __restrict__ s3, unsigned short* __restrict__ d3,
    const unsigned short* __restrict__ s4, unsigned short* __restrict__ d4,
    const unsigned short* __restrict__ s5, unsigned short* __restrict__ d5,
    const unsigned short* __restrict__ s6, unsigned short* __restrict__ d6,
    const unsigned short* __restrict__ s7, unsigned short* __restrict__ d7,
    const unsigned short* __restrict__ s8, unsigned short* __restrict__ d8,
    const unsigned short* __restrict__ s9, unsigned short* __restrict__ d9,
    const unsigned short* __restrict__ s10, unsigned short* __restrict__ d10,
    const int* __restrict__ flag)
{
  long long idx = (long long)blockIdx.x * 256 + threadIdx.x;
  if (idx >= CV_E10) return;
  int f = *flag;
  const unsigned short* s; unsigned short* d; long long off;
  if (idx < CV_E0)      { s = s0;  d = d0;  off = idx; }
  else if (idx < CV_E1) { s = s1;  d = d1;  off = idx - CV_E0; }
  else if (idx < CV_E2) { s = s2;  d = d2;  off = idx - CV_E1; }
  else if (idx < CV_E3) { s = s3;  d = d3;  off = idx - CV_E2; }
  else if (idx < CV_E4) { s = s4;  d = d4;  off = idx - CV_E3; }
  else if (idx < CV_E5) { s = s5;  d = d5;  off = idx - CV_E4; }
  else if (idx < CV_E6) { s = s6;  d = d6;  off = idx - CV_E5; }
  else if (idx < CV_E7) { s = s7;  d = d7;  off = idx - CV_E6; }
  else if (idx < CV_E8) { s = s8;  d = d8;  off = idx - CV_E7; }
  else if (idx < CV_E9) { s = s9;  d = d9;  off = idx - CV_E8; }
  else                  { s = s10; d = d10; off = idx - CV_E9; }
  if (f) d[off] = f2b(((const float*)s)[off]);
  else   d[off] = s[off];
}

// Skinny GEMM body: C[M x 256] = A[M x K] * BT[256 x K]^T, bf16 in/out, f32 acc.
// BM=64, BN=256. Whole-K A tile in LDS via global_load_lds(16B), XOR-swizzled
// source + swizzled ds_read (conflict-free). B from global (L2). 4 waves.
// MFMA called as mfma(bq, af) -> lane holds 4 CONSECUTIVE COLS of one row
// (C^T fragment) -> packed 8B row-major stores (sector-aligned writes).
template <int K, int RELU>
__device__ __forceinline__ void gemm_body(
    const unsigned short* __restrict__ A, const unsigned short* __restrict__ BT,
    unsigned short* __restrict__ C, int M, const unsigned short* __restrict__ bias,
    int bx, unsigned short* As)
{
  constexpr int SLOT = K / 8;               // 16B slots per row (32 or 16)
  const int t = threadIdx.x;
  const int lane = t & 63;
  const int w = t >> 6;                     // wave id 0..3 -> 64-col group
  const int quad = lane >> 4;
  const int l16 = lane & 15;
  const int m0 = bx * 64;

  {
    constexpr int CALLS = (64 * SLOT) / 256;
#pragma unroll
    for (int c = 0; c < CALLS; c++) {
      int slot = c * 256 + t;
      int row = slot / SLOT;
      int c16 = slot % SLOT;
      int gr = m0 + row; gr = gr < M ? gr : (M - 1);
      int gc16 = c16 ^ (row & 7);
      const unsigned short* gp = A + (size_t)gr * K + gc16 * 8;
      unsigned short* lp = As + (size_t)(c * 256 + (t & ~63)) * 8;
      __builtin_amdgcn_global_load_lds(
          (const __attribute__((address_space(1))) unsigned int*)gp,
          (__attribute__((address_space(3))) unsigned int*)lp, 16, 0, 0);
    }
  }
  __syncthreads();

  f32x4 acc[4][4];
#pragma unroll
  for (int i = 0; i < 4; i++)
#pragma unroll
    for (int j = 0; j < 4; j++) { acc[i][j][0] = 0.f; acc[i][j][1] = 0.f; acc[i][j][2] = 0.f; acc[i][j][3] = 0.f; }

  const int colbase = w * 64;
#pragma unroll 1
  for (int kc = 0; kc < K / 32; ++kc) {
    short8 af[4], bq[4];
#pragma unroll
    for (int i = 0; i < 4; i++) {
      int row = i * 16 + l16;
      int c16 = (kc * 4 + quad) ^ (row & 7);
      af[i] = *(const short8*)(As + (size_t)row * K + c16 * 8);
    }
#pragma unroll
    for (int j = 0; j < 4; j++)
      bq[j] = *(const short8*)(BT + (size_t)(colbase + j * 16 + l16) * K + kc * 32 + quad * 8);
#pragma unroll
    for (int i = 0; i < 4; i++)
#pragma unroll
      for (int j = 0; j < 4; j++)
        acc[i][j] = __builtin_amdgcn_mfma_f32_16x16x32_bf16(bq[j], af[i], acc[i][j], 0, 0, 0);
  }

  // acc[i][j][r] = C[m0 + i*16 + l16][colbase + j*16 + quad*4 + r]
#pragma unroll
  for (int i = 0; i < 4; i++) {
    int row = m0 + i * 16 + l16;
    if (row < M) {
#pragma unroll
      for (int j = 0; j < 4; j++) {
        int col0 = colbase + j * 16 + quad * 4;
        float b0 = 0.f, b1 = 0.f, b2 = 0.f, b3 = 0.f;
        if (bias) {
          const ushort4 bb = *(const ushort4*)(bias + col0);
          b0 = b2f(bb.x); b1 = b2f(bb.y); b2 = b2f(bb.z); b3 = b2f(bb.w);
        }
        float v0 = acc[i][j][0] + b0;
        float v1 = acc[i][j][1] + b1;
        float v2 = acc[i][j][2] + b2;
        float v3 = acc[i][j][3] + b3;
        if (RELU) {
          v0 = v0 > 0.f ? v0 : 0.f; v1 = v1 > 0.f ? v1 : 0.f;
          v2 = v2 > 0.f ? v2 : 0.f; v3 = v3 > 0.f ? v3 : 0.f;
        }
        ushort4 ov; ov.x = f2b(v0); ov.y = f2b(v1); ov.z = f2b(v2); ov.w = f2b(v3);
        *(ushort4*)(C + (size_t)row * 256 + col0) = ov;
      }
    }
  }
}

// al body: out[row, 0..NCOL) = X[row,:256] (bf16) dot W[:,j] (f32)
template <int NCOL>
__device__ __forceinline__ void al_body(const unsigned short* __restrict__ X, int rows,
                                        const float* __restrict__ W, float* __restrict__ out,
                                        int bx, float* Ws)
{
  for (int i = threadIdx.x; i < 256 * NCOL; i += 256) Ws[i] = W[i];
  __syncthreads();
  int row = bx * 256 + threadIdx.x;
  if (row >= rows) return;
  f32x4 acc[NCOL / 4];
#pragma unroll
  for (int jv = 0; jv < NCOL / 4; jv++) { acc[jv][0] = 0.f; acc[jv][1] = 0.f; acc[jv][2] = 0.f; acc[jv][3] = 0.f; }
  const unsigned short* xr = X + (size_t)row * 256;
  for (int k = 0; k < 256; k += 8) {
    uint4 pk = *(const uint4*)(xr + k);
    unsigned int uu[4] = {pk.x, pk.y, pk.z, pk.w};
#pragma unroll
    for (int e2 = 0; e2 < 4; e2++) {
      float x0 = b2f((unsigned short)(uu[e2] & 0xffffu));
      float x1 = b2f((unsigned short)(uu[e2] >> 16));
      int k0 = k + e2 * 2;
#pragma unroll
      for (int jv = 0; jv < NCOL / 4; jv++) {
        const f32x4 w0 = *(const f32x4*)&Ws[k0 * NCOL + jv * 4];
        const f32x4 w1 = *(const f32x4*)&Ws[(k0 + 1) * NCOL + jv * 4];
#pragma unroll
        for (int c = 0; c < 4; c++) acc[jv][c] += x0 * w0[c] + x1 * w1[c];
      }
    }
  }
#pragma unroll
  for (int jv = 0; jv < NCOL / 4; jv++)
    *(f32x4*)&out[(size_t)row * NCOL + jv * 4] = acc[jv];
}

// merged input gemms: [0,1563) paper K=128, [1563,2345) author K=128
__global__ __launch_bounds__(256) void gemm_in_kernel(
    const unsigned short* __restrict__ cxp, const unsigned short* __restrict__ WinpT,
    unsigned short* __restrict__ xp, const unsigned short* __restrict__ cbinP,
    const unsigned short* __restrict__ cxa, const unsigned short* __restrict__ WinaT,
    unsigned short* __restrict__ xa, const unsigned short* __restrict__ cbinA)
{
  __shared__ __align__(16) unsigned short As[64 * 128];
  int bx = blockIdx.x;
  if (bx < 1563) gemm_body<128, 1>(cxp, WinpT, xp, NP, cbinP, bx, As);
  else           gemm_body<128, 1>(cxa, WinaT, xa, NA, cbinA, bx - 1563, As);
}

// merged per-layer compute: hs0 [0,782), hs1 [782,2345), hs2 [2345,3908),
// al_p [3908,4299), al_a [4299,4495)
__global__ __launch_bounds__(256) void layer_kernel(
    const unsigned short* __restrict__ xp, const unsigned short* __restrict__ xa,
    const unsigned short* __restrict__ linsT_l,
    unsigned short* __restrict__ hs0, unsigned short* __restrict__ hs1,
    unsigned short* __restrict__ hs2,
    const float* __restrict__ Wp_l, const float* __restrict__ Wa_l,
    float* __restrict__ al_p, float* __restrict__ al_a)
{
  __shared__ __align__(16) unsigned short smem[64 * 256];   // 32 KB union
  int bx = blockIdx.x;
  if (bx < 782)       gemm_body<256, 0>(xa, linsT_l + 0 * 65536, hs0, NA, nullptr, bx, smem);
  else if (bx < 2345) gemm_body<256, 0>(xp, linsT_l + 1 * 65536, hs1, NP, nullptr, bx - 782, smem);
  else if (bx < 3908) gemm_body<256, 0>(xp, linsT_l + 2 * 65536, hs2, NP, nullptr, bx - 2345, smem);
  else if (bx < 4299) al_body<16>(xp, NP, Wp_l, al_p, bx - 3908, (float*)smem);
  else                al_body<8>(xa, NA, Wa_l, al_a, bx - 4299, (float*)smem);
}

// Wp cols: 0-3 al_s(t=1), 4-7 al_s(t=2), 8-11 al_d(t=0), 12-15 al_d(t=1)
// Wa cols: 0-3 al_s(t=0), 4-7 al_d(t=2)
__global__ void fold_kernel(const unsigned short* __restrict__ lin_src,
                            const unsigned short* __restrict__ lin_dst,
                            const unsigned short* __restrict__ att_src,
                            const unsigned short* __restrict__ att_dst,
                            float* __restrict__ Wp, float* __restrict__ Wa)
{
  int idx = blockIdx.x * 256 + threadIdx.x;
  if (idx >= 12288) return;
  const unsigned short *L, *At;
  int l, k, j, t, h;
  if (idx < 8192) {
    l = idx >> 12; int rem = idx & 4095; k = rem >> 4; j = rem & 15;
    if (j < 4)       { t = 1; h = j;      L = lin_src; At = att_src; }
    else if (j < 8)  { t = 2; h = j - 4;  L = lin_src; At = att_src; }
    else if (j < 12) { t = 0; h = j - 8;  L = lin_dst; At = att_dst; }
    else             { t = 1; h = j - 12; L = lin_dst; At = att_dst; }
    int lt = l * 3 + t;
    float s = 0.f;
    for (int c = 0; c < 64; c++)
      s += b2f(L[((size_t)lt * 256 + k) * 256 + h * 64 + c]) * b2f(At[(lt * 4 + h) * 64 + c]);
    Wp[l * 4096 + k * 16 + j] = s;
  } else {
    int i2 = idx - 8192;
    l = i2 >> 11; int rem = i2 & 2047; k = rem >> 3; j = rem & 7;
    if (j < 4) { t = 0; h = j;     L = lin_src; At = att_src; }
    else       { t = 2; h = j - 4; L = lin_dst; At = att_dst; }
    int lt = l * 3 + t;
    float s = 0.f;
    for (int c = 0; c < 64; c++)
      s += b2f(L[((size_t)lt * 256 + k) * 256 + h * 64 + c]) * b2f(At[(lt * 4 + h) * 64 + c]);
    Wa[l * 2048 + k * 8 + j] = s;
  }
}

// merged transposes: lins(6x256x256) [0,393216), WinP [393216,425984), WinA [..458752)
__global__ void transpose_all_kernel(const unsigned short* __restrict__ clins,
                                     unsigned short* __restrict__ linsT,
                                     const unsigned short* __restrict__ cWinP,
                                     unsigned short* __restrict__ WinpT,
                                     const unsigned short* __restrict__ cWinA,
                                     unsigned short* __restrict__ WinaT)
{
  int idx = blockIdx.x * 256 + threadIdx.x;
  if (idx < 393216) {
    int b = idx >> 16; int rem = idx & 65535; int k = rem >> 8; int n = rem & 255;
    linsT[(size_t)b * 65536 + n * 256 + k] = clins[idx];
  } else if (idx < 425984) {
    int i2 = idx - 393216; int k = i2 >> 8; int n = i2 & 255;
    WinpT[n * 128 + k] = cWinP[i2];
  } else if (idx < 458752) {
    int i2 = idx - 425984; int k = i2 >> 8; int n = i2 & 255;
    WinaT[n * 128 + k] = cWinA[i2];
  }
}

__global__ void hist3_kernel(const int* __restrict__ wdst, const int* __restrict__ cdst,
                             const int* __restrict__ adst,
                             int* __restrict__ deg0, int* __restrict__ deg1, int* __restrict__ deg2)
{
  int idx = blockIdx.x * 256 + threadIdx.x;
  if (idx < NE)          atomicAdd(&deg0[wdst[idx]], 1);
  else if (idx < 2 * NE) atomicAdd(&deg1[cdst[idx - NE]], 1);
  else if (idx < 3 * NE) atomicAdd(&deg2[adst[idx - 2 * NE]], 1);
}

// ---------------- hierarchical scan, 3 edge-types per launch via blockIdx.y
__global__ __launch_bounds__(256) void scan_partial3(const int* __restrict__ deg0,
                                                     const int* __restrict__ deg1,
                                                     const int* __restrict__ deg2,
                                                     int* __restrict__ b0, int* __restrict__ b1,
                                                     int* __restrict__ b2)
{
  const int* deg; int n; int* bs;
  if (blockIdx.y == 0)      { deg = deg0; n = NP; bs = b0; }
  else if (blockIdx.y == 1) { deg = deg1; n = NP; bs = b1; }
  else                      { deg = deg2; n = NA; bs = b2; }
  if ((int)blockIdx.x * 2048 >= n) return;
  int tid = threadIdx.x;
  int base = blockIdx.x * 2048 + tid * 8;
  int s = 0;
#pragma unroll
  for (int i = 0; i < 8; i++) { int idx = base + i; if (idx < n) s += deg[idx]; }
  __shared__ int red[256];
  red[tid] = s;
  __syncthreads();
  for (int d = 128; d > 0; d >>= 1) {
    if (tid < d) red[tid] += red[tid + d];
    __syncthreads();
  }
  if (tid == 0) bs[blockIdx.x] = red[0];
}

// three blocks, one wave each; nb <= 64. In-place exclusive scan of block sums.
__global__ void scan_bsum3(int* __restrict__ b0, int* __restrict__ b1, int* __restrict__ b2,
                           int nb0, int nb1, int nb2)
{
  int* bsum; int nb;
  if (blockIdx.x == 0)      { bsum = b0; nb = nb0; }
  else if (blockIdx.x == 1) { bsum = b1; nb = nb1; }
  else                      { bsum = b2; nb = nb2; }
  int lane = threadIdx.x;
  int orig = (lane < nb) ? bsum[lane] : 0;
  int v = orig;
  for (int d = 1; d < 64; d <<= 1) {
    int t = __shfl_up(v, d);
    if (lane >= d) v += t;
  }
  if (lane < nb) bsum[lane] = v - orig;   // exclusive
}

__global__ __launch_bounds__(256) void scan_emit3(const int* __restrict__ deg0,
                                                  const int* __restrict__ deg1,
                                                  const int* __restrict__ deg2,
                                                  const int* __restrict__ b0,
                                                  const int* __restrict__ b1,
                                                  const int* __restrict__ b2,
                                                  int* __restrict__ off0a, int* __restrict__ cur0a,
                                                  int* __restrict__ off1a, int* __restrict__ cur1a,
                                                  int* __restrict__ off2a, int* __restrict__ cur2a)
{
  const int* deg; int n; const int* bsum; int* off; int* cur;
  if (blockIdx.y == 0)      { deg = deg0; n = NP; bsum = b0; off = off0a; cur = cur0a; }
  else if (blockIdx.y == 1) { deg = deg1; n = NP; bsum = b1; off = off1a; cur = cur1a; }
  else                      { deg = deg2; n = NA; bsum = b2; off = off2a; cur = cur2a; }
  if ((int)blockIdx.x * 2048 >= n) return;
  int tid = threadIdx.x;
  int base = blockIdx.x * 2048 + tid * 8;
  int vals[8]; int s = 0;
#pragma unroll
  for (int i = 0; i < 8; i++) { int idx = base + i; vals[i] = (idx < n) ? deg[idx] : 0; s += vals[i]; }
  __shared__ int sh[256];
  sh[tid] = s;
  __syncthreads();
  for (int d = 1; d < 256; d <<= 1) {
    int t = (tid >= d) ? sh[tid - d] : 0;
    __syncthreads();
    sh[tid] += t;
    __syncthreads();
  }
  int run = bsum[blockIdx.x] + sh[tid] - s;   // exclusive prefix for this thread's chunk
#pragma unroll
  for (int i = 0; i < 8; i++) {
    int idx = base + i;
    if (idx < n) { off[idx] = run; cur[idx] = run; run += vals[i]; }
  }
  if (blockIdx.x == 0 && tid == 0) off[n] = NE;
}

__global__ void scatter3_kernel(const int* __restrict__ ws, const int* __restrict__ wd,
                                const int* __restrict__ cs, const int* __restrict__ cd,
                                const int* __restrict__ as, const int* __restrict__ ad,
                                int* __restrict__ cur0, int* __restrict__ cur1, int* __restrict__ cur2,
                                int* __restrict__ csr0, int* __restrict__ csr1, int* __restrict__ csr2)
{
  int idx = blockIdx.x * 256 + threadIdx.x;
  if (idx < NE) {
    int p = atomicAdd(&cur0[wd[idx]], 1); csr0[p] = ws[idx];
  } else if (idx < 2 * NE) {
    int e = idx - NE;
    int p = atomicAdd(&cur1[cd[e]], 1); csr1[p] = cs[e];
  } else if (idx < 3 * NE) {
    int e = idx - 2 * NE;
    int p = atomicAdd(&cur2[ad[e]], 1); csr2[p] = as[e];
  }
}

// 4-wide-batched GAT accumulation, NO online max: p = exp(min(lg,60)) directly
// (softmax is shift-invariant; logits here are O(3), clamp guards overflow).
// Padded slots duplicate the last edge (valid address) and get p=0.
template <int STRIDE>
__device__ __forceinline__ void gat_accum(const unsigned short* __restrict__ hs,
                                          const float* __restrict__ alsb,
                                          const int* __restrict__ csr,
                                          int s, int e, float ald, int cb,
                                          float& o0, float& o1, float& o2, float& o3)
{
  if (s >= e) return;
  float denom = 0.f, a0 = 0.f, a1 = 0.f, a2 = 0.f, a3 = 0.f;
  for (int i = s; i < e; i += 4) {
    int svv[4];
#pragma unroll
    for (int j = 0; j < 4; j++) {
      int idx = (i + j < e) ? (i + j) : (e - 1);
      svv[j] = csr[idx];
    }
    float als[4]; uint2 hv[4];
#pragma unroll
    for (int j = 0; j < 4; j++) {
      als[j] = alsb[(size_t)svv[j] * STRIDE];
      hv[j] = *(const uint2*)(hs + (size_t)svv[j] * 256 + cb);
    }
#pragma unroll
    for (int j = 0; j < 4; j++) {
      float l = als[j] + ald;
      l = l > 0.f ? l : 0.2f * l;
      l = fminf(l, 60.f);
      float p = (i + j < e) ? __expf(l) : 0.f;
      denom += p;
      a0 += p * u2f_lo(hv[j].x);
      a1 += p * u2f_hi(hv[j].x);
      a2 += p * u2f_lo(hv[j].y);
      a3 += p * u2f_hi(hv[j].y);
    }
  }
  float inv = denom > 0.f ? 1.f / denom : 0.f;
  o0 += a0 * inv; o1 += a1 * inv; o2 += a2 * inv; o3 += a3 * inv;
}

// merged msg: paper [0,25000), author [25000,37500). bias_base: 0 (l=0) / 3 (l=1)
__global__ __launch_bounds__(256) void msg_all_kernel(
    const unsigned short* __restrict__ hs0, const unsigned short* __restrict__ hs1,
    const unsigned short* __restrict__ hs2,
    const float* __restrict__ al_p, const float* __restrict__ al_a,
    const int* __restrict__ off0, const int* __restrict__ csr0,
    const int* __restrict__ off1, const int* __restrict__ csr1,
    const int* __restrict__ off2, const int* __restrict__ csr2,
    const unsigned short* __restrict__ cbias, int bias_base,
    void* __restrict__ out_p, void* __restrict__ out_a, int final_,
    const int* __restrict__ flag)
{
  int bx = blockIdx.x;
  int lane = threadIdx.x & 63;
  int h = lane >> 4;
  int cb = lane * 4;
  if (bx < 25000) {
    int n = bx * 4 + (threadIdx.x >> 6);
    float o0 = 0.f, o1 = 0.f, o2 = 0.f, o3 = 0.f;
    gat_accum<8>(hs0, al_a + h, csr0, off0[n], off0[n + 1], al_p[n * 16 + 8 + h], cb,
                 o0, o1, o2, o3);
    gat_accum<16>(hs1, al_p + h, csr1, off1[n], off1[n + 1], al_p[n * 16 + 12 + h], cb,
                  o0, o1, o2, o3);
    const unsigned short* bg0 = cbias + (size_t)(bias_base + 0) * 256;
    const unsigned short* bg1 = cbias + (size_t)(bias_base + 1) * 256;
    const ushort4 bv0 = *(const ushort4*)(bg0 + cb);
    const ushort4 bv1 = *(const ushort4*)(bg1 + cb);
    float v0 = o0 + b2f(bv0.x) + b2f(bv1.x); v0 = v0 > 0.f ? v0 : __expf(v0) - 1.f;
    float v1 = o1 + b2f(bv0.y) + b2f(bv1.y); v1 = v1 > 0.f ? v1 : __expf(v1) - 1.f;
    float v2 = o2 + b2f(bv0.z) + b2f(bv1.z); v2 = v2 > 0.f ? v2 : __expf(v2) - 1.f;
    float v3 = o3 + b2f(bv0.w) + b2f(bv1.w); v3 = v3 > 0.f ? v3 : __expf(v3) - 1.f;
    if (final_ && *flag) {
      float* of = (float*)out_p;
      f32x4 ov = {v0, v1, v2, v3};
      *(f32x4*)(of + (size_t)n * 256 + cb) = ov;
    } else {
      unsigned short* ob = (unsigned short*)out_p;
      ushort4 ov; ov.x = f2b(v0); ov.y = f2b(v1); ov.z = f2b(v2); ov.w = f2b(v3);
      *(ushort4*)(ob + (size_t)n * 256 + cb) = ov;
    }
  } else {
    int n = (bx - 25000) * 4 + (threadIdx.x >> 6);
    float o0 = 0.f, o1 = 0.f, o2 = 0.f, o3 = 0.f;
    gat_accum<16>(hs2, al_p + 4 + h, csr2, off2[n], off2[n + 1], al_a[n * 8 + 4 + h], cb,
                  o0, o1, o2, o3);
    const unsigned short* bg2 = cbias + (size_t)(bias_base + 2) * 256;
    const ushort4 bv = *(const ushort4*)(bg2 + cb);
    float v0 = o0 + b2f(bv.x); v0 = v0 > 0.f ? v0 : __expf(v0) - 1.f;
    float v1 = o1 + b2f(bv.y); v1 = v1 > 0.f ? v1 : __expf(v1) - 1.f;
    float v2 = o2 + b2f(bv.z); v2 = v2 > 0.f ? v2 : __expf(v2) - 1.f;
    float v3 = o3 + b2f(bv.w); v3 = v3 > 0.f ? v3 : __expf(v3) - 1.f;
    size_t elem = (size_t)n * 256 + cb + (final_ ? (size_t)NP * 256 : 0);
    if (final_ && *flag) {
      float* of = (float*)out_a;
      f32x4 ov = {v0, v1, v2, v3};
      *(f32x4*)(of + elem) = ov;
    } else {
      unsigned short* ob = (unsigned short*)out_a;
      ushort4 ov; ov.x = f2b(v0); ov.y = f2b(v1); ov.z = f2b(v2); ov.w = f2b(v3);
      *(ushort4*)(ob + elem) = ov;
    }
  }
}

extern "C" void kernel_launch(void* const* d_in, const int* in_sizes, int n_in,
                              void* d_out, int out_size, void* d_ws, size_t ws_size,
                              hipStream_t stream)
{
  const unsigned short* x_paper  = (const unsigned short*)d_in[0];
  const unsigned short* x_author = (const unsigned short*)d_in[1];
  const unsigned short* W_in_p   = (const unsigned short*)d_in[2];
  const unsigned short* b_in_p   = (const unsigned short*)d_in[3];
  const unsigned short* W_in_a   = (const unsigned short*)d_in[4];
  const unsigned short* b_in_a   = (const unsigned short*)d_in[5];
  const unsigned short* lin_src  = (const unsigned short*)d_in[6];
  const unsigned short* lin_dst  = (const unsigned short*)d_in[7];
  const unsigned short* att_src  = (const unsigned short*)d_in[8];
  const unsigned short* att_dst  = (const unsigned short*)d_in[9];
  const unsigned short* bias_gat = (const unsigned short*)d_in[10];
  const int* writes_src = (const int*)d_in[11];
  const int* writes_dst = (const int*)d_in[12];
  const int* cites_src  = (const int*)d_in[13];
  const int* cites_dst  = (const int*)d_in[14];
  const int* wb_src     = (const int*)d_in[15];
  const int* wb_dst     = (const int*)d_in[16];

  char* base = (char*)d_ws;
  size_t cur = 0;
  auto take = [&](size_t bytes) -> char* {
    char* p = base + cur;
    cur += (bytes + 255) & ~(size_t)255;
    return p;
  };

  int* flag = (int*)take(256);
  unsigned short* cxp   = (unsigned short*)take((size_t)NP * 128 * 2);
  unsigned short* cxa   = (unsigned short*)take((size_t)NA * 128 * 2);
  unsigned short* cWinP = (unsigned short*)take(128 * 256 * 2);
  unsigned short* cWinA = (unsigned short*)take(128 * 256 * 2);
  unsigned short* cbinP = (unsigned short*)take(256 * 2);
  unsigned short* cbinA = (unsigned short*)take(256 * 2);
  unsigned short* clins = (unsigned short*)take((size_t)6 * 65536 * 2);
  unsigned short* clind = (unsigned short*)take((size_t)6 * 65536 * 2);
  unsigned short* catts = (unsigned short*)take(1536 * 2);
  unsigned short* cattd = (unsigned short*)take(1536 * 2);
  unsigned short* cbias = (unsigned short*)take(1536 * 2);

  unsigned short* xp  = (unsigned short*)take((size_t)NP * 256 * 2);
  unsigned short* xa  = (unsigned short*)take((size_t)NA * 256 * 2);
  unsigned short* hs0 = (unsigned short*)take((size_t)NA * 256 * 2);
  unsigned short* hs1 = (unsigned short*)take((size_t)NP * 256 * 2);
  unsigned short* hs2 = (unsigned short*)take((size_t)NP * 256 * 2);
  float* al_p = (float*)take((size_t)NP * 16 * 4);
  float* al_a = (float*)take((size_t)NA * 8 * 4);
  float* Wp   = (float*)take(2 * 256 * 16 * 4);
  float* Wa   = (float*)take(2 * 256 * 8 * 4);
  unsigned short* WinpT = (unsigned short*)take(256 * 128 * 2);
  unsigned short* WinaT = (unsigned short*)take(256 * 128 * 2);
  unsigned short* linsT = (unsigned short*)take((size_t)6 * 65536 * 2);
  int* off0 = (int*)take((size_t)(NP + 1) * 4);
  int* cur0 = (int*)take((size_t)NP * 4);
  int* csr0 = (int*)take((size_t)NE * 4);
  int* off1 = (int*)take((size_t)(NP + 1) * 4);
  int* cur1 = (int*)take((size_t)NP * 4);
  int* csr1 = (int*)take((size_t)NE * 4);
  int* off2 = (int*)take((size_t)(NA + 1) * 4);
  int* cur2 = (int*)take((size_t)NA * 4);
  int* csr2 = (int*)take((size_t)NE * 4);
  int* degAll = (int*)take((size_t)(2 * NP + NA) * 4);
  int* deg0 = degAll;
  int* deg1 = degAll + NP;
  int* deg2 = degAll + 2 * NP;
  int* bsum0 = (int*)take(64 * 4);
  int* bsum1 = (int*)take(64 * 4);
  int* bsum2 = (int*)take(64 * 4);

  probe_kernel<<<1, 256, 0, stream>>>(x_paper, flag);

  const long long CVN = (CV_E10 + 255) / 256;
  conv_all_kernel<<<(unsigned)CVN, 256, 0, stream>>>(
      x_paper, cxp, x_author, cxa, W_in_p, cWinP, W_in_a, cWinA,
      b_in_p, cbinP, b_in_a, cbinA, lin_src, clins, lin_dst, clind,
      att_src, catts, att_dst, cattd, bias_gat, cbias, flag);

  hipMemsetAsync(degAll, 0, (size_t)(2 * NP + NA) * 4, stream);

  fold_kernel<<<48, 256, 0, stream>>>(clins, clind, catts, cattd, Wp, Wa);
  transpose_all_kernel<<<458752 / 256, 256, 0, stream>>>(clins, linsT, cWinP, WinpT, cWinA, WinaT);

  hist3_kernel<<<(3 * NE + 255) / 256, 256, 0, stream>>>(writes_dst, cites_dst, wb_dst,
                                                         deg0, deg1, deg2);

  const int nbP = (NP + 2047) / 2048;   // 49
  const int nbA = (NA + 2047) / 2048;   // 25
  scan_partial3<<<dim3(nbP, 3), 256, 0, stream>>>(deg0, deg1, deg2, bsum0, bsum1, bsum2);
  scan_bsum3<<<3, 64, 0, stream>>>(bsum0, bsum1, bsum2, nbP, nbP, nbA);
  scan_emit3<<<dim3(nbP, 3), 256, 0, stream>>>(deg0, deg1, deg2, bsum0, bsum1, bsum2,
                                               off0, cur0, off1, cur1, off2, cur2);

  scatter3_kernel<<<(3 * NE + 255) / 256, 256, 0, stream>>>(
      writes_src, writes_dst, cites_src, cites_dst, wb_src, wb_dst,
      cur0, cur1, cur2, csr0, csr1, csr2);

  gemm_in_kernel<<<2345, 256, 0, stream>>>(cxp, WinpT, xp, cbinP, cxa, WinaT, xa, cbinA);

  for (int l = 0; l < 2; ++l) {
    layer_kernel<<<4495, 256, 0, stream>>>(
        xp, xa, linsT + (size_t)l * 3 * 65536, hs0, hs1, hs2,
        Wp + l * 4096, Wa + l * 2048, al_p, al_a);
    if (l == 0) {
      msg_all_kernel<<<37500, 256, 0, stream>>>(
          hs0, hs1, hs2, al_p, al_a, off0, csr0, off1, csr1, off2, csr2,
          cbias, 0, xp, xa, 0, flag);
    } else {
      msg_all_kernel<<<37500, 256, 0, stream>>>(
          hs0, hs1, hs2, al_p, al_a, off0, csr0, off1, csr1, off2, csr2,
          cbias, 3, d_out, d_out, 1, flag);
    }
  }
}

// Round 6
// 799.408 us; speedup vs baseline: 1.5667x; 1.0269x over previous
//
#include <hip/hip_runtime.h>

// HeteroGAT on MI355X. Round 9:
//  - gemm_body: ALL B fragments hoisted to registers up-front (bq[K/32][4],
//    issued as one deep VMEM burst right after the A-stage DMAs). The k-loop
//    is now pure LDS+MFMA -> no per-kc global-latency stall (round-5 counters:
//    34k cyc/block latency vs 1.5k of work). ~220 VGPR -> launch_bounds(256,2).
//  - everything else identical to the 821us round-8 pipeline.

#define NP 100000
#define NA 50000
#define NE 250000

typedef __attribute__((ext_vector_type(8))) short short8;
typedef __attribute__((ext_vector_type(4))) float f32x4;

__device__ __forceinline__ float b2f(unsigned short u) {
  union { unsigned int i; float f; } v; v.i = ((unsigned int)u) << 16; return v.f;
}
__device__ __forceinline__ float u2f_lo(unsigned int u) {
  union { unsigned int i; float f; } v; v.i = u << 16; return v.f;
}
__device__ __forceinline__ float u2f_hi(unsigned int u) {
  union { unsigned int i; float f; } v; v.i = u & 0xffff0000u; return v.f;
}
__device__ __forceinline__ unsigned short f2b(float f) {
  union { float f; unsigned int i; } v; v.f = f;
  unsigned int u = v.i;
  return (unsigned short)((u + 0x7fffu + ((u >> 16) & 1u)) >> 16);
}

__global__ void probe_kernel(const unsigned short* __restrict__ x, int* __restrict__ flag)
{
  __shared__ int cnt;
  if (threadIdx.x == 0) cnt = 0;
  __syncthreads();
  int c = 0;
  for (int i = threadIdx.x; i < 4096; i += 256) {
    unsigned int e = (x[i] >> 7) & 0xFFu;
    if (e >= 0xC0u) c++;
  }
  atomicAdd(&cnt, c);
  __syncthreads();
  if (threadIdx.x == 0) *flag = (cnt > 64) ? 1 : 0;   // 1 = inputs are fp32
}

// ---- fused bf16-conversion of all 11 input tensors in one launch ----
#define CV_E0 12800000LL
#define CV_E1 19200000LL
#define CV_E2 19232768LL
#define CV_E3 19265536LL
#define CV_E4 19265792LL
#define CV_E5 19266048LL
#define CV_E6 19659264LL
#define CV_E7 20052480LL
#define CV_E8 20054016LL
#define CV_E9 20055552LL
#define CV_E10 20057088LL

__global__ void conv_all_kernel(
    const unsigned short* __restrict__ s0, unsigned short* __restrict__ d0,
    const unsigned short* __restrict__ s1, unsigned short* __restrict__ d1,
    const unsigned short* __restrict__ s2, unsigned short* __restrict__ d2,
    const unsigned short* __restrict__ s3, unsigned short* __restrict__ d3,
    const unsigned short* __restrict__ s4, unsigned short* __restrict__ d4,
    const unsigned short* __restrict__ s5, unsigned short* __restrict__ d5,
    const unsigned short* __restrict__ s6, unsigned short* __restrict__ d6,
    const unsigned short* __restrict__ s7, unsigned short* __restrict__ d7,
    const unsigned short* __restrict__ s8, unsigned short* __restrict__ d8,
    const unsigned short* __restrict__ s9, unsigned short* __restrict__ d9,
    const unsigned short* __restrict__ s10, unsigned short* __restrict__ d10,
    const int* __restrict__ flag)
{
  long long idx = (long long)blockIdx.x * 256 + threadIdx.x;
  if (idx >= CV_E10) return;
  int f = *flag;
  const unsigned short* s; unsigned short* d; long long off;
  if (idx < CV_E0)      { s = s0;  d = d0;  off = idx; }
  else if (idx < CV_E1) { s = s1;  d = d1;  off = idx - CV_E0; }
  else if (idx < CV_E2) { s = s2;  d = d2;  off = idx - CV_E1; }
  else if (idx < CV_E3) { s = s3;  d = d3;  off = idx - CV_E2; }
  else if (idx < CV_E4) { s = s4;  d = d4;  off = idx - CV_E3; }
  else if (idx < CV_E5) { s = s5;  d = d5;  off = idx - CV_E4; }
  else if (idx < CV_E6) { s = s6;  d = d6;  off = idx - CV_E5; }
  else if (idx < CV_E7) { s = s7;  d = d7;  off = idx - CV_E6; }
  else if (idx < CV_E8) { s = s8;  d = d8;  off = idx - CV_E7; }
  else if (idx < CV_E9) { s = s9;  d = d9;  off = idx - CV_E8; }
  else                  { s = s10; d = d10; off = idx - CV_E9; }
  if (f) d[off] = f2b(((const float*)s)[off]);
  else   d[off] = s[off];
}

// Skinny GEMM body: C[M x 256] = A[M x K] * BT[256 x K]^T, bf16 in/out, f32 acc.
// BM=64, BN=256. A tile -> LDS via global_load_lds (XOR-swizzled source +
// swizzled ds_read). ALL B fragments -> registers in one up-front burst
// (bq[K/32][4] short8): the k-loop has zero global-memory latency.
// mfma(bq, af) -> lane holds 4 consecutive cols of one row -> packed 8B stores.
template <int K, int RELU>
__device__ __forceinline__ void gemm_body(
    const unsigned short* __restrict__ A, const unsigned short* __restrict__ BT,
    unsigned short* __restrict__ C, int M, const unsigned short* __restrict__ bias,
    int bx, unsigned short* As)
{
  constexpr int SLOT = K / 8;               // 16B slots per row (32 or 16)
  constexpr int NKC = K / 32;
  const int t = threadIdx.x;
  const int lane = t & 63;
  const int w = t >> 6;                     // wave id 0..3 -> 64-col group
  const int quad = lane >> 4;
  const int l16 = lane & 15;
  const int m0 = bx * 64;
  const int colbase = w * 64;

  // 1) issue A-stage DMAs (global -> LDS, swizzled source, linear dest)
  {
    constexpr int CALLS = (64 * SLOT) / 256;
#pragma unroll
    for (int c = 0; c < CALLS; c++) {
      int slot = c * 256 + t;
      int row = slot / SLOT;
      int c16 = slot % SLOT;
      int gr = m0 + row; gr = gr < M ? gr : (M - 1);
      int gc16 = c16 ^ (row & 7);
      const unsigned short* gp = A + (size_t)gr * K + gc16 * 8;
      unsigned short* lp = As + (size_t)(c * 256 + (t & ~63)) * 8;
      __builtin_amdgcn_global_load_lds(
          (const __attribute__((address_space(1))) unsigned int*)gp,
          (__attribute__((address_space(3))) unsigned int*)lp, 16, 0, 0);
    }
  }

  // 2) issue ALL B loads as one deep burst (32 VMEM ops for K=256)
  short8 bq[NKC][4];
#pragma unroll
  for (int kc = 0; kc < NKC; ++kc)
#pragma unroll
    for (int j = 0; j < 4; j++)
      bq[kc][j] = *(const short8*)(BT + (size_t)(colbase + j * 16 + l16) * K + kc * 32 + quad * 8);

  __syncthreads();

  f32x4 acc[4][4];
#pragma unroll
  for (int i = 0; i < 4; i++)
#pragma unroll
    for (int j = 0; j < 4; j++) { acc[i][j][0] = 0.f; acc[i][j][1] = 0.f; acc[i][j][2] = 0.f; acc[i][j][3] = 0.f; }

  // 3) pure LDS + MFMA loop
#pragma unroll
  for (int kc = 0; kc < NKC; ++kc) {
    short8 af[4];
#pragma unroll
    for (int i = 0; i < 4; i++) {
      int row = i * 16 + l16;
      int c16 = (kc * 4 + quad) ^ (row & 7);
      af[i] = *(const short8*)(As + (size_t)row * K + c16 * 8);
    }
#pragma unroll
    for (int i = 0; i < 4; i++)
#pragma unroll
      for (int j = 0; j < 4; j++)
        acc[i][j] = __builtin_amdgcn_mfma_f32_16x16x32_bf16(bq[kc][j], af[i], acc[i][j], 0, 0, 0);
  }

  // acc[i][j][r] = C[m0 + i*16 + l16][colbase + j*16 + quad*4 + r]
#pragma unroll
  for (int i = 0; i < 4; i++) {
    int row = m0 + i * 16 + l16;
    if (row < M) {
#pragma unroll
      for (int j = 0; j < 4; j++) {
        int col0 = colbase + j * 16 + quad * 4;
        float b0 = 0.f, b1 = 0.f, b2 = 0.f, b3 = 0.f;
        if (bias) {
          const ushort4 bb = *(const ushort4*)(bias + col0);
          b0 = b2f(bb.x); b1 = b2f(bb.y); b2 = b2f(bb.z); b3 = b2f(bb.w);
        }
        float v0 = acc[i][j][0] + b0;
        float v1 = acc[i][j][1] + b1;
        float v2 = acc[i][j][2] + b2;
        float v3 = acc[i][j][3] + b3;
        if (RELU) {
          v0 = v0 > 0.f ? v0 : 0.f; v1 = v1 > 0.f ? v1 : 0.f;
          v2 = v2 > 0.f ? v2 : 0.f; v3 = v3 > 0.f ? v3 : 0.f;
        }
        ushort4 ov; ov.x = f2b(v0); ov.y = f2b(v1); ov.z = f2b(v2); ov.w = f2b(v3);
        *(ushort4*)(C + (size_t)row * 256 + col0) = ov;
      }
    }
  }
}

// al body: out[row, 0..NCOL) = X[row,:256] (bf16) dot W[:,j] (f32)
template <int NCOL>
__device__ __forceinline__ void al_body(const unsigned short* __restrict__ X, int rows,
                                        const float* __restrict__ W, float* __restrict__ out,
                                        int bx, float* Ws)
{
  for (int i = threadIdx.x; i < 256 * NCOL; i += 256) Ws[i] = W[i];
  __syncthreads();
  int row = bx * 256 + threadIdx.x;
  if (row >= rows) return;
  f32x4 acc[NCOL / 4];
#pragma unroll
  for (int jv = 0; jv < NCOL / 4; jv++) { acc[jv][0] = 0.f; acc[jv][1] = 0.f; acc[jv][2] = 0.f; acc[jv][3] = 0.f; }
  const unsigned short* xr = X + (size_t)row * 256;
  for (int k = 0; k < 256; k += 8) {
    uint4 pk = *(const uint4*)(xr + k);
    unsigned int uu[4] = {pk.x, pk.y, pk.z, pk.w};
#pragma unroll
    for (int e2 = 0; e2 < 4; e2++) {
      float x0 = b2f((unsigned short)(uu[e2] & 0xffffu));
      float x1 = b2f((unsigned short)(uu[e2] >> 16));
      int k0 = k + e2 * 2;
#pragma unroll
      for (int jv = 0; jv < NCOL / 4; jv++) {
        const f32x4 w0 = *(const f32x4*)&Ws[k0 * NCOL + jv * 4];
        const f32x4 w1 = *(const f32x4*)&Ws[(k0 + 1) * NCOL + jv * 4];
#pragma unroll
        for (int c = 0; c < 4; c++) acc[jv][c] += x0 * w0[c] + x1 * w1[c];
      }
    }
  }
#pragma unroll
  for (int jv = 0; jv < NCOL / 4; jv++)
    *(f32x4*)&out[(size_t)row * NCOL + jv * 4] = acc[jv];
}

// merged input gemms: [0,1563) paper K=128, [1563,2345) author K=128
__global__ __launch_bounds__(256) void gemm_in_kernel(
    const unsigned short* __restrict__ cxp, const unsigned short* __restrict__ WinpT,
    unsigned short* __restrict__ xp, const unsigned short* __restrict__ cbinP,
    const unsigned short* __restrict__ cxa, const unsigned short* __restrict__ WinaT,
    unsigned short* __restrict__ xa, const unsigned short* __restrict__ cbinA)
{
  __shared__ __align__(16) unsigned short As[64 * 128];
  int bx = blockIdx.x;
  if (bx < 1563) gemm_body<128, 1>(cxp, WinpT, xp, NP, cbinP, bx, As);
  else           gemm_body<128, 1>(cxa, WinaT, xa, NA, cbinA, bx - 1563, As);
}

// merged per-layer compute: hs0 [0,782), hs1 [782,2345), hs2 [2345,3908),
// al_p [3908,4299), al_a [4299,4495)
__global__ __launch_bounds__(256, 2) void layer_kernel(
    const unsigned short* __restrict__ xp, const unsigned short* __restrict__ xa,
    const unsigned short* __restrict__ linsT_l,
    unsigned short* __restrict__ hs0, unsigned short* __restrict__ hs1,
    unsigned short* __restrict__ hs2,
    const float* __restrict__ Wp_l, const float* __restrict__ Wa_l,
    float* __restrict__ al_p, float* __restrict__ al_a)
{
  __shared__ __align__(16) unsigned short smem[64 * 256];   // 32 KB union
  int bx = blockIdx.x;
  if (bx < 782)       gemm_body<256, 0>(xa, linsT_l + 0 * 65536, hs0, NA, nullptr, bx, smem);
  else if (bx < 2345) gemm_body<256, 0>(xp, linsT_l + 1 * 65536, hs1, NP, nullptr, bx - 782, smem);
  else if (bx < 3908) gemm_body<256, 0>(xp, linsT_l + 2 * 65536, hs2, NP, nullptr, bx - 2345, smem);
  else if (bx < 4299) al_body<16>(xp, NP, Wp_l, al_p, bx - 3908, (float*)smem);
  else                al_body<8>(xa, NA, Wa_l, al_a, bx - 4299, (float*)smem);
}

// Wp cols: 0-3 al_s(t=1), 4-7 al_s(t=2), 8-11 al_d(t=0), 12-15 al_d(t=1)
// Wa cols: 0-3 al_s(t=0), 4-7 al_d(t=2)
__global__ void fold_kernel(const unsigned short* __restrict__ lin_src,
                            const unsigned short* __restrict__ lin_dst,
                            const unsigned short* __restrict__ att_src,
                            const unsigned short* __restrict__ att_dst,
                            float* __restrict__ Wp, float* __restrict__ Wa)
{
  int idx = blockIdx.x * 256 + threadIdx.x;
  if (idx >= 12288) return;
  const unsigned short *L, *At;
  int l, k, j, t, h;
  if (idx < 8192) {
    l = idx >> 12; int rem = idx & 4095; k = rem >> 4; j = rem & 15;
    if (j < 4)       { t = 1; h = j;      L = lin_src; At = att_src; }
    else if (j < 8)  { t = 2; h = j - 4;  L = lin_src; At = att_src; }
    else if (j < 12) { t = 0; h = j - 8;  L = lin_dst; At = att_dst; }
    else             { t = 1; h = j - 12; L = lin_dst; At = att_dst; }
    int lt = l * 3 + t;
    float s = 0.f;
    for (int c = 0; c < 64; c++)
      s += b2f(L[((size_t)lt * 256 + k) * 256 + h * 64 + c]) * b2f(At[(lt * 4 + h) * 64 + c]);
    Wp[l * 4096 + k * 16 + j] = s;
  } else {
    int i2 = idx - 8192;
    l = i2 >> 11; int rem = i2 & 2047; k = rem >> 3; j = rem & 7;
    if (j < 4) { t = 0; h = j;     L = lin_src; At = att_src; }
    else       { t = 2; h = j - 4; L = lin_dst; At = att_dst; }
    int lt = l * 3 + t;
    float s = 0.f;
    for (int c = 0; c < 64; c++)
      s += b2f(L[((size_t)lt * 256 + k) * 256 + h * 64 + c]) * b2f(At[(lt * 4 + h) * 64 + c]);
    Wa[l * 2048 + k * 8 + j] = s;
  }
}

// merged transposes: lins(6x256x256) [0,393216), WinP [393216,425984), WinA [..458752)
__global__ void transpose_all_kernel(const unsigned short* __restrict__ clins,
                                     unsigned short* __restrict__ linsT,
                                     const unsigned short* __restrict__ cWinP,
                                     unsigned short* __restrict__ WinpT,
                                     const unsigned short* __restrict__ cWinA,
                                     unsigned short* __restrict__ WinaT)
{
  int idx = blockIdx.x * 256 + threadIdx.x;
  if (idx < 393216) {
    int b = idx >> 16; int rem = idx & 65535; int k = rem >> 8; int n = rem & 255;
    linsT[(size_t)b * 65536 + n * 256 + k] = clins[idx];
  } else if (idx < 425984) {
    int i2 = idx - 393216; int k = i2 >> 8; int n = i2 & 255;
    WinpT[n * 128 + k] = cWinP[i2];
  } else if (idx < 458752) {
    int i2 = idx - 425984; int k = i2 >> 8; int n = i2 & 255;
    WinaT[n * 128 + k] = cWinA[i2];
  }
}

__global__ void hist3_kernel(const int* __restrict__ wdst, const int* __restrict__ cdst,
                             const int* __restrict__ adst,
                             int* __restrict__ deg0, int* __restrict__ deg1, int* __restrict__ deg2)
{
  int idx = blockIdx.x * 256 + threadIdx.x;
  if (idx < NE)          atomicAdd(&deg0[wdst[idx]], 1);
  else if (idx < 2 * NE) atomicAdd(&deg1[cdst[idx - NE]], 1);
  else if (idx < 3 * NE) atomicAdd(&deg2[adst[idx - 2 * NE]], 1);
}

// ---------------- hierarchical scan, 3 edge-types per launch via blockIdx.y
__global__ __launch_bounds__(256) void scan_partial3(const int* __restrict__ deg0,
                                                     const int* __restrict__ deg1,
                                                     const int* __restrict__ deg2,
                                                     int* __restrict__ b0, int* __restrict__ b1,
                                                     int* __restrict__ b2)
{
  const int* deg; int n; int* bs;
  if (blockIdx.y == 0)      { deg = deg0; n = NP; bs = b0; }
  else if (blockIdx.y == 1) { deg = deg1; n = NP; bs = b1; }
  else                      { deg = deg2; n = NA; bs = b2; }
  if ((int)blockIdx.x * 2048 >= n) return;
  int tid = threadIdx.x;
  int base = blockIdx.x * 2048 + tid * 8;
  int s = 0;
#pragma unroll
  for (int i = 0; i < 8; i++) { int idx = base + i; if (idx < n) s += deg[idx]; }
  __shared__ int red[256];
  red[tid] = s;
  __syncthreads();
  for (int d = 128; d > 0; d >>= 1) {
    if (tid < d) red[tid] += red[tid + d];
    __syncthreads();
  }
  if (tid == 0) bs[blockIdx.x] = red[0];
}

// three blocks, one wave each; nb <= 64. In-place exclusive scan of block sums.
__global__ void scan_bsum3(int* __restrict__ b0, int* __restrict__ b1, int* __restrict__ b2,
                           int nb0, int nb1, int nb2)
{
  int* bsum; int nb;
  if (blockIdx.x == 0)      { bsum = b0; nb = nb0; }
  else if (blockIdx.x == 1) { bsum = b1; nb = nb1; }
  else                      { bsum = b2; nb = nb2; }
  int lane = threadIdx.x;
  int orig = (lane < nb) ? bsum[lane] : 0;
  int v = orig;
  for (int d = 1; d < 64; d <<= 1) {
    int t = __shfl_up(v, d);
    if (lane >= d) v += t;
  }
  if (lane < nb) bsum[lane] = v - orig;   // exclusive
}

__global__ __launch_bounds__(256) void scan_emit3(const int* __restrict__ deg0,
                                                  const int* __restrict__ deg1,
                                                  const int* __restrict__ deg2,
                                                  const int* __restrict__ b0,
                                                  const int* __restrict__ b1,
                                                  const int* __restrict__ b2,
                                                  int* __restrict__ off0a, int* __restrict__ cur0a,
                                                  int* __restrict__ off1a, int* __restrict__ cur1a,
                                                  int* __restrict__ off2a, int* __restrict__ cur2a)
{
  const int* deg; int n; const int* bsum; int* off; int* cur;
  if (blockIdx.y == 0)      { deg = deg0; n = NP; bsum = b0; off = off0a; cur = cur0a; }
  else if (blockIdx.y == 1) { deg = deg1; n = NP; bsum = b1; off = off1a; cur = cur1a; }
  else                      { deg = deg2; n = NA; bsum = b2; off = off2a; cur = cur2a; }
  if ((int)blockIdx.x * 2048 >= n) return;
  int tid = threadIdx.x;
  int base = blockIdx.x * 2048 + tid * 8;
  int vals[8]; int s = 0;
#pragma unroll
  for (int i = 0; i < 8; i++) { int idx = base + i; vals[i] = (idx < n) ? deg[idx] : 0; s += vals[i]; }
  __shared__ int sh[256];
  sh[tid] = s;
  __syncthreads();
  for (int d = 1; d < 256; d <<= 1) {
    int t = (tid >= d) ? sh[tid - d] : 0;
    __syncthreads();
    sh[tid] += t;
    __syncthreads();
  }
  int run = bsum[blockIdx.x] + sh[tid] - s;   // exclusive prefix for this thread's chunk
#pragma unroll
  for (int i = 0; i < 8; i++) {
    int idx = base + i;
    if (idx < n) { off[idx] = run; cur[idx] = run; run += vals[i]; }
  }
  if (blockIdx.x == 0 && tid == 0) off[n] = NE;
}

__global__ void scatter3_kernel(const int* __restrict__ ws, const int* __restrict__ wd,
                                const int* __restrict__ cs, const int* __restrict__ cd,
                                const int* __restrict__ as, const int* __restrict__ ad,
                                int* __restrict__ cur0, int* __restrict__ cur1, int* __restrict__ cur2,
                                int* __restrict__ csr0, int* __restrict__ csr1, int* __restrict__ csr2)
{
  int idx = blockIdx.x * 256 + threadIdx.x;
  if (idx < NE) {
    int p = atomicAdd(&cur0[wd[idx]], 1); csr0[p] = ws[idx];
  } else if (idx < 2 * NE) {
    int e = idx - NE;
    int p = atomicAdd(&cur1[cd[e]], 1); csr1[p] = cs[e];
  } else if (idx < 3 * NE) {
    int e = idx - 2 * NE;
    int p = atomicAdd(&cur2[ad[e]], 1); csr2[p] = as[e];
  }
}

// 4-wide-batched GAT accumulation, NO online max: p = exp(min(lg,60)) directly
// (softmax shift-invariant; logits O(3), clamp guards overflow).
// Padded slots duplicate the last edge (valid address) and get p=0.
template <int STRIDE>
__device__ __forceinline__ void gat_accum(const unsigned short* __restrict__ hs,
                                          const float* __restrict__ alsb,
                                          const int* __restrict__ csr,
                                          int s, int e, float ald, int cb,
                                          float& o0, float& o1, float& o2, float& o3)
{
  if (s >= e) return;
  float denom = 0.f, a0 = 0.f, a1 = 0.f, a2 = 0.f, a3 = 0.f;
  for (int i = s; i < e; i += 4) {
    int svv[4];
#pragma unroll
    for (int j = 0; j < 4; j++) {
      int idx = (i + j < e) ? (i + j) : (e - 1);
      svv[j] = csr[idx];
    }
    float als[4]; uint2 hv[4];
#pragma unroll
    for (int j = 0; j < 4; j++) {
      als[j] = alsb[(size_t)svv[j] * STRIDE];
      hv[j] = *(const uint2*)(hs + (size_t)svv[j] * 256 + cb);
    }
#pragma unroll
    for (int j = 0; j < 4; j++) {
      float l = als[j] + ald;
      l = l > 0.f ? l : 0.2f * l;
      l = fminf(l, 60.f);
      float p = (i + j < e) ? __expf(l) : 0.f;
      denom += p;
      a0 += p * u2f_lo(hv[j].x);
      a1 += p * u2f_hi(hv[j].x);
      a2 += p * u2f_lo(hv[j].y);
      a3 += p * u2f_hi(hv[j].y);
    }
  }
  float inv = denom > 0.f ? 1.f / denom : 0.f;
  o0 += a0 * inv; o1 += a1 * inv; o2 += a2 * inv; o3 += a3 * inv;
}

// merged msg: paper [0,25000), author [25000,37500). bias_base: 0 (l=0) / 3 (l=1)
__global__ __launch_bounds__(256) void msg_all_kernel(
    const unsigned short* __restrict__ hs0, const unsigned short* __restrict__ hs1,
    const unsigned short* __restrict__ hs2,
    const float* __restrict__ al_p, const float* __restrict__ al_a,
    const int* __restrict__ off0, const int* __restrict__ csr0,
    const int* __restrict__ off1, const int* __restrict__ csr1,
    const int* __restrict__ off2, const int* __restrict__ csr2,
    const unsigned short* __restrict__ cbias, int bias_base,
    void* __restrict__ out_p, void* __restrict__ out_a, int final_,
    const int* __restrict__ flag)
{
  int bx = blockIdx.x;
  int lane = threadIdx.x & 63;
  int h = lane >> 4;
  int cb = lane * 4;
  if (bx < 25000) {
    int n = bx * 4 + (threadIdx.x >> 6);
    float o0 = 0.f, o1 = 0.f, o2 = 0.f, o3 = 0.f;
    gat_accum<8>(hs0, al_a + h, csr0, off0[n], off0[n + 1], al_p[n * 16 + 8 + h], cb,
                 o0, o1, o2, o3);
    gat_accum<16>(hs1, al_p + h, csr1, off1[n], off1[n + 1], al_p[n * 16 + 12 + h], cb,
                  o0, o1, o2, o3);
    const unsigned short* bg0 = cbias + (size_t)(bias_base + 0) * 256;
    const unsigned short* bg1 = cbias + (size_t)(bias_base + 1) * 256;
    const ushort4 bv0 = *(const ushort4*)(bg0 + cb);
    const ushort4 bv1 = *(const ushort4*)(bg1 + cb);
    float v0 = o0 + b2f(bv0.x) + b2f(bv1.x); v0 = v0 > 0.f ? v0 : __expf(v0) - 1.f;
    float v1 = o1 + b2f(bv0.y) + b2f(bv1.y); v1 = v1 > 0.f ? v1 : __expf(v1) - 1.f;
    float v2 = o2 + b2f(bv0.z) + b2f(bv1.z); v2 = v2 > 0.f ? v2 : __expf(v2) - 1.f;
    float v3 = o3 + b2f(bv0.w) + b2f(bv1.w); v3 = v3 > 0.f ? v3 : __expf(v3) - 1.f;
    if (final_ && *flag) {
      float* of = (float*)out_p;
      f32x4 ov = {v0, v1, v2, v3};
      *(f32x4*)(of + (size_t)n * 256 + cb) = ov;
    } else {
      unsigned short* ob = (unsigned short*)out_p;
      ushort4 ov; ov.x = f2b(v0); ov.y = f2b(v1); ov.z = f2b(v2); ov.w = f2b(v3);
      *(ushort4*)(ob + (size_t)n * 256 + cb) = ov;
    }
  } else {
    int n = (bx - 25000) * 4 + (threadIdx.x >> 6);
    float o0 = 0.f, o1 = 0.f, o2 = 0.f, o3 = 0.f;
    gat_accum<16>(hs2, al_p + 4 + h, csr2, off2[n], off2[n + 1], al_a[n * 8 + 4 + h], cb,
                  o0, o1, o2, o3);
    const unsigned short* bg2 = cbias + (size_t)(bias_base + 2) * 256;
    const ushort4 bv = *(const ushort4*)(bg2 + cb);
    float v0 = o0 + b2f(bv.x); v0 = v0 > 0.f ? v0 : __expf(v0) - 1.f;
    float v1 = o1 + b2f(bv.y); v1 = v1 > 0.f ? v1 : __expf(v1) - 1.f;
    float v2 = o2 + b2f(bv.z); v2 = v2 > 0.f ? v2 : __expf(v2) - 1.f;
    float v3 = o3 + b2f(bv.w); v3 = v3 > 0.f ? v3 : __expf(v3) - 1.f;
    size_t elem = (size_t)n * 256 + cb + (final_ ? (size_t)NP * 256 : 0);
    if (final_ && *flag) {
      float* of = (float*)out_a;
      f32x4 ov = {v0, v1, v2, v3};
      *(f32x4*)(of + elem) = ov;
    } else {
      unsigned short* ob = (unsigned short*)out_a;
      ushort4 ov; ov.x = f2b(v0); ov.y = f2b(v1); ov.z = f2b(v2); ov.w = f2b(v3);
      *(ushort4*)(ob + elem) = ov;
    }
  }
}

extern "C" void kernel_launch(void* const* d_in, const int* in_sizes, int n_in,
                              void* d_out, int out_size, void* d_ws, size_t ws_size,
                              hipStream_t stream)
{
  const unsigned short* x_paper  = (const unsigned short*)d_in[0];
  const unsigned short* x_author = (const unsigned short*)d_in[1];
  const unsigned short* W_in_p   = (const unsigned short*)d_in[2];
  const unsigned short* b_in_p   = (const unsigned short*)d_in[3];
  const unsigned short* W_in_a   = (const unsigned short*)d_in[4];
  const unsigned short* b_in_a   = (const unsigned short*)d_in[5];
  const unsigned short* lin_src  = (const unsigned short*)d_in[6];
  const unsigned short* lin_dst  = (const unsigned short*)d_in[7];
  const unsigned short* att_src  = (const unsigned short*)d_in[8];
  const unsigned short* att_dst  = (const unsigned short*)d_in[9];
  const unsigned short* bias_gat = (const unsigned short*)d_in[10];
  const int* writes_src = (const int*)d_in[11];
  const int* writes_dst = (const int*)d_in[12];
  const int* cites_src  = (const int*)d_in[13];
  const int* cites_dst  = (const int*)d_in[14];
  const int* wb_src     = (const int*)d_in[15];
  const int* wb_dst     = (const int*)d_in[16];

  char* base = (char*)d_ws;
  size_t cur = 0;
  auto take = [&](size_t bytes) -> char* {
    char* p = base + cur;
    cur += (bytes + 255) & ~(size_t)255;
    return p;
  };

  int* flag = (int*)take(256);
  unsigned short* cxp   = (unsigned short*)take((size_t)NP * 128 * 2);
  unsigned short* cxa   = (unsigned short*)take((size_t)NA * 128 * 2);
  unsigned short* cWinP = (unsigned short*)take(128 * 256 * 2);
  unsigned short* cWinA = (unsigned short*)take(128 * 256 * 2);
  unsigned short* cbinP = (unsigned short*)take(256 * 2);
  unsigned short* cbinA = (unsigned short*)take(256 * 2);
  unsigned short* clins = (unsigned short*)take((size_t)6 * 65536 * 2);
  unsigned short* clind = (unsigned short*)take((size_t)6 * 65536 * 2);
  unsigned short* catts = (unsigned short*)take(1536 * 2);
  unsigned short* cattd = (unsigned short*)take(1536 * 2);
  unsigned short* cbias = (unsigned short*)take(1536 * 2);

  unsigned short* xp  = (unsigned short*)take((size_t)NP * 256 * 2);
  unsigned short* xa  = (unsigned short*)take((size_t)NA * 256 * 2);
  unsigned short* hs0 = (unsigned short*)take((size_t)NA * 256 * 2);
  unsigned short* hs1 = (unsigned short*)take((size_t)NP * 256 * 2);
  unsigned short* hs2 = (unsigned short*)take((size_t)NP * 256 * 2);
  float* al_p = (float*)take((size_t)NP * 16 * 4);
  float* al_a = (float*)take((size_t)NA * 8 * 4);
  float* Wp   = (float*)take(2 * 256 * 16 * 4);
  float* Wa   = (float*)take(2 * 256 * 8 * 4);
  unsigned short* WinpT = (unsigned short*)take(256 * 128 * 2);
  unsigned short* WinaT = (unsigned short*)take(256 * 128 * 2);
  unsigned short* linsT = (unsigned short*)take((size_t)6 * 65536 * 2);
  int* off0 = (int*)take((size_t)(NP + 1) * 4);
  int* cur0 = (int*)take((size_t)NP * 4);
  int* csr0 = (int*)take((size_t)NE * 4);
  int* off1 = (int*)take((size_t)(NP + 1) * 4);
  int* cur1 = (int*)take((size_t)NP * 4);
  int* csr1 = (int*)take((size_t)NE * 4);
  int* off2 = (int*)take((size_t)(NA + 1) * 4);
  int* cur2 = (int*)take((size_t)NA * 4);
  int* csr2 = (int*)take((size_t)NE * 4);
  int* degAll = (int*)take((size_t)(2 * NP + NA) * 4);
  int* deg0 = degAll;
  int* deg1 = degAll + NP;
  int* deg2 = degAll + 2 * NP;
  int* bsum0 = (int*)take(64 * 4);
  int* bsum1 = (int*)take(64 * 4);
  int* bsum2 = (int*)take(64 * 4);

  probe_kernel<<<1, 256, 0, stream>>>(x_paper, flag);

  const long long CVN = (CV_E10 + 255) / 256;
  conv_all_kernel<<<(unsigned)CVN, 256, 0, stream>>>(
      x_paper, cxp, x_author, cxa, W_in_p, cWinP, W_in_a, cWinA,
      b_in_p, cbinP, b_in_a, cbinA, lin_src, clins, lin_dst, clind,
      att_src, catts, att_dst, cattd, bias_gat, cbias, flag);

  hipMemsetAsync(degAll, 0, (size_t)(2 * NP + NA) * 4, stream);

  fold_kernel<<<48, 256, 0, stream>>>(clins, clind, catts, cattd, Wp, Wa);
  transpose_all_kernel<<<458752 / 256, 256, 0, stream>>>(clins, linsT, cWinP, WinpT, cWinA, WinaT);

  hist3_kernel<<<(3 * NE + 255) / 256, 256, 0, stream>>>(writes_dst, cites_dst, wb_dst,
                                                         deg0, deg1, deg2);

  const int nbP = (NP + 2047) / 2048;   // 49
  const int nbA = (NA + 2047) / 2048;   // 25
  scan_partial3<<<dim3(nbP, 3), 256, 0, stream>>>(deg0, deg1, deg2, bsum0, bsum1, bsum2);
  scan_bsum3<<<3, 64, 0, stream>>>(bsum0, bsum1, bsum2, nbP, nbP, nbA);
  scan_emit3<<<dim3(nbP, 3), 256, 0, stream>>>(deg0, deg1, deg2, bsum0, bsum1, bsum2,
                                               off0, cur0, off1, cur1, off2, cur2);

  scatter3_kernel<<<(3 * NE + 255) / 256, 256, 0, stream>>>(
      writes_src, writes_dst, cites_src, cites_dst, wb_src, wb_dst,
      cur0, cur1, cur2, csr0, csr1, csr2);

  gemm_in_kernel<<<2345, 256, 0, stream>>>(cxp, WinpT, xp, cbinP, cxa, WinaT, xa, cbinA);

  for (int l = 0; l < 2; ++l) {
    layer_kernel<<<4495, 256, 0, stream>>>(
        xp, xa, linsT + (size_t)l * 3 * 65536, hs0, hs1, hs2,
        Wp + l * 4096, Wa + l * 2048, al_p, al_a);
    if (l == 0) {
      msg_all_kernel<<<37500, 256, 0, stream>>>(
          hs0, hs1, hs2, al_p, al_a, off0, csr0, off1, csr1, off2, csr2,
          cbias, 0, xp, xa, 0, flag);
    } else {
      msg_all_kernel<<<37500, 256, 0, stream>>>(
          hs0, hs1, hs2, al_p, al_a, off0, csr0, off1, csr1, off2, csr2,
          cbias, 3, d_out, d_out, 1, flag);
    }
  }
}

// Round 7
// 724.376 us; speedup vs baseline: 1.7289x; 1.1036x over previous
//
#include <hip/hip_runtime.h>

// HeteroGAT on MI355X. Round 10:
//  - WEIGHT LAYOUT: linsT/WinpT/WinaT now stored in MFMA-fragment order
//    W[(k>>3)*2048 + n*8 + (k&7)] so each B-fragment load is a fully
//    coalesced 1KB/wave burst (was: 16 lanes x 512B-strided scatter = 16
//    separate 64B lines per instr -> TA serialization, 32k cyc/block).
//  - gemm_body reads B via the fragment layout; everything else as round-9.

#define NP 100000
#define NA 50000
#define NE 250000

typedef __attribute__((ext_vector_type(8))) short short8;
typedef __attribute__((ext_vector_type(4))) float f32x4;

__device__ __forceinline__ float b2f(unsigned short u) {
  union { unsigned int i; float f; } v; v.i = ((unsigned int)u) << 16; return v.f;
}
__device__ __forceinline__ float u2f_lo(unsigned int u) {
  union { unsigned int i; float f; } v; v.i = u << 16; return v.f;
}
__device__ __forceinline__ float u2f_hi(unsigned int u) {
  union { unsigned int i; float f; } v; v.i = u & 0xffff0000u; return v.f;
}
__device__ __forceinline__ unsigned short f2b(float f) {
  union { float f; unsigned int i; } v; v.f = f;
  unsigned int u = v.i;
  return (unsigned short)((u + 0x7fffu + ((u >> 16) & 1u)) >> 16);
}

__global__ void probe_kernel(const unsigned short* __restrict__ x, int* __restrict__ flag)
{
  __shared__ int cnt;
  if (threadIdx.x == 0) cnt = 0;
  __syncthreads();
  int c = 0;
  for (int i = threadIdx.x; i < 4096; i += 256) {
    unsigned int e = (x[i] >> 7) & 0xFFu;
    if (e >= 0xC0u) c++;
  }
  atomicAdd(&cnt, c);
  __syncthreads();
  if (threadIdx.x == 0) *flag = (cnt > 64) ? 1 : 0;   // 1 = inputs are fp32
}

// ---- fused bf16-conversion of all 11 input tensors in one launch ----
#define CV_E0 12800000LL
#define CV_E1 19200000LL
#define CV_E2 19232768LL
#define CV_E3 19265536LL
#define CV_E4 19265792LL
#define CV_E5 19266048LL
#define CV_E6 19659264LL
#define CV_E7 20052480LL
#define CV_E8 20054016LL
#define CV_E9 20055552LL
#define CV_E10 20057088LL

__global__ void conv_all_kernel(
    const unsigned short* __restrict__ s0, unsigned short* __restrict__ d0,
    const unsigned short* __restrict__ s1, unsigned short* __restrict__ d1,
    const unsigned short* __restrict__ s2, unsigned short* __restrict__ d2,
    const unsigned short* __restrict__ s3, unsigned short* __restrict__ d3,
    const unsigned short* __restrict__ s4, unsigned short* __restrict__ d4,
    const unsigned short* __restrict__ s5, unsigned short* __restrict__ d5,
    const unsigned short* __restrict__ s6, unsigned short* __restrict__ d6,
    const unsigned short* __restrict__ s7, unsigned short* __restrict__ d7,
    const unsigned short* __restrict__ s8, unsigned short* __restrict__ d8,
    const unsigned short* __restrict__ s9, unsigned short* __restrict__ d9,
    const unsigned short* __restrict__ s10, unsigned short* __restrict__ d10,
    const int* __restrict__ flag)
{
  long long idx = (long long)blockIdx.x * 256 + threadIdx.x;
  if (idx >= CV_E10) return;
  int f = *flag;
  const unsigned short* s; unsigned short* d; long long off;
  if (idx < CV_E0)      { s = s0;  d = d0;  off = idx; }
  else if (idx < CV_E1) { s = s1;  d = d1;  off = idx - CV_E0; }
  else if (idx < CV_E2) { s = s2;  d = d2;  off = idx - CV_E1; }
  else if (idx < CV_E3) { s = s3;  d = d3;  off = idx - CV_E2; }
  else if (idx < CV_E4) { s = s4;  d = d4;  off = idx - CV_E3; }
  else if (idx < CV_E5) { s = s5;  d = d5;  off = idx - CV_E4; }
  else if (idx < CV_E6) { s = s6;  d = d6;  off = idx - CV_E5; }
  else if (idx < CV_E7) { s = s7;  d = d7;  off = idx - CV_E6; }
  else if (idx < CV_E8) { s = s8;  d = d8;  off = idx - CV_E7; }
  else if (idx < CV_E9) { s = s9;  d = d9;  off = idx - CV_E8; }
  else                  { s = s10; d = d10; off = idx - CV_E9; }
  if (f) d[off] = f2b(((const float*)s)[off]);
  else   d[off] = s[off];
}

// Skinny GEMM body: C[M x 256] = A[M x K] * W, bf16 in/out, f32 acc.
// BM=64, BN=256. A tile -> LDS via global_load_lds (XOR-swizzled source +
// swizzled ds_read). B (weights) stored in MFMA-FRAGMENT ORDER:
//   BF[(k>>3)*2048 + n*8 + (k&7)]   (k = reduction idx, n = output col)
// so each bq load is 1KB/wave fully coalesced. All B fragments live in
// registers (loop-invariant per block). mfma(bq, af) -> lane holds 4
// consecutive cols of one row -> packed 8B stores.
template <int K, int RELU>
__device__ __forceinline__ void gemm_body(
    const unsigned short* __restrict__ A, const unsigned short* __restrict__ BF,
    unsigned short* __restrict__ C, int M, const unsigned short* __restrict__ bias,
    int bx, unsigned short* As)
{
  constexpr int SLOT = K / 8;               // 16B slots per row (32 or 16)
  constexpr int NKC = K / 32;
  const int t = threadIdx.x;
  const int lane = t & 63;
  const int w = t >> 6;                     // wave id 0..3 -> 64-col group
  const int quad = lane >> 4;
  const int l16 = lane & 15;
  const int m0 = bx * 64;
  const int colbase = w * 64;

  // 1) issue A-stage DMAs (global -> LDS, swizzled source, linear dest)
  {
    constexpr int CALLS = (64 * SLOT) / 256;
#pragma unroll
    for (int c = 0; c < CALLS; c++) {
      int slot = c * 256 + t;
      int row = slot / SLOT;
      int c16 = slot % SLOT;
      int gr = m0 + row; gr = gr < M ? gr : (M - 1);
      int gc16 = c16 ^ (row & 7);
      const unsigned short* gp = A + (size_t)gr * K + gc16 * 8;
      unsigned short* lp = As + (size_t)(c * 256 + (t & ~63)) * 8;
      __builtin_amdgcn_global_load_lds(
          (const __attribute__((address_space(1))) unsigned int*)gp,
          (__attribute__((address_space(3))) unsigned int*)lp, 16, 0, 0);
    }
  }

  // 2) B fragments, coalesced: k-slot s = kc*4+quad, cols colbase+j*16+l16
  short8 bq[NKC][4];
#pragma unroll
  for (int kc = 0; kc < NKC; ++kc)
#pragma unroll
    for (int j = 0; j < 4; j++)
      bq[kc][j] = *(const short8*)(BF + ((size_t)(kc * 4 + quad) * 256 + colbase + j * 16 + l16) * 8);

  __syncthreads();

  f32x4 acc[4][4];
#pragma unroll
  for (int i = 0; i < 4; i++)
#pragma unroll
    for (int j = 0; j < 4; j++) { acc[i][j][0] = 0.f; acc[i][j][1] = 0.f; acc[i][j][2] = 0.f; acc[i][j][3] = 0.f; }

  // 3) pure LDS + MFMA loop
#pragma unroll
  for (int kc = 0; kc < NKC; ++kc) {
    short8 af[4];
#pragma unroll
    for (int i = 0; i < 4; i++) {
      int row = i * 16 + l16;
      int c16 = (kc * 4 + quad) ^ (row & 7);
      af[i] = *(const short8*)(As + (size_t)row * K + c16 * 8);
    }
#pragma unroll
    for (int i = 0; i < 4; i++)
#pragma unroll
      for (int j = 0; j < 4; j++)
        acc[i][j] = __builtin_amdgcn_mfma_f32_16x16x32_bf16(bq[kc][j], af[i], acc[i][j], 0, 0, 0);
  }

  // acc[i][j][r] = C[m0 + i*16 + l16][colbase + j*16 + quad*4 + r]
#pragma unroll
  for (int i = 0; i < 4; i++) {
    int row = m0 + i * 16 + l16;
    if (row < M) {
#pragma unroll
      for (int j = 0; j < 4; j++) {
        int col0 = colbase + j * 16 + quad * 4;
        float b0 = 0.f, b1 = 0.f, b2 = 0.f, b3 = 0.f;
        if (bias) {
          const ushort4 bb = *(const ushort4*)(bias + col0);
          b0 = b2f(bb.x); b1 = b2f(bb.y); b2 = b2f(bb.z); b3 = b2f(bb.w);
        }
        float v0 = acc[i][j][0] + b0;
        float v1 = acc[i][j][1] + b1;
        float v2 = acc[i][j][2] + b2;
        float v3 = acc[i][j][3] + b3;
        if (RELU) {
          v0 = v0 > 0.f ? v0 : 0.f; v1 = v1 > 0.f ? v1 : 0.f;
          v2 = v2 > 0.f ? v2 : 0.f; v3 = v3 > 0.f ? v3 : 0.f;
        }
        ushort4 ov; ov.x = f2b(v0); ov.y = f2b(v1); ov.z = f2b(v2); ov.w = f2b(v3);
        *(ushort4*)(C + (size_t)row * 256 + col0) = ov;
      }
    }
  }
}

// al body: out[row, 0..NCOL) = X[row,:256] (bf16) dot W[:,j] (f32)
template <int NCOL>
__device__ __forceinline__ void al_body(const unsigned short* __restrict__ X, int rows,
                                        const float* __restrict__ W, float* __restrict__ out,
                                        int bx, float* Ws)
{
  for (int i = threadIdx.x; i < 256 * NCOL; i += 256) Ws[i] = W[i];
  __syncthreads();
  int row = bx * 256 + threadIdx.x;
  if (row >= rows) return;
  f32x4 acc[NCOL / 4];
#pragma unroll
  for (int jv = 0; jv < NCOL / 4; jv++) { acc[jv][0] = 0.f; acc[jv][1] = 0.f; acc[jv][2] = 0.f; acc[jv][3] = 0.f; }
  const unsigned short* xr = X + (size_t)row * 256;
  for (int k = 0; k < 256; k += 8) {
    uint4 pk = *(const uint4*)(xr + k);
    unsigned int uu[4] = {pk.x, pk.y, pk.z, pk.w};
#pragma unroll
    for (int e2 = 0; e2 < 4; e2++) {
      float x0 = b2f((unsigned short)(uu[e2] & 0xffffu));
      float x1 = b2f((unsigned short)(uu[e2] >> 16));
      int k0 = k + e2 * 2;
#pragma unroll
      for (int jv = 0; jv < NCOL / 4; jv++) {
        const f32x4 w0 = *(const f32x4*)&Ws[k0 * NCOL + jv * 4];
        const f32x4 w1 = *(const f32x4*)&Ws[(k0 + 1) * NCOL + jv * 4];
#pragma unroll
        for (int c = 0; c < 4; c++) acc[jv][c] += x0 * w0[c] + x1 * w1[c];
      }
    }
  }
#pragma unroll
  for (int jv = 0; jv < NCOL / 4; jv++)
    *(f32x4*)&out[(size_t)row * NCOL + jv * 4] = acc[jv];
}

// merged input gemms: [0,1563) paper K=128, [1563,2345) author K=128
__global__ __launch_bounds__(256) void gemm_in_kernel(
    const unsigned short* __restrict__ cxp, const unsigned short* __restrict__ WinpT,
    unsigned short* __restrict__ xp, const unsigned short* __restrict__ cbinP,
    const unsigned short* __restrict__ cxa, const unsigned short* __restrict__ WinaT,
    unsigned short* __restrict__ xa, const unsigned short* __restrict__ cbinA)
{
  __shared__ __align__(16) unsigned short As[64 * 128];
  int bx = blockIdx.x;
  if (bx < 1563) gemm_body<128, 1>(cxp, WinpT, xp, NP, cbinP, bx, As);
  else           gemm_body<128, 1>(cxa, WinaT, xa, NA, cbinA, bx - 1563, As);
}

// merged per-layer compute: hs0 [0,782), hs1 [782,2345), hs2 [2345,3908),
// al_p [3908,4299), al_a [4299,4495)
__global__ __launch_bounds__(256, 2) void layer_kernel(
    const unsigned short* __restrict__ xp, const unsigned short* __restrict__ xa,
    const unsigned short* __restrict__ linsT_l,
    unsigned short* __restrict__ hs0, unsigned short* __restrict__ hs1,
    unsigned short* __restrict__ hs2,
    const float* __restrict__ Wp_l, const float* __restrict__ Wa_l,
    float* __restrict__ al_p, float* __restrict__ al_a)
{
  __shared__ __align__(16) unsigned short smem[64 * 256];   // 32 KB union
  int bx = blockIdx.x;
  if (bx < 782)       gemm_body<256, 0>(xa, linsT_l + 0 * 65536, hs0, NA, nullptr, bx, smem);
  else if (bx < 2345) gemm_body<256, 0>(xp, linsT_l + 1 * 65536, hs1, NP, nullptr, bx - 782, smem);
  else if (bx < 3908) gemm_body<256, 0>(xp, linsT_l + 2 * 65536, hs2, NP, nullptr, bx - 2345, smem);
  else if (bx < 4299) al_body<16>(xp, NP, Wp_l, al_p, bx - 3908, (float*)smem);
  else                al_body<8>(xa, NA, Wa_l, al_a, bx - 4299, (float*)smem);
}

// Wp cols: 0-3 al_s(t=1), 4-7 al_s(t=2), 8-11 al_d(t=0), 12-15 al_d(t=1)
// Wa cols: 0-3 al_s(t=0), 4-7 al_d(t=2)
__global__ void fold_kernel(const unsigned short* __restrict__ lin_src,
                            const unsigned short* __restrict__ lin_dst,
                            const unsigned short* __restrict__ att_src,
                            const unsigned short* __restrict__ att_dst,
                            float* __restrict__ Wp, float* __restrict__ Wa)
{
  int idx = blockIdx.x * 256 + threadIdx.x;
  if (idx >= 12288) return;
  const unsigned short *L, *At;
  int l, k, j, t, h;
  if (idx < 8192) {
    l = idx >> 12; int rem = idx & 4095; k = rem >> 4; j = rem & 15;
    if (j < 4)       { t = 1; h = j;      L = lin_src; At = att_src; }
    else if (j < 8)  { t = 2; h = j - 4;  L = lin_src; At = att_src; }
    else if (j < 12) { t = 0; h = j - 8;  L = lin_dst; At = att_dst; }
    else             { t = 1; h = j - 12; L = lin_dst; At = att_dst; }
    int lt = l * 3 + t;
    float s = 0.f;
    for (int c = 0; c < 64; c++)
      s += b2f(L[((size_t)lt * 256 + k) * 256 + h * 64 + c]) * b2f(At[(lt * 4 + h) * 64 + c]);
    Wp[l * 4096 + k * 16 + j] = s;
  } else {
    int i2 = idx - 8192;
    l = i2 >> 11; int rem = i2 & 2047; k = rem >> 3; j = rem & 7;
    if (j < 4) { t = 0; h = j;     L = lin_src; At = att_src; }
    else       { t = 2; h = j - 4; L = lin_dst; At = att_dst; }
    int lt = l * 3 + t;
    float s = 0.f;
    for (int c = 0; c < 64; c++)
      s += b2f(L[((size_t)lt * 256 + k) * 256 + h * 64 + c]) * b2f(At[(lt * 4 + h) * 64 + c]);
    Wa[l * 2048 + k * 8 + j] = s;
  }
}

// merged transposes -> MFMA-fragment layout:
//   out[(k>>3)*2048 + n*8 + (k&7)] = in[k*256 + n]
// lins (6 batches of 256x256) [0,393216), WinP (128x256) [..425984), WinA [..458752)
__global__ void transpose_all_kernel(const unsigned short* __restrict__ clins,
                                     unsigned short* __restrict__ linsT,
                                     const unsigned short* __restrict__ cWinP,
                                     unsigned short* __restrict__ WinpT,
                                     const unsigned short* __restrict__ cWinA,
                                     unsigned short* __restrict__ WinaT)
{
  int idx = blockIdx.x * 256 + threadIdx.x;
  if (idx < 393216) {
    int b = idx >> 16; int rem = idx & 65535; int k = rem >> 8; int n = rem & 255;
    linsT[(size_t)b * 65536 + (size_t)(k >> 3) * 2048 + n * 8 + (k & 7)] = clins[idx];
  } else if (idx < 425984) {
    int i2 = idx - 393216; int k = i2 >> 8; int n = i2 & 255;
    WinpT[(size_t)(k >> 3) * 2048 + n * 8 + (k & 7)] = cWinP[i2];
  } else if (idx < 458752) {
    int i2 = idx - 425984; int k = i2 >> 8; int n = i2 & 255;
    WinaT[(size_t)(k >> 3) * 2048 + n * 8 + (k & 7)] = cWinA[i2];
  }
}

__global__ void hist3_kernel(const int* __restrict__ wdst, const int* __restrict__ cdst,
                             const int* __restrict__ adst,
                             int* __restrict__ deg0, int* __restrict__ deg1, int* __restrict__ deg2)
{
  int idx = blockIdx.x * 256 + threadIdx.x;
  if (idx < NE)          atomicAdd(&deg0[wdst[idx]], 1);
  else if (idx < 2 * NE) atomicAdd(&deg1[cdst[idx - NE]], 1);
  else if (idx < 3 * NE) atomicAdd(&deg2[adst[idx - 2 * NE]], 1);
}

// ---------------- hierarchical scan, 3 edge-types per launch via blockIdx.y
__global__ __launch_bounds__(256) void scan_partial3(const int* __restrict__ deg0,
                                                     const int* __restrict__ deg1,
                                                     const int* __restrict__ deg2,
                                                     int* __restrict__ b0, int* __restrict__ b1,
                                                     int* __restrict__ b2)
{
  const int* deg; int n; int* bs;
  if (blockIdx.y == 0)      { deg = deg0; n = NP; bs = b0; }
  else if (blockIdx.y == 1) { deg = deg1; n = NP; bs = b1; }
  else                      { deg = deg2; n = NA; bs = b2; }
  if ((int)blockIdx.x * 2048 >= n) return;
  int tid = threadIdx.x;
  int base = blockIdx.x * 2048 + tid * 8;
  int s = 0;
#pragma unroll
  for (int i = 0; i < 8; i++) { int idx = base + i; if (idx < n) s += deg[idx]; }
  __shared__ int red[256];
  red[tid] = s;
  __syncthreads();
  for (int d = 128; d > 0; d >>= 1) {
    if (tid < d) red[tid] += red[tid + d];
    __syncthreads();
  }
  if (tid == 0) bs[blockIdx.x] = red[0];
}

// three blocks, one wave each; nb <= 64. In-place exclusive scan of block sums.
__global__ void scan_bsum3(int* __restrict__ b0, int* __restrict__ b1, int* __restrict__ b2,
                           int nb0, int nb1, int nb2)
{
  int* bsum; int nb;
  if (blockIdx.x == 0)      { bsum = b0; nb = nb0; }
  else if (blockIdx.x == 1) { bsum = b1; nb = nb1; }
  else                      { bsum = b2; nb = nb2; }
  int lane = threadIdx.x;
  int orig = (lane < nb) ? bsum[lane] : 0;
  int v = orig;
  for (int d = 1; d < 64; d <<= 1) {
    int t = __shfl_up(v, d);
    if (lane >= d) v += t;
  }
  if (lane < nb) bsum[lane] = v - orig;   // exclusive
}

__global__ __launch_bounds__(256) void scan_emit3(const int* __restrict__ deg0,
                                                  const int* __restrict__ deg1,
                                                  const int* __restrict__ deg2,
                                                  const int* __restrict__ b0,
                                                  const int* __restrict__ b1,
                                                  const int* __restrict__ b2,
                                                  int* __restrict__ off0a, int* __restrict__ cur0a,
                                                  int* __restrict__ off1a, int* __restrict__ cur1a,
                                                  int* __restrict__ off2a, int* __restrict__ cur2a)
{
  const int* deg; int n; const int* bsum; int* off; int* cur;
  if (blockIdx.y == 0)      { deg = deg0; n = NP; bsum = b0; off = off0a; cur = cur0a; }
  else if (blockIdx.y == 1) { deg = deg1; n = NP; bsum = b1; off = off1a; cur = cur1a; }
  else                      { deg = deg2; n = NA; bsum = b2; off = off2a; cur = cur2a; }
  if ((int)blockIdx.x * 2048 >= n) return;
  int tid = threadIdx.x;
  int base = blockIdx.x * 2048 + tid * 8;
  int vals[8]; int s = 0;
#pragma unroll
  for (int i = 0; i < 8; i++) { int idx = base + i; vals[i] = (idx < n) ? deg[idx] : 0; s += vals[i]; }
  __shared__ int sh[256];
  sh[tid] = s;
  __syncthreads();
  for (int d = 1; d < 256; d <<= 1) {
    int t = (tid >= d) ? sh[tid - d] : 0;
    __syncthreads();
    sh[tid] += t;
    __syncthreads();
  }
  int run = bsum[blockIdx.x] + sh[tid] - s;   // exclusive prefix for this thread's chunk
#pragma unroll
  for (int i = 0; i < 8; i++) {
    int idx = base + i;
    if (idx < n) { off[idx] = run; cur[idx] = run; run += vals[i]; }
  }
  if (blockIdx.x == 0 && tid == 0) off[n] = NE;
}

__global__ void scatter3_kernel(const int* __restrict__ ws, const int* __restrict__ wd,
                                const int* __restrict__ cs, const int* __restrict__ cd,
                                const int* __restrict__ as, const int* __restrict__ ad,
                                int* __restrict__ cur0, int* __restrict__ cur1, int* __restrict__ cur2,
                                int* __restrict__ csr0, int* __restrict__ csr1, int* __restrict__ csr2)
{
  int idx = blockIdx.x * 256 + threadIdx.x;
  if (idx < NE) {
    int p = atomicAdd(&cur0[wd[idx]], 1); csr0[p] = ws[idx];
  } else if (idx < 2 * NE) {
    int e = idx - NE;
    int p = atomicAdd(&cur1[cd[e]], 1); csr1[p] = cs[e];
  } else if (idx < 3 * NE) {
    int e = idx - 2 * NE;
    int p = atomicAdd(&cur2[ad[e]], 1); csr2[p] = as[e];
  }
}

// 4-wide-batched GAT accumulation, NO online max: p = exp(min(lg,60)) directly
// (softmax shift-invariant; logits O(3), clamp guards overflow).
// Padded slots duplicate the last edge (valid address) and get p=0.
template <int STRIDE>
__device__ __forceinline__ void gat_accum(const unsigned short* __restrict__ hs,
                                          const float* __restrict__ alsb,
                                          const int* __restrict__ csr,
                                          int s, int e, float ald, int cb,
                                          float& o0, float& o1, float& o2, float& o3)
{
  if (s >= e) return;
  float denom = 0.f, a0 = 0.f, a1 = 0.f, a2 = 0.f, a3 = 0.f;
  for (int i = s; i < e; i += 4) {
    int svv[4];
#pragma unroll
    for (int j = 0; j < 4; j++) {
      int idx = (i + j < e) ? (i + j) : (e - 1);
      svv[j] = csr[idx];
    }
    float als[4]; uint2 hv[4];
#pragma unroll
    for (int j = 0; j < 4; j++) {
      als[j] = alsb[(size_t)svv[j] * STRIDE];
      hv[j] = *(const uint2*)(hs + (size_t)svv[j] * 256 + cb);
    }
#pragma unroll
    for (int j = 0; j < 4; j++) {
      float l = als[j] + ald;
      l = l > 0.f ? l : 0.2f * l;
      l = fminf(l, 60.f);
      float p = (i + j < e) ? __expf(l) : 0.f;
      denom += p;
      a0 += p * u2f_lo(hv[j].x);
      a1 += p * u2f_hi(hv[j].x);
      a2 += p * u2f_lo(hv[j].y);
      a3 += p * u2f_hi(hv[j].y);
    }
  }
  float inv = denom > 0.f ? 1.f / denom : 0.f;
  o0 += a0 * inv; o1 += a1 * inv; o2 += a2 * inv; o3 += a3 * inv;
}

// merged msg: paper [0,25000), author [25000,37500). bias_base: 0 (l=0) / 3 (l=1)
__global__ __launch_bounds__(256) void msg_all_kernel(
    const unsigned short* __restrict__ hs0, const unsigned short* __restrict__ hs1,
    const unsigned short* __restrict__ hs2,
    const float* __restrict__ al_p, const float* __restrict__ al_a,
    const int* __restrict__ off0, const int* __restrict__ csr0,
    const int* __restrict__ off1, const int* __restrict__ csr1,
    const int* __restrict__ off2, const int* __restrict__ csr2,
    const unsigned short* __restrict__ cbias, int bias_base,
    void* __restrict__ out_p, void* __restrict__ out_a, int final_,
    const int* __restrict__ flag)
{
  int bx = blockIdx.x;
  int lane = threadIdx.x & 63;
  int h = lane >> 4;
  int cb = lane * 4;
  if (bx < 25000) {
    int n = bx * 4 + (threadIdx.x >> 6);
    float o0 = 0.f, o1 = 0.f, o2 = 0.f, o3 = 0.f;
    gat_accum<8>(hs0, al_a + h, csr0, off0[n], off0[n + 1], al_p[n * 16 + 8 + h], cb,
                 o0, o1, o2, o3);
    gat_accum<16>(hs1, al_p + h, csr1, off1[n], off1[n + 1], al_p[n * 16 + 12 + h], cb,
                  o0, o1, o2, o3);
    const unsigned short* bg0 = cbias + (size_t)(bias_base + 0) * 256;
    const unsigned short* bg1 = cbias + (size_t)(bias_base + 1) * 256;
    const ushort4 bv0 = *(const ushort4*)(bg0 + cb);
    const ushort4 bv1 = *(const ushort4*)(bg1 + cb);
    float v0 = o0 + b2f(bv0.x) + b2f(bv1.x); v0 = v0 > 0.f ? v0 : __expf(v0) - 1.f;
    float v1 = o1 + b2f(bv0.y) + b2f(bv1.y); v1 = v1 > 0.f ? v1 : __expf(v1) - 1.f;
    float v2 = o2 + b2f(bv0.z) + b2f(bv1.z); v2 = v2 > 0.f ? v2 : __expf(v2) - 1.f;
    float v3 = o3 + b2f(bv0.w) + b2f(bv1.w); v3 = v3 > 0.f ? v3 : __expf(v3) - 1.f;
    if (final_ && *flag) {
      float* of = (float*)out_p;
      f32x4 ov = {v0, v1, v2, v3};
      *(f32x4*)(of + (size_t)n * 256 + cb) = ov;
    } else {
      unsigned short* ob = (unsigned short*)out_p;
      ushort4 ov; ov.x = f2b(v0); ov.y = f2b(v1); ov.z = f2b(v2); ov.w = f2b(v3);
      *(ushort4*)(ob + (size_t)n * 256 + cb) = ov;
    }
  } else {
    int n = (bx - 25000) * 4 + (threadIdx.x >> 6);
    float o0 = 0.f, o1 = 0.f, o2 = 0.f, o3 = 0.f;
    gat_accum<16>(hs2, al_p + 4 + h, csr2, off2[n], off2[n + 1], al_a[n * 8 + 4 + h], cb,
                  o0, o1, o2, o3);
    const unsigned short* bg2 = cbias + (size_t)(bias_base + 2) * 256;
    const ushort4 bv = *(const ushort4*)(bg2 + cb);
    float v0 = o0 + b2f(bv.x); v0 = v0 > 0.f ? v0 : __expf(v0) - 1.f;
    float v1 = o1 + b2f(bv.y); v1 = v1 > 0.f ? v1 : __expf(v1) - 1.f;
    float v2 = o2 + b2f(bv.z); v2 = v2 > 0.f ? v2 : __expf(v2) - 1.f;
    float v3 = o3 + b2f(bv.w); v3 = v3 > 0.f ? v3 : __expf(v3) - 1.f;
    size_t elem = (size_t)n * 256 + cb + (final_ ? (size_t)NP * 256 : 0);
    if (final_ && *flag) {
      float* of = (float*)out_a;
      f32x4 ov = {v0, v1, v2, v3};
      *(f32x4*)(of + elem) = ov;
    } else {
      unsigned short* ob = (unsigned short*)out_a;
      ushort4 ov; ov.x = f2b(v0); ov.y = f2b(v1); ov.z = f2b(v2); ov.w = f2b(v3);
      *(ushort4*)(ob + elem) = ov;
    }
  }
}

extern "C" void kernel_launch(void* const* d_in, const int* in_sizes, int n_in,
                              void* d_out, int out_size, void* d_ws, size_t ws_size,
                              hipStream_t stream)
{
  const unsigned short* x_paper  = (const unsigned short*)d_in[0];
  const unsigned short* x_author = (const unsigned short*)d_in[1];
  const unsigned short* W_in_p   = (const unsigned short*)d_in[2];
  const unsigned short* b_in_p   = (const unsigned short*)d_in[3];
  const unsigned short* W_in_a   = (const unsigned short*)d_in[4];
  const unsigned short* b_in_a   = (const unsigned short*)d_in[5];
  const unsigned short* lin_src  = (const unsigned short*)d_in[6];
  const unsigned short* lin_dst  = (const unsigned short*)d_in[7];
  const unsigned short* att_src  = (const unsigned short*)d_in[8];
  const unsigned short* att_dst  = (const unsigned short*)d_in[9];
  const unsigned short* bias_gat = (const unsigned short*)d_in[10];
  const int* writes_src = (const int*)d_in[11];
  const int* writes_dst = (const int*)d_in[12];
  const int* cites_src  = (const int*)d_in[13];
  const int* cites_dst  = (const int*)d_in[14];
  const int* wb_src     = (const int*)d_in[15];
  const int* wb_dst     = (const int*)d_in[16];

  char* base = (char*)d_ws;
  size_t cur = 0;
  auto take = [&](size_t bytes) -> char* {
    char* p = base + cur;
    cur += (bytes + 255) & ~(size_t)255;
    return p;
  };

  int* flag = (int*)take(256);
  unsigned short* cxp   = (unsigned short*)take((size_t)NP * 128 * 2);
  unsigned short* cxa   = (unsigned short*)take((size_t)NA * 128 * 2);
  unsigned short* cWinP = (unsigned short*)take(128 * 256 * 2);
  unsigned short* cWinA = (unsigned short*)take(128 * 256 * 2);
  unsigned short* cbinP = (unsigned short*)take(256 * 2);
  unsigned short* cbinA = (unsigned short*)take(256 * 2);
  unsigned short* clins = (unsigned short*)take((size_t)6 * 65536 * 2);
  unsigned short* clind = (unsigned short*)take((size_t)6 * 65536 * 2);
  unsigned short* catts = (unsigned short*)take(1536 * 2);
  unsigned short* cattd = (unsigned short*)take(1536 * 2);
  unsigned short* cbias = (unsigned short*)take(1536 * 2);

  unsigned short* xp  = (unsigned short*)take((size_t)NP * 256 * 2);
  unsigned short* xa  = (unsigned short*)take((size_t)NA * 256 * 2);
  unsigned short* hs0 = (unsigned short*)take((size_t)NA * 256 * 2);
  unsigned short* hs1 = (unsigned short*)take((size_t)NP * 256 * 2);
  unsigned short* hs2 = (unsigned short*)take((size_t)NP * 256 * 2);
  float* al_p = (float*)take((size_t)NP * 16 * 4);
  float* al_a = (float*)take((size_t)NA * 8 * 4);
  float* Wp   = (float*)take(2 * 256 * 16 * 4);
  float* Wa   = (float*)take(2 * 256 * 8 * 4);
  unsigned short* WinpT = (unsigned short*)take(256 * 128 * 2);
  unsigned short* WinaT = (unsigned short*)take(256 * 128 * 2);
  unsigned short* linsT = (unsigned short*)take((size_t)6 * 65536 * 2);
  int* off0 = (int*)take((size_t)(NP + 1) * 4);
  int* cur0 = (int*)take((size_t)NP * 4);
  int* csr0 = (int*)take((size_t)NE * 4);
  int* off1 = (int*)take((size_t)(NP + 1) * 4);
  int* cur1 = (int*)take((size_t)NP * 4);
  int* csr1 = (int*)take((size_t)NE * 4);
  int* off2 = (int*)take((size_t)(NA + 1) * 4);
  int* cur2 = (int*)take((size_t)NA * 4);
  int* csr2 = (int*)take((size_t)NE * 4);
  int* degAll = (int*)take((size_t)(2 * NP + NA) * 4);
  int* deg0 = degAll;
  int* deg1 = degAll + NP;
  int* deg2 = degAll + 2 * NP;
  int* bsum0 = (int*)take(64 * 4);
  int* bsum1 = (int*)take(64 * 4);
  int* bsum2 = (int*)take(64 * 4);

  probe_kernel<<<1, 256, 0, stream>>>(x_paper, flag);

  const long long CVN = (CV_E10 + 255) / 256;
  conv_all_kernel<<<(unsigned)CVN, 256, 0, stream>>>(
      x_paper, cxp, x_author, cxa, W_in_p, cWinP, W_in_a, cWinA,
      b_in_p, cbinP, b_in_a, cbinA, lin_src, clins, lin_dst, clind,
      att_src, catts, att_dst, cattd, bias_gat, cbias, flag);

  hipMemsetAsync(degAll, 0, (size_t)(2 * NP + NA) * 4, stream);

  fold_kernel<<<48, 256, 0, stream>>>(clins, clind, catts, cattd, Wp, Wa);
  transpose_all_kernel<<<458752 / 256, 256, 0, stream>>>(clins, linsT, cWinP, WinpT, cWinA, WinaT);

  hist3_kernel<<<(3 * NE + 255) / 256, 256, 0, stream>>>(writes_dst, cites_dst, wb_dst,
                                                         deg0, deg1, deg2);

  const int nbP = (NP + 2047) / 2048;   // 49
  const int nbA = (NA + 2047) / 2048;   // 25
  scan_partial3<<<dim3(nbP, 3), 256, 0, stream>>>(deg0, deg1, deg2, bsum0, bsum1, bsum2);
  scan_bsum3<<<3, 64, 0, stream>>>(bsum0, bsum1, bsum2, nbP, nbP, nbA);
  scan_emit3<<<dim3(nbP, 3), 256, 0, stream>>>(deg0, deg1, deg2, bsum0, bsum1, bsum2,
                                               off0, cur0, off1, cur1, off2, cur2);

  scatter3_kernel<<<(3 * NE + 255) / 256, 256, 0, stream>>>(
      writes_src, writes_dst, cites_src, cites_dst, wb_src, wb_dst,
      cur0, cur1, cur2, csr0, csr1, csr2);

  gemm_in_kernel<<<2345, 256, 0, stream>>>(cxp, WinpT, xp, cbinP, cxa, WinaT, xa, cbinA);

  for (int l = 0; l < 2; ++l) {
    layer_kernel<<<4495, 256, 0, stream>>>(
        xp, xa, linsT + (size_t)l * 3 * 65536, hs0, hs1, hs2,
        Wp + l * 4096, Wa + l * 2048, al_p, al_a);
    if (l == 0) {
      msg_all_kernel<<<37500, 256, 0, stream>>>(
          hs0, hs1, hs2, al_p, al_a, off0, csr0, off1, csr1, off2, csr2,
          cbias, 0, xp, xa, 0, flag);
    } else {
      msg_all_kernel<<<37500, 256, 0, stream>>>(
          hs0, hs1, hs2, al_p, al_a, off0, csr0, off1, csr1, off2, csr2,
          cbias, 3, d_out, d_out, 1, flag);
    }
  }
}